// Round 1
// baseline (445.266 us; speedup 1.0000x reference)
//
#include <hip/hip_runtime.h>
#include <hip/hip_bf16.h>
#include <hip/hip_fp16.h>
#include <cstdint>

// Problem constants
constexpr int B_   = 64;
constexpr int L_   = 512;
constexpr int G_   = 128;
constexpr int E_   = 65536;
constexpr int RH   = 256;    // NREL*NHID
constexpr int M_   = 2048;   // B*N distinct nodes
constexpr int JA   = 33;     // augmented j (32 + const-1 slot)
constexpr int COLS = RH * JA;   // 8448
constexpr int NREP = 16;     // LN-stat accumulator replicas (atomic decontention)

typedef _Float16 v2h __attribute__((ext_vector_type(2)));
typedef _Float16 v8h __attribute__((ext_vector_type(8)));
typedef float    v4f __attribute__((ext_vector_type(4)));
typedef float    v2f32 __attribute__((ext_vector_type(2)));
typedef union { uint4 u4; v8h h8; } cvt8;

#define DEV static __device__ __forceinline__

DEV float sigm(float x) { return 1.f / (1.f + __expf(-x)); }
DEV float tanh_fast(float x) {
    x = fminf(15.f, fmaxf(-15.f, x));
    float e = __expf(2.f * x);
    return (e - 1.f) / (e + 1.f);
}

// ---------------- K_eh: embed + edge histograms + waug build ----------------
// blocks 0..255: embed (4 blocks/batch, lgkm-clean inner loop);
// blocks 256..511: hist; 512..1600: waug (read-coalesced).
// waug layout: waug[i*COLS + j*256 + rh]
__global__ __launch_bounds__(256) void k_eh(const int* __restrict__ seq,
                                            const int* __restrict__ p2g,
                                            const float* __restrict__ emb,
                                            const int* __restrict__ u,
                                            const int* __restrict__ v,
                                            const float* __restrict__ ntlw,
                                            const float* __restrict__ ntlv,
                                            const float* __restrict__ ntlb,
                                            float* __restrict__ xg,
                                            int* __restrict__ cu, int* __restrict__ cv,
                                            float* __restrict__ waug) {
    int blk = blockIdx.x;
    int t   = threadIdx.x;
    if (blk >= 512) {
        int gid = (blk - 512) * 256 + t;      // j-fastest: coalesced ntlw reads
        int i   = gid / COLS;
        int rem = gid - i * COLS;
        int rh  = rem / JA;
        int j   = rem - rh * JA;
        float val;
        if (i < 32) val = (j < 32) ? ntlw[((size_t)rh * 32 + i) * 32 + j] : ntlv[rh * 64 + i];
        else        val = (j < 32) ? ntlv[rh * 64 + 32 + j] : ntlb[rh];
        waug[(size_t)i * COLS + j * 256 + rh] = val;   // scattered, L2-absorbed
        return;
    }
    if (blk >= 256) {
        int n = (blk - 256) * 256 + t;
        atomicAdd(&cu[u[n]], 1);
        atomicAdd(&cv[v[n]], 1);
        return;
    }
    // ---- embed: 4 blocks per batch, each covers 128 sequence positions ----
    __shared__ float xgl[G_ * 64];          // 32 KB partial sums
    __shared__ int sl[128], gld[128];
    int b = blk >> 2, part = blk & 3;
    for (int i = t; i < G_ * 64; i += 256) xgl[i] = 0.f;
    if (t < 128) {
        sl[t]  = seq[b * L_ + part * 128 + t];
        gld[t] = p2g[b * L_ + part * 128 + t];
    }
    __syncthreads();
    int d = t & 63, sub = t >> 6;
#pragma unroll
    for (int gg = 0; gg < 2; gg++) {
        int sv[16], gv[16];
#pragma unroll
        for (int k = 0; k < 16; k++) {       // batch LDS reads first (lgkm group)
            sv[k] = sl[sub * 32 + gg * 16 + k];
            gv[k] = gld[sub * 32 + gg * 16 + k];
        }
#pragma unroll
        for (int k = 0; k < 16; k++)         // then pure-vm loads + ds atomics
            atomicAdd(&xgl[gv[k] * 64 + d], emb[(size_t)sv[k] * 64 + d]);
    }
    __syncthreads();
    for (int i = t; i < G_ * 64; i += 256)   // flush partials (xg pre-zeroed)
        atomicAdd(&xg[(size_t)b * G_ * 64 + i], xgl[i]);
}

// ---------------- K_pre: input-gate GEMM (scalar x broadcast) + scan --------
__global__ __launch_bounds__(256) void k_pre(const float* __restrict__ xg,
                                             const float* __restrict__ wihf,
                                             const float* __restrict__ bihf,
                                             const float* __restrict__ bhhf,
                                             const float* __restrict__ wihb,
                                             const float* __restrict__ bihb,
                                             const float* __restrict__ bhhb,
                                             float* __restrict__ pre,
                                             const int* __restrict__ cu,
                                             int* __restrict__ ustart,
                                             int* __restrict__ ucursor) {
    int blk = blockIdx.x;
    int t   = threadIdx.x;
    if (blk == 512) {
        __shared__ int ps[256];
        int base = t * 8, run = 0;
        int c[8], loc[8];
#pragma unroll
        for (int i = 0; i < 8; i++) c[i] = cu[base + i];
#pragma unroll
        for (int i = 0; i < 8; i++) { loc[i] = run; run += c[i]; }
        ps[t] = run;
        __syncthreads();
        for (int off = 1; off < 256; off <<= 1) {
            int a = (t >= off) ? ps[t - off] : 0;
            __syncthreads();
            ps[t] += a;
            __syncthreads();
        }
        int ex = ps[t] - run;
#pragma unroll
        for (int i = 0; i < 8; i++) { ustart[base + i] = ex + loc[i]; ucursor[base + i] = ex + loc[i]; }
        if (t == 255) ustart[2048] = E_;
        return;
    }
    int dir = blk >> 8;
    const float* wih = dir ? wihb : wihf;
    float bias = dir ? (bihb[t] + bhhb[t]) : (bihf[t] + bhhf[t]);
    int r0 = (blk & 255) * 32;

    float4 wv[16];
#pragma unroll
    for (int c = 0; c < 16; c++) wv[c] = ((const float4*)(wih + t * 64))[c];

#pragma unroll 2
    for (int ml = 0; ml < 32; ml++) {
        const float* xr = xg + (size_t)(r0 + ml) * 64;   // wave-uniform -> s_load
        float acc = bias;
#pragma unroll
        for (int c = 0; c < 16; c++) {
            float x0 = xr[4 * c], x1 = xr[4 * c + 1], x2 = xr[4 * c + 2], x3 = xr[4 * c + 3];
            acc += x0 * wv[c].x + x1 * wv[c].y + x2 * wv[c].z + x3 * wv[c].w;
        }
        pre[((size_t)dir * 8192 + r0 + ml) * 256 + t] = acc;   // gate-major, coalesced
    }
}

// ---------------- K_lstm: one WAVE per recurrence, zero LDS / zero barrier --
// Lane e owns hidden unit e: holds whh rows {e, 64+e, 128+e, 192+e} in VGPRs
// (~256 regs; gfx950 unified 512-reg file, no spill), computes all 4 gates
// locally, broadcasts h via v_readlane (SGPR operand reused by 4 FMAs, packed
// as float2 -> v_pk_fma_f32). pre is read from global with a 1-step register
// prefetch; h stored coalesced straight to hgrp. No __syncthreads anywhere.
// blocks 128..1151: edge counting-sort rider (64 threads each).
__global__ __launch_bounds__(64, 1) void k_lstm(const float* __restrict__ pre,
                                                const float* __restrict__ whh_f,
                                                const float* __restrict__ whh_b,
                                                float* __restrict__ hgrp,
                                                const int* __restrict__ u,
                                                const int* __restrict__ v,
                                                int* __restrict__ ucursor,
                                                int2* __restrict__ eonv) {
    int blk = blockIdx.x;
    int e   = threadIdx.x;               // 0..63 = hidden unit
    if (blk >= 128) {
        int n = (blk - 128) * 64 + e;
        int pos = atomicAdd(&ucursor[u[n]], 1);
        eonv[pos] = make_int2(n, v[n]);
        return;
    }
    int dir = blk >> 6;
    int b   = blk & 63;
    const float* whh     = dir ? whh_b : whh_f;
    const float* prebase = pre + ((size_t)dir * 8192 + (size_t)b * G_) * 256;
    float* hout = hgrp + (size_t)b * G_ * 128 + dir * 64 + e;

    // ---- load 4 whh rows (gates i,f,g,o for unit e), packed in float2 pairs
    v2f32 w01[64], w23[64];
    {
        const float4* pi = (const float4*)(whh + (size_t)(0 * 64 + e) * 64);
        const float4* pf = (const float4*)(whh + (size_t)(1 * 64 + e) * 64);
        const float4* pg = (const float4*)(whh + (size_t)(2 * 64 + e) * 64);
        const float4* po = (const float4*)(whh + (size_t)(3 * 64 + e) * 64);
#pragma unroll
        for (int c = 0; c < 16; c++) {
            float4 a = pi[c], f = pf[c], g = pg[c], o = po[c];
            w01[4 * c + 0] = (v2f32){a.x, f.x};
            w01[4 * c + 1] = (v2f32){a.y, f.y};
            w01[4 * c + 2] = (v2f32){a.z, f.z};
            w01[4 * c + 3] = (v2f32){a.w, f.w};
            w23[4 * c + 0] = (v2f32){g.x, o.x};
            w23[4 * c + 1] = (v2f32){g.y, o.y};
            w23[4 * c + 2] = (v2f32){g.z, o.z};
            w23[4 * c + 3] = (v2f32){g.w, o.w};
        }
    }

    float h = 0.f, creg = 0.f;
    // prime the pre-activation prefetch
    int sfirst = dir ? (G_ - 1) : 0;
    float p0 = prebase[(size_t)sfirst * 256 + e];
    float p1 = prebase[(size_t)sfirst * 256 + 64 + e];
    float p2 = prebase[(size_t)sfirst * 256 + 128 + e];
    float p3 = prebase[(size_t)sfirst * 256 + 192 + e];

#pragma unroll 1
    for (int step = 0; step < G_; step++) {
        int s  = dir ? (G_ - 1 - step) : step;
        int sn = dir ? (s - 1 < 0 ? 0 : s - 1) : (s + 1 > G_ - 1 ? G_ - 1 : s + 1);
        float q0 = p0, q1 = p1, q2 = p2, q3 = p3;
        {   // issue next step's loads now; consumed next iteration (latency
            // hidden under the ~500-cycle matvec below)
            const float* pn = prebase + (size_t)sn * 256;
            p0 = pn[e]; p1 = pn[64 + e]; p2 = pn[128 + e]; p3 = pn[192 + e];
        }
        v2f32 a01 = {q0, q1};
        v2f32 a23 = {q2, q3};
#pragma unroll
        for (int j = 0; j < 64; j++) {
            float hv = __int_as_float(__builtin_amdgcn_readlane(__float_as_int(h), j));
            v2f32 hv2 = {hv, hv};
            a01 += w01[j] * hv2;
            a23 += w23[j] * hv2;
        }
        float ai = sigm(a01.x);
        float af = sigm(a01.y);
        float ag = tanh_fast(a23.x);
        float ao = sigm(a23.y);
        creg = af * creg + ai * ag;
        h    = ao * tanh_fast(creg);
        hout[(size_t)s * 128] = h;       // coalesced 256B store, fire-and-forget
    }
}

// ---------------- K_gp: gather + projections + BN partial stats (fused) -----
__global__ __launch_bounds__(256) void k_gp(const int* __restrict__ idx,
                                            const int* __restrict__ p2g,
                                            const float* __restrict__ hgrp,
                                            const int* __restrict__ cu,
                                            const int* __restrict__ cv,
                                            const float* __restrict__ wsrc,
                                            const float* __restrict__ bsrc,
                                            const float* __restrict__ wdst,
                                            const float* __restrict__ bdst,
                                            float* __restrict__ Ps, float* __restrict__ Pd,
                                            float* __restrict__ bn_raw) {
    __shared__ __align__(16) float hsl[8][128];
    __shared__ float red[256];
    int m0 = blockIdx.x * 8;
    int t  = threadIdx.x;
    int d = t & 127, mh = t >> 7;
#pragma unroll
    for (int rep = 0; rep < 4; rep++) {
        int ml = rep * 2 + mh;
        int m  = m0 + ml;
        int b  = m >> 5;
        float acc = 0.f;
#pragma unroll
        for (int k = 0; k < 8; k++) {
            int l = idx[m * 8 + k];
            int g = p2g[b * L_ + l];
            acc += hgrp[((size_t)b * G_ + g) * 128 + d];
        }
        hsl[ml][d] = acc;
    }
    __syncthreads();
    int ml = t >> 5, o = t & 31;
    int m  = m0 + ml;
    const float4* hp = (const float4*)&hsl[ml][0];
    float cw_u = (float)cu[m], cw_v = (float)cv[m];
#pragma unroll 1
    for (int side = 0; side < 2; side++) {
        const float* W = side ? wdst : wsrc;
        float4 wr[32];
#pragma unroll
        for (int c = 0; c < 32; c++) wr[c] = ((const float4*)(W + (size_t)o * 128))[c];
        float acc = side ? bdst[o] : bsrc[o];
#pragma unroll
        for (int c = 0; c < 32; c++) {
            float4 h4 = hp[c];
            acc += h4.x * wr[c].x + h4.y * wr[c].y + h4.z * wr[c].z + h4.w * wr[c].w;
        }
        (side ? Pd : Ps)[(size_t)m * 32 + o] = acc;
        float cw = side ? cw_v : cw_u;
        red[t] = cw * acc;
        __syncthreads();
        if (t < 32) {
            float s = 0.f;
#pragma unroll
            for (int i = 0; i < 8; i++) s += red[i * 32 + t];
            atomicAdd(&bn_raw[side * 64 + t], s);
        }
        __syncthreads();
        red[t] = cw * acc * acc;
        __syncthreads();
        if (t < 32) {
            float s = 0.f;
#pragma unroll
            for (int i = 0; i < 8; i++) s += red[i * 32 + t];
            atomicAdd(&bn_raw[side * 64 + 32 + t], s);
        }
        __syncthreads();
    }
}

// ---------------- K_prep: BN-normalize; build hsaugT[i][m] and htp (f16x2) --
__global__ __launch_bounds__(256) void k_prep(const float* __restrict__ Ps,
                                              const float* __restrict__ Pd,
                                              const float* __restrict__ bn_raw,
                                              const float* __restrict__ gs,
                                              const float* __restrict__ bes,
                                              const float* __restrict__ gd,
                                              const float* __restrict__ bed,
                                              float* __restrict__ hsaugT,
                                              v2h* __restrict__ htp) {
    int blk = blockIdx.x;
    int t   = threadIdx.x;
    constexpr float invE = 1.f / (float)E_;
    if (blk < 264) {                        // 264*256 = 33*2048
        int gid = blk * 256 + t;
        int c = gid >> 11;                   // 0..32
        int m = gid & 2047;
        float val = 1.f;
        if (c < 32) {
            float mu  = bn_raw[c] * invE;
            float isd = rsqrtf(bn_raw[32 + c] * invE - mu * mu + 1e-5f);
            val = gs[c] * (Ps[(size_t)m * 32 + c] - mu) * isd + bes[c];
        }
        hsaugT[(size_t)c * 2048 + m] = val;   // coalesced over m
        return;
    }
    int gid = (blk - 264) * 256 + t;         // 128*256 = 2048*16
    int m  = gid >> 4;
    int jp = gid & 15;
    int j0 = 2 * jp, j1 = 2 * jp + 1;
    float mu0  = bn_raw[64 + j0] * invE;
    float isd0 = rsqrtf(bn_raw[96 + j0] * invE - mu0 * mu0 + 1e-5f);
    float mu1  = bn_raw[64 + j1] * invE;
    float isd1 = rsqrtf(bn_raw[96 + j1] * invE - mu1 * mu1 + 1e-5f);
    float h0 = gd[j0] * (Pd[(size_t)m * 32 + j0] - mu0) * isd0 + bed[j0];
    float h1 = gd[j1] * (Pd[(size_t)m * 32 + j1] - mu1) * isd1 + bed[j1];
    v2h p;
    p.x = (_Float16)h0; p.y = (_Float16)h1;
    htp[gid] = p;                            // coalesced
}

// ---------------- K_agemm: w in REGISTERS (fully-unrolled i), low block count
// grid (16 m-slices, 17 jp). Each block: load w once, loop 16 chunks x 8 m.
__global__ __launch_bounds__(256, 1) void k_agemm(const float* __restrict__ hsaugT,
                                                  const float* __restrict__ waug,
                                                  v2h* __restrict__ Ah,
                                                  float* __restrict__ A32) {
    int ms = blockIdx.x;                   // 16 slices of 128 m
    int jp = blockIdx.y;                   // 0..16
    int t  = threadIdx.x;                  // rh
    int mbase = ms * 128;
    if (jp < 16) {
        float w0[JA], w1[JA];
#pragma unroll
        for (int i = 0; i < JA; i++) {      // FULL unroll: static indices -> registers
            w0[i] = waug[(size_t)i * COLS + (2 * jp) * 256 + t];
            w1[i] = waug[(size_t)i * COLS + (2 * jp + 1) * 256 + t];
        }
#pragma unroll 1
        for (int ch = 0; ch < 16; ch++) {
            int m0 = mbase + ch * 8;
            float acc0[8], acc1[8];
#pragma unroll
            for (int ml = 0; ml < 8; ml++) { acc0[ml] = 0.f; acc1[ml] = 0.f; }
#pragma unroll
            for (int i = 0; i < JA; i++) {
                const float* hr = hsaugT + (size_t)i * 2048 + m0;   // s_load dwordx8
#pragma unroll
                for (int ml = 0; ml < 8; ml++) {
                    float hv = hr[ml];
                    acc0[ml] += hv * w0[i];
                    acc1[ml] += hv * w1[i];
                }
            }
#pragma unroll
            for (int ml = 0; ml < 8; ml++) {
                v2h p;
                p.x = (_Float16)acc0[ml]; p.y = (_Float16)acc1[ml];
                Ah[(size_t)(m0 + ml) * 4096 + jp * 256 + t] = p;
            }
        }
    } else {
        float w2[JA];
#pragma unroll
        for (int i = 0; i < JA; i++) w2[i] = waug[(size_t)i * COLS + 32 * 256 + t];
#pragma unroll 1
        for (int ch = 0; ch < 16; ch++) {
            int m0 = mbase + ch * 8;
            float acc[8];
#pragma unroll
            for (int ml = 0; ml < 8; ml++) acc[ml] = 0.f;
#pragma unroll
            for (int i = 0; i < JA; i++) {
                const float* hr = hsaugT + (size_t)i * 2048 + m0;
#pragma unroll
                for (int ml = 0; ml < 8; ml++) acc[ml] += hr[ml] * w2[i];
            }
#pragma unroll
            for (int ml = 0; ml < 8; ml++)
                A32[(size_t)(m0 + ml) * 256 + t] = acc[ml];
        }
    }
}

// ---------------- K_z: MFMA edge-tile GEMM + replicated LN-stat atomics -----
__global__ __launch_bounds__(256) void k_z(const unsigned int* __restrict__ Ah,
                                           const float* __restrict__ A32,
                                           const uint4* __restrict__ htp4,
                                           const int* __restrict__ ustart,
                                           const int2* __restrict__ eonv,
                                           _Float16* __restrict__ zh,
                                           float* __restrict__ zsumR,
                                           float* __restrict__ zsqR) {
    int t    = threadIdx.x;
    int lane = t & 63;
    int uu   = blockIdx.x * 4 + (t >> 6);
    int l15  = lane & 15, quad = lane >> 4;

    // B fragments for all 16 rh-tiles (64 VGPRs, loaded once per u)
    uint4 bf[16];
#pragma unroll
    for (int nt = 0; nt < 16; nt++) {
        const unsigned int* bp = Ah + (size_t)uu * 4096 + (quad * 4) * 256 + nt * 16 + l15;
        bf[nt].x = bp[0]; bf[nt].y = bp[256]; bf[nt].z = bp[512]; bf[nt].w = bp[768];
    }
    float a32[16];
#pragma unroll
    for (int nt = 0; nt < 16; nt++) a32[nt] = A32[(size_t)uu * 256 + nt * 16 + l15];

    float s1[16], s2[16];
#pragma unroll
    for (int nt = 0; nt < 16; nt++) { s1[nt] = 0.f; s2[nt] = 0.f; }

    int e0 = ustart[uu], e1 = ustart[uu + 1];
    for (int base = e0; base < e1; base += 16) {
        int ei = min(base + l15, e1 - 1);          // clamp: duplicate rows are idempotent
        int2 q = eonv[ei];
        uint4 afu = htp4[(size_t)q.y * 4 + quad];  // A-frag: vector dwordx4, no broadcast
        cvt8 ac; ac.u4 = afu;
        int nrow[4], valid[4];
#pragma unroll
        for (int r = 0; r < 4; r++) {
            int er = quad * 4 + r;
            nrow[r]  = __builtin_amdgcn_ds_bpermute(er << 2, q.x);   // n of D-row er
            valid[r] = (base + er) < e1;
        }
#pragma unroll
        for (int nt = 0; nt < 16; nt++) {
            cvt8 bc; bc.u4 = bf[nt];
            v4f acc = { a32[nt], a32[nt], a32[nt], a32[nt] };
            acc = __builtin_amdgcn_mfma_f32_16x16x32_f16(ac.h8, bc.h8, acc, 0, 0, 0);
#pragma unroll
            for (int r = 0; r < 4; r++) {
                if (valid[r]) {
                    float z = acc[r];
                    zh[(size_t)nrow[r] * 256 + nt * 16 + l15] = (_Float16)z;
                    s1[nt] += z; s2[nt] += z * z;
                }
            }
        }
    }
    int rep = (blockIdx.x & (NREP - 1)) * 256;     // replica slice (atomic decontention)
#pragma unroll
    for (int nt = 0; nt < 16; nt++) {
        float a = s1[nt], b = s2[nt];
        a += __shfl_xor(a, 16); a += __shfl_xor(a, 32);
        b += __shfl_xor(b, 16); b += __shfl_xor(b, 32);
        if (quad == 0) {
            atomicAdd(&zsumR[rep + nt * 16 + l15], a);
            atomicAdd(&zsqR[rep + nt * 16 + l15], b);
        }
    }
}

// ---------------- K_logit: LN (replica-sum inline) + tanh + contract --------
__global__ __launch_bounds__(256) void k_logit(const _Float16* __restrict__ zh,
                                               const float* __restrict__ zsumR,
                                               const float* __restrict__ zsqR,
                                               const float* __restrict__ ntlu,
                                               const float* __restrict__ ntlg,
                                               const float* __restrict__ ntlbe,
                                               float* __restrict__ out) {
    int t  = threadIdx.x;                 // rh = r*16+h
    int n0 = blockIdx.x * 16;
    float su = 0.f, sq = 0.f;
#pragma unroll
    for (int r = 0; r < NREP; r++) {
        su += zsumR[r * 256 + t];
        sq += zsqR[r * 256 + t];
    }
    float mu  = su / (float)E_;
    float var = sq / (float)E_ - mu * mu;
    float isd = rsqrtf(var + 1e-5f);
    float g   = ntlg[t],  be  = ntlbe[t];
    float uw  = ntlu[t];
    float zv[16];
#pragma unroll
    for (int nl = 0; nl < 16; nl++)
        zv[nl] = (float)zh[(size_t)(n0 + nl) * 256 + t];
#pragma unroll 1
    for (int nl = 0; nl < 16; nl++) {
        float zn  = g * (zv[nl] - mu) * isd + be;
        float val = uw * tanh_fast(zn);
        val += __shfl_xor(val, 1);
        val += __shfl_xor(val, 2);
        val += __shfl_xor(val, 4);
        val += __shfl_xor(val, 8);
        if ((t & 15) == 0) out[(size_t)(n0 + nl) * 16 + (t >> 4)] = val;
    }
}

// ============================ host side =====================================
extern "C" void kernel_launch(void* const* d_in, const int* in_sizes, int n_in,
                              void* d_out, int out_size, void* d_ws, size_t ws_size,
                              hipStream_t stream) {
    const int*   seq   = (const int*)d_in[0];
    const int*   p2g   = (const int*)d_in[1];
    const int*   idx   = (const int*)d_in[2];
    const int*   u     = (const int*)d_in[3];
    const int*   v     = (const int*)d_in[4];
    const float* emb   = (const float*)d_in[5];
    const float* wihf  = (const float*)d_in[6];
    const float* whhf  = (const float*)d_in[7];
    const float* bihf  = (const float*)d_in[8];
    const float* bhhf  = (const float*)d_in[9];
    const float* wihb  = (const float*)d_in[10];
    const float* whhb  = (const float*)d_in[11];
    const float* bihb  = (const float*)d_in[12];
    const float* bhhb  = (const float*)d_in[13];
    const float* wsrc  = (const float*)d_in[14];
    const float* bsrc  = (const float*)d_in[15];
    const float* wdst  = (const float*)d_in[16];
    const float* bdst  = (const float*)d_in[17];
    const float* gs    = (const float*)d_in[18];
    const float* bes   = (const float*)d_in[19];
    const float* gd    = (const float*)d_in[20];
    const float* bed   = (const float*)d_in[21];
    const float* ntlw  = (const float*)d_in[22];
    const float* ntlv  = (const float*)d_in[23];
    const float* ntlb  = (const float*)d_in[24];
    const float* ntlu  = (const float*)d_in[25];
    const float* ntlg  = (const float*)d_in[26];
    const float* ntlbe = (const float*)d_in[27];
    float* out = (float*)d_out;

    char* ws = (char*)d_ws;
    size_t off = 0;
    auto take = [&](size_t bytes) -> char* {
        char* p = ws + off;
        off = (off + bytes + 255) & ~(size_t)255;
        return p;
    };
    // zeroed region (contiguous, one memset)
    int*   cnt_u  = (int*)  take(2048 * 4);
    int*   cnt_v  = (int*)  take(2048 * 4);
    float* zsumR  = (float*)take((size_t)NREP * 256 * 4);
    float* zsqR   = (float*)take((size_t)NREP * 256 * 4);
    float* bn_raw = (float*)take(128 * 4);
    float* x_grp  = (float*)take((size_t)B_ * G_ * 64 * 4);   // accumulated via atomics
    size_t zero_bytes = off;
    // rest
    int*   ucursor = (int*)  take(2048 * 4);
    int*   ustart  = (int*)  take(2049 * 4);
    int2*  eonv    = (int2*) take((size_t)E_ * 8);
    float* pre     = (float*)take((size_t)2 * 8192 * 256 * 4);
    float* hgrp    = (float*)take((size_t)B_ * G_ * 128 * 4);
    float* Psrc    = (float*)take((size_t)M_ * 32 * 4);
    float* Pdst    = (float*)take((size_t)M_ * 32 * 4);
    float* hsaugT  = (float*)take((size_t)36 * 2048 * 4);
    v2h*   htp     = (v2h*)  take((size_t)M_ * 16 * 4);
    float* waug    = (float*)take((size_t)JA * COLS * 4);
    v2h*   Ah      = (v2h*)  take((size_t)M_ * 4096 * 4);
    float* A32     = (float*)take((size_t)M_ * 256 * 4);
    _Float16* zbuf = (_Float16*)take((size_t)E_ * 256 * 2);
    (void)ws_size; (void)in_sizes; (void)n_in; (void)out_size;

    hipMemsetAsync(d_ws, 0, zero_bytes, stream);

    k_eh<<<512 + 1089, 256, 0, stream>>>(seq, p2g, emb, u, v, ntlw, ntlv, ntlb,
                                         x_grp, cnt_u, cnt_v, waug);
    k_pre<<<513, 256, 0, stream>>>(x_grp, wihf, bihf, bhhf, wihb, bihb, bhhb, pre,
                                   cnt_u, ustart, ucursor);
    k_lstm<<<128 + E_ / 64, 64, 0, stream>>>(pre, whhf, whhb, hgrp, u, v, ucursor, eonv);
    k_gp<<<M_ / 8, 256, 0, stream>>>(idx, p2g, hgrp, cnt_u, cnt_v,
                                     wsrc, bsrc, wdst, bdst, Psrc, Pdst, bn_raw);
    k_prep<<<392, 256, 0, stream>>>(Psrc, Pdst, bn_raw, gs, bes, gd, bed, hsaugT, htp);
    k_agemm<<<dim3(16, 17), 256, 0, stream>>>(hsaugT, waug, Ah, A32);
    k_z<<<512, 256, 0, stream>>>((const unsigned int*)Ah, A32, (const uint4*)htp,
                                 ustart, eonv, zbuf, zsumR, zsqR);
    k_logit<<<E_ / 16, 256, 0, stream>>>(zbuf, zsumR, zsqR, ntlu, ntlg, ntlbe, out);
}

// Round 2
// 416.508 us; speedup vs baseline: 1.0690x; 1.0690x over previous
//
#include <hip/hip_runtime.h>
#include <hip/hip_bf16.h>
#include <hip/hip_fp16.h>
#include <cstdint>

// Problem constants
constexpr int B_   = 64;
constexpr int L_   = 512;
constexpr int G_   = 128;
constexpr int E_   = 65536;
constexpr int RH   = 256;    // NREL*NHID
constexpr int M_   = 2048;   // B*N distinct nodes
constexpr int JA   = 33;     // augmented j (32 + const-1 slot)
constexpr int COLS = RH * JA;   // 8448
constexpr int NREP = 16;     // LN-stat accumulator replicas (atomic decontention)

typedef _Float16 v2h __attribute__((ext_vector_type(2)));
typedef _Float16 v8h __attribute__((ext_vector_type(8)));
typedef float    v4f __attribute__((ext_vector_type(4)));
typedef float    v2f32 __attribute__((ext_vector_type(2)));
typedef union { uint4 u4; v8h h8; } cvt8;

#define DEV static __device__ __forceinline__

DEV float sigm(float x) { return 1.f / (1.f + __expf(-x)); }
DEV float tanh_fast(float x) {
    x = fminf(15.f, fmaxf(-15.f, x));
    float e = __expf(2.f * x);
    return (e - 1.f) / (e + 1.f);
}

// ---------------- K_eh: embed + edge histograms + waug build ----------------
// blocks 0..255: embed (4 blocks/batch, lgkm-clean inner loop);
// blocks 256..511: hist; 512..1600: waug (read-coalesced).
// waug layout: waug[i*COLS + j*256 + rh]
__global__ __launch_bounds__(256) void k_eh(const int* __restrict__ seq,
                                            const int* __restrict__ p2g,
                                            const float* __restrict__ emb,
                                            const int* __restrict__ u,
                                            const int* __restrict__ v,
                                            const float* __restrict__ ntlw,
                                            const float* __restrict__ ntlv,
                                            const float* __restrict__ ntlb,
                                            float* __restrict__ xg,
                                            int* __restrict__ cu, int* __restrict__ cv,
                                            float* __restrict__ waug) {
    int blk = blockIdx.x;
    int t   = threadIdx.x;
    if (blk >= 512) {
        int gid = (blk - 512) * 256 + t;      // j-fastest: coalesced ntlw reads
        int i   = gid / COLS;
        int rem = gid - i * COLS;
        int rh  = rem / JA;
        int j   = rem - rh * JA;
        float val;
        if (i < 32) val = (j < 32) ? ntlw[((size_t)rh * 32 + i) * 32 + j] : ntlv[rh * 64 + i];
        else        val = (j < 32) ? ntlv[rh * 64 + 32 + j] : ntlb[rh];
        waug[(size_t)i * COLS + j * 256 + rh] = val;   // scattered, L2-absorbed
        return;
    }
    if (blk >= 256) {
        int n = (blk - 256) * 256 + t;
        atomicAdd(&cu[u[n]], 1);
        atomicAdd(&cv[v[n]], 1);
        return;
    }
    // ---- embed: 4 blocks per batch, each covers 128 sequence positions ----
    __shared__ float xgl[G_ * 64];          // 32 KB partial sums
    __shared__ int sl[128], gld[128];
    int b = blk >> 2, part = blk & 3;
    for (int i = t; i < G_ * 64; i += 256) xgl[i] = 0.f;
    if (t < 128) {
        sl[t]  = seq[b * L_ + part * 128 + t];
        gld[t] = p2g[b * L_ + part * 128 + t];
    }
    __syncthreads();
    int d = t & 63, sub = t >> 6;
#pragma unroll
    for (int gg = 0; gg < 2; gg++) {
        int sv[16], gv[16];
#pragma unroll
        for (int k = 0; k < 16; k++) {       // batch LDS reads first (lgkm group)
            sv[k] = sl[sub * 32 + gg * 16 + k];
            gv[k] = gld[sub * 32 + gg * 16 + k];
        }
#pragma unroll
        for (int k = 0; k < 16; k++)         // then pure-vm loads + ds atomics
            atomicAdd(&xgl[gv[k] * 64 + d], emb[(size_t)sv[k] * 64 + d]);
    }
    __syncthreads();
    for (int i = t; i < G_ * 64; i += 256)   // flush partials (xg pre-zeroed)
        atomicAdd(&xg[(size_t)b * G_ * 64 + i], xgl[i]);
}

// ---------------- K_pre: input-gate GEMM (scalar x broadcast) + scan --------
__global__ __launch_bounds__(256) void k_pre(const float* __restrict__ xg,
                                             const float* __restrict__ wihf,
                                             const float* __restrict__ bihf,
                                             const float* __restrict__ bhhf,
                                             const float* __restrict__ wihb,
                                             const float* __restrict__ bihb,
                                             const float* __restrict__ bhhb,
                                             float* __restrict__ pre,
                                             const int* __restrict__ cu,
                                             int* __restrict__ ustart,
                                             int* __restrict__ ucursor) {
    int blk = blockIdx.x;
    int t   = threadIdx.x;
    if (blk == 512) {
        __shared__ int ps[256];
        int base = t * 8, run = 0;
        int c[8], loc[8];
#pragma unroll
        for (int i = 0; i < 8; i++) c[i] = cu[base + i];
#pragma unroll
        for (int i = 0; i < 8; i++) { loc[i] = run; run += c[i]; }
        ps[t] = run;
        __syncthreads();
        for (int off = 1; off < 256; off <<= 1) {
            int a = (t >= off) ? ps[t - off] : 0;
            __syncthreads();
            ps[t] += a;
            __syncthreads();
        }
        int ex = ps[t] - run;
#pragma unroll
        for (int i = 0; i < 8; i++) { ustart[base + i] = ex + loc[i]; ucursor[base + i] = ex + loc[i]; }
        if (t == 255) ustart[2048] = E_;
        return;
    }
    int dir = blk >> 8;
    const float* wih = dir ? wihb : wihf;
    float bias = dir ? (bihb[t] + bhhb[t]) : (bihf[t] + bhhf[t]);
    int r0 = (blk & 255) * 32;

    float4 wv[16];
#pragma unroll
    for (int c = 0; c < 16; c++) wv[c] = ((const float4*)(wih + t * 64))[c];

#pragma unroll 2
    for (int ml = 0; ml < 32; ml++) {
        const float* xr = xg + (size_t)(r0 + ml) * 64;   // wave-uniform -> s_load
        float acc = bias;
#pragma unroll
        for (int c = 0; c < 16; c++) {
            float x0 = xr[4 * c], x1 = xr[4 * c + 1], x2 = xr[4 * c + 2], x3 = xr[4 * c + 3];
            acc += x0 * wv[c].x + x1 * wv[c].y + x2 * wv[c].z + x3 * wv[c].w;
        }
        pre[((size_t)dir * 8192 + r0 + ml) * 256 + t] = acc;   // gate-major, coalesced
    }
}

// ---------------- K_lstm: one WAVE per recurrence, zero LDS / zero barrier --
// Lane e owns hidden unit e. Weight residency is split EXPLICITLY across the
// two register files: gates i,f (64 v2f32) in arch VGPRs (v_pk_fma_f32);
// gates g,o (128 floats) in AGPRs via "a"-constrained inline asm (compiler
// cannot scratch-spill these). Per step each g/o weight is consumed by a
// paired volatile {v_accvgpr_read_b32 ; v_fmac_f32} so reads never pile up.
// pre is read with a 2-deep register prefetch (L3 latency ~600cy < 2 steps).
// blocks 128..1151: edge counting-sort rider.
__global__ __launch_bounds__(64, 1) void k_lstm(const float* __restrict__ pre,
                                                const float* __restrict__ whh_f,
                                                const float* __restrict__ whh_b,
                                                float* __restrict__ hgrp,
                                                const int* __restrict__ u,
                                                const int* __restrict__ v,
                                                int* __restrict__ ucursor,
                                                int2* __restrict__ eonv) {
    int blk = blockIdx.x;
    int e   = threadIdx.x;               // 0..63 = hidden unit
    if (blk >= 128) {
        int n = (blk - 128) * 64 + e;
        int pos = atomicAdd(&ucursor[u[n]], 1);
        eonv[pos] = make_int2(n, v[n]);
        return;
    }
    int dir = blk >> 6;
    int b   = blk & 63;
    const float* whh     = dir ? whh_b : whh_f;
    const float* prebase = pre + ((size_t)dir * 8192 + (size_t)b * G_) * 256;
    float* hout = hgrp + (size_t)b * G_ * 128 + dir * 64 + e;

    // ---- i,f rows packed into VGPR pairs; g,o rows into AGPRs -------------
    v2f32 w01[64];
    float awg[64], awo[64];              // AGPR-resident (asm "a" class)
    {
        const float4* pi = (const float4*)(whh + (size_t)(0 * 64 + e) * 64);
        const float4* pf = (const float4*)(whh + (size_t)(1 * 64 + e) * 64);
        const float4* pg = (const float4*)(whh + (size_t)(2 * 64 + e) * 64);
        const float4* po = (const float4*)(whh + (size_t)(3 * 64 + e) * 64);
#pragma unroll
        for (int c = 0; c < 16; c++) {
            float4 a = pi[c], f = pf[c], g = pg[c], o = po[c];
            w01[4 * c + 0] = (v2f32){a.x, f.x};
            w01[4 * c + 1] = (v2f32){a.y, f.y};
            w01[4 * c + 2] = (v2f32){a.z, f.z};
            w01[4 * c + 3] = (v2f32){a.w, f.w};
            asm("v_accvgpr_write_b32 %0, %1" : "=a"(awg[4 * c + 0]) : "v"(g.x));
            asm("v_accvgpr_write_b32 %0, %1" : "=a"(awg[4 * c + 1]) : "v"(g.y));
            asm("v_accvgpr_write_b32 %0, %1" : "=a"(awg[4 * c + 2]) : "v"(g.z));
            asm("v_accvgpr_write_b32 %0, %1" : "=a"(awg[4 * c + 3]) : "v"(g.w));
            asm("v_accvgpr_write_b32 %0, %1" : "=a"(awo[4 * c + 0]) : "v"(o.x));
            asm("v_accvgpr_write_b32 %0, %1" : "=a"(awo[4 * c + 1]) : "v"(o.y));
            asm("v_accvgpr_write_b32 %0, %1" : "=a"(awo[4 * c + 2]) : "v"(o.z));
            asm("v_accvgpr_write_b32 %0, %1" : "=a"(awo[4 * c + 3]) : "v"(o.w));
        }
    }

    float h = 0.f, creg = 0.f;

    // ---- 2-deep prefetch of pre-activations (static stage registers) -----
    int s0i = dir ? (G_ - 1) : 0;
    int s1i = dir ? (G_ - 2) : 1;
    float q0 = prebase[(size_t)s0i * 256 + e];
    float q1 = prebase[(size_t)s0i * 256 + 64 + e];
    float q2 = prebase[(size_t)s0i * 256 + 128 + e];
    float q3 = prebase[(size_t)s0i * 256 + 192 + e];
    float r0 = prebase[(size_t)s1i * 256 + e];
    float r1 = prebase[(size_t)s1i * 256 + 64 + e];
    float r2 = prebase[(size_t)s1i * 256 + 128 + e];
    float r3 = prebase[(size_t)s1i * 256 + 192 + e];

#pragma unroll 1
    for (int step = 0; step < G_; step++) {
        int s  = dir ? (G_ - 1 - step) : step;
        int t2 = (step + 2 < G_) ? step + 2 : G_ - 1;
        int s2 = dir ? (G_ - 1 - t2) : t2;
        // issue loads for step+2 now (consumed 2 iterations later)
        const float* pn = prebase + (size_t)s2 * 256;
        float n0 = pn[e], n1 = pn[64 + e], n2 = pn[128 + e], n3 = pn[192 + e];

        // ---- matvec: 4-way split accumulator chains -----------------------
        v2f32 acc01[4];
        float accg[4], acco[4];
        acc01[0] = (v2f32){q0, q1};
        acc01[1] = (v2f32){0.f, 0.f};
        acc01[2] = (v2f32){0.f, 0.f};
        acc01[3] = (v2f32){0.f, 0.f};
        accg[0] = q2; accg[1] = 0.f; accg[2] = 0.f; accg[3] = 0.f;
        acco[0] = q3; acco[1] = 0.f; acco[2] = 0.f; acco[3] = 0.f;
#pragma unroll
        for (int j = 0; j < 64; j++) {
            float hv = __int_as_float(__builtin_amdgcn_readlane(__float_as_int(h), j));
            int cc = j & 3;
            v2f32 hv2 = {hv, hv};
            acc01[cc] += w01[j] * hv2;
            float tg, to;
            asm volatile("v_accvgpr_read_b32 %1, %2\n\t"
                         "v_fmac_f32 %0, %3, %1"
                         : "+v"(accg[cc]), "=&v"(tg)
                         : "a"(awg[j]), "s"(hv));
            asm volatile("v_accvgpr_read_b32 %1, %2\n\t"
                         "v_fmac_f32 %0, %3, %1"
                         : "+v"(acco[cc]), "=&v"(to)
                         : "a"(awo[j]), "s"(hv));
        }
        v2f32 s01 = (acc01[0] + acc01[1]) + (acc01[2] + acc01[3]);
        float sg  = (accg[0] + accg[1]) + (accg[2] + accg[3]);
        float so  = (acco[0] + acco[1]) + (acco[2] + acco[3]);

        float ai = sigm(s01.x);
        float af = sigm(s01.y);
        float ag = tanh_fast(sg);
        float ao = sigm(so);
        creg = af * creg + ai * ag;
        h    = ao * tanh_fast(creg);
        hout[(size_t)s * 128] = h;       // coalesced 256B store, fire-and-forget

        // rotate prefetch stages (pure register renames)
        q0 = r0; q1 = r1; q2 = r2; q3 = r3;
        r0 = n0; r1 = n1; r2 = n2; r3 = n3;
    }
}

// ---------------- K_gp: gather + projections + BN partial stats (fused) -----
__global__ __launch_bounds__(256) void k_gp(const int* __restrict__ idx,
                                            const int* __restrict__ p2g,
                                            const float* __restrict__ hgrp,
                                            const int* __restrict__ cu,
                                            const int* __restrict__ cv,
                                            const float* __restrict__ wsrc,
                                            const float* __restrict__ bsrc,
                                            const float* __restrict__ wdst,
                                            const float* __restrict__ bdst,
                                            float* __restrict__ Ps, float* __restrict__ Pd,
                                            float* __restrict__ bn_raw) {
    __shared__ __align__(16) float hsl[8][128];
    __shared__ float red[256];
    int m0 = blockIdx.x * 8;
    int t  = threadIdx.x;
    int d = t & 127, mh = t >> 7;
#pragma unroll
    for (int rep = 0; rep < 4; rep++) {
        int ml = rep * 2 + mh;
        int m  = m0 + ml;
        int b  = m >> 5;
        float acc = 0.f;
#pragma unroll
        for (int k = 0; k < 8; k++) {
            int l = idx[m * 8 + k];
            int g = p2g[b * L_ + l];
            acc += hgrp[((size_t)b * G_ + g) * 128 + d];
        }
        hsl[ml][d] = acc;
    }
    __syncthreads();
    int ml = t >> 5, o = t & 31;
    int m  = m0 + ml;
    const float4* hp = (const float4*)&hsl[ml][0];
    float cw_u = (float)cu[m], cw_v = (float)cv[m];
#pragma unroll 1
    for (int side = 0; side < 2; side++) {
        const float* W = side ? wdst : wsrc;
        float4 wr[32];
#pragma unroll
        for (int c = 0; c < 32; c++) wr[c] = ((const float4*)(W + (size_t)o * 128))[c];
        float acc = side ? bdst[o] : bsrc[o];
#pragma unroll
        for (int c = 0; c < 32; c++) {
            float4 h4 = hp[c];
            acc += h4.x * wr[c].x + h4.y * wr[c].y + h4.z * wr[c].z + h4.w * wr[c].w;
        }
        (side ? Pd : Ps)[(size_t)m * 32 + o] = acc;
        float cw = side ? cw_v : cw_u;
        red[t] = cw * acc;
        __syncthreads();
        if (t < 32) {
            float s = 0.f;
#pragma unroll
            for (int i = 0; i < 8; i++) s += red[i * 32 + t];
            atomicAdd(&bn_raw[side * 64 + t], s);
        }
        __syncthreads();
        red[t] = cw * acc * acc;
        __syncthreads();
        if (t < 32) {
            float s = 0.f;
#pragma unroll
            for (int i = 0; i < 8; i++) s += red[i * 32 + t];
            atomicAdd(&bn_raw[side * 64 + 32 + t], s);
        }
        __syncthreads();
    }
}

// ---------------- K_prep: BN-normalize; build hsaugT[i][m] and htp (f16x2) --
__global__ __launch_bounds__(256) void k_prep(const float* __restrict__ Ps,
                                              const float* __restrict__ Pd,
                                              const float* __restrict__ bn_raw,
                                              const float* __restrict__ gs,
                                              const float* __restrict__ bes,
                                              const float* __restrict__ gd,
                                              const float* __restrict__ bed,
                                              float* __restrict__ hsaugT,
                                              v2h* __restrict__ htp) {
    int blk = blockIdx.x;
    int t   = threadIdx.x;
    constexpr float invE = 1.f / (float)E_;
    if (blk < 264) {                        // 264*256 = 33*2048
        int gid = blk * 256 + t;
        int c = gid >> 11;                   // 0..32
        int m = gid & 2047;
        float val = 1.f;
        if (c < 32) {
            float mu  = bn_raw[c] * invE;
            float isd = rsqrtf(bn_raw[32 + c] * invE - mu * mu + 1e-5f);
            val = gs[c] * (Ps[(size_t)m * 32 + c] - mu) * isd + bes[c];
        }
        hsaugT[(size_t)c * 2048 + m] = val;   // coalesced over m
        return;
    }
    int gid = (blk - 264) * 256 + t;         // 128*256 = 2048*16
    int m  = gid >> 4;
    int jp = gid & 15;
    int j0 = 2 * jp, j1 = 2 * jp + 1;
    float mu0  = bn_raw[64 + j0] * invE;
    float isd0 = rsqrtf(bn_raw[96 + j0] * invE - mu0 * mu0 + 1e-5f);
    float mu1  = bn_raw[64 + j1] * invE;
    float isd1 = rsqrtf(bn_raw[96 + j1] * invE - mu1 * mu1 + 1e-5f);
    float h0 = gd[j0] * (Pd[(size_t)m * 32 + j0] - mu0) * isd0 + bed[j0];
    float h1 = gd[j1] * (Pd[(size_t)m * 32 + j1] - mu1) * isd1 + bed[j1];
    v2h p;
    p.x = (_Float16)h0; p.y = (_Float16)h1;
    htp[gid] = p;                            // coalesced
}

// ---------------- K_agemm: w in REGISTERS (fully-unrolled i), low block count
// grid (16 m-slices, 17 jp). Each block: load w once, loop 16 chunks x 8 m.
__global__ __launch_bounds__(256, 1) void k_agemm(const float* __restrict__ hsaugT,
                                                  const float* __restrict__ waug,
                                                  v2h* __restrict__ Ah,
                                                  float* __restrict__ A32) {
    int ms = blockIdx.x;                   // 16 slices of 128 m
    int jp = blockIdx.y;                   // 0..16
    int t  = threadIdx.x;                  // rh
    int mbase = ms * 128;
    if (jp < 16) {
        float w0[JA], w1[JA];
#pragma unroll
        for (int i = 0; i < JA; i++) {      // FULL unroll: static indices -> registers
            w0[i] = waug[(size_t)i * COLS + (2 * jp) * 256 + t];
            w1[i] = waug[(size_t)i * COLS + (2 * jp + 1) * 256 + t];
        }
#pragma unroll 1
        for (int ch = 0; ch < 16; ch++) {
            int m0 = mbase + ch * 8;
            float acc0[8], acc1[8];
#pragma unroll
            for (int ml = 0; ml < 8; ml++) { acc0[ml] = 0.f; acc1[ml] = 0.f; }
#pragma unroll
            for (int i = 0; i < JA; i++) {
                const float* hr = hsaugT + (size_t)i * 2048 + m0;   // s_load dwordx8
#pragma unroll
                for (int ml = 0; ml < 8; ml++) {
                    float hv = hr[ml];
                    acc0[ml] += hv * w0[i];
                    acc1[ml] += hv * w1[i];
                }
            }
#pragma unroll
            for (int ml = 0; ml < 8; ml++) {
                v2h p;
                p.x = (_Float16)acc0[ml]; p.y = (_Float16)acc1[ml];
                Ah[(size_t)(m0 + ml) * 4096 + jp * 256 + t] = p;
            }
        }
    } else {
        float w2[JA];
#pragma unroll
        for (int i = 0; i < JA; i++) w2[i] = waug[(size_t)i * COLS + 32 * 256 + t];
#pragma unroll 1
        for (int ch = 0; ch < 16; ch++) {
            int m0 = mbase + ch * 8;
            float acc[8];
#pragma unroll
            for (int ml = 0; ml < 8; ml++) acc[ml] = 0.f;
#pragma unroll
            for (int i = 0; i < JA; i++) {
                const float* hr = hsaugT + (size_t)i * 2048 + m0;
#pragma unroll
                for (int ml = 0; ml < 8; ml++) acc[ml] += hr[ml] * w2[i];
            }
#pragma unroll
            for (int ml = 0; ml < 8; ml++)
                A32[(size_t)(m0 + ml) * 256 + t] = acc[ml];
        }
    }
}

// ---------------- K_z: MFMA edge-tile GEMM + replicated LN-stat atomics -----
__global__ __launch_bounds__(256) void k_z(const unsigned int* __restrict__ Ah,
                                           const float* __restrict__ A32,
                                           const uint4* __restrict__ htp4,
                                           const int* __restrict__ ustart,
                                           const int2* __restrict__ eonv,
                                           _Float16* __restrict__ zh,
                                           float* __restrict__ zsumR,
                                           float* __restrict__ zsqR) {
    int t    = threadIdx.x;
    int lane = t & 63;
    int uu   = blockIdx.x * 4 + (t >> 6);
    int l15  = lane & 15, quad = lane >> 4;

    // B fragments for all 16 rh-tiles (64 VGPRs, loaded once per u)
    uint4 bf[16];
#pragma unroll
    for (int nt = 0; nt < 16; nt++) {
        const unsigned int* bp = Ah + (size_t)uu * 4096 + (quad * 4) * 256 + nt * 16 + l15;
        bf[nt].x = bp[0]; bf[nt].y = bp[256]; bf[nt].z = bp[512]; bf[nt].w = bp[768];
    }
    float a32[16];
#pragma unroll
    for (int nt = 0; nt < 16; nt++) a32[nt] = A32[(size_t)uu * 256 + nt * 16 + l15];

    float s1[16], s2[16];
#pragma unroll
    for (int nt = 0; nt < 16; nt++) { s1[nt] = 0.f; s2[nt] = 0.f; }

    int e0 = ustart[uu], e1 = ustart[uu + 1];
    for (int base = e0; base < e1; base += 16) {
        int ei = min(base + l15, e1 - 1);          // clamp: duplicate rows are idempotent
        int2 q = eonv[ei];
        uint4 afu = htp4[(size_t)q.y * 4 + quad];  // A-frag: vector dwordx4, no broadcast
        cvt8 ac; ac.u4 = afu;
        int nrow[4], valid[4];
#pragma unroll
        for (int r = 0; r < 4; r++) {
            int er = quad * 4 + r;
            nrow[r]  = __builtin_amdgcn_ds_bpermute(er << 2, q.x);   // n of D-row er
            valid[r] = (base + er) < e1;
        }
#pragma unroll
        for (int nt = 0; nt < 16; nt++) {
            cvt8 bc; bc.u4 = bf[nt];
            v4f acc = { a32[nt], a32[nt], a32[nt], a32[nt] };
            acc = __builtin_amdgcn_mfma_f32_16x16x32_f16(ac.h8, bc.h8, acc, 0, 0, 0);
#pragma unroll
            for (int r = 0; r < 4; r++) {
                if (valid[r]) {
                    float z = acc[r];
                    zh[(size_t)nrow[r] * 256 + nt * 16 + l15] = (_Float16)z;
                    s1[nt] += z; s2[nt] += z * z;
                }
            }
        }
    }
    int rep = (blockIdx.x & (NREP - 1)) * 256;     // replica slice (atomic decontention)
#pragma unroll
    for (int nt = 0; nt < 16; nt++) {
        float a = s1[nt], b = s2[nt];
        a += __shfl_xor(a, 16); a += __shfl_xor(a, 32);
        b += __shfl_xor(b, 16); b += __shfl_xor(b, 32);
        if (quad == 0) {
            atomicAdd(&zsumR[rep + nt * 16 + l15], a);
            atomicAdd(&zsqR[rep + nt * 16 + l15], b);
        }
    }
}

// ---------------- K_logit: LN (replica-sum inline) + tanh + contract --------
__global__ __launch_bounds__(256) void k_logit(const _Float16* __restrict__ zh,
                                               const float* __restrict__ zsumR,
                                               const float* __restrict__ zsqR,
                                               const float* __restrict__ ntlu,
                                               const float* __restrict__ ntlg,
                                               const float* __restrict__ ntlbe,
                                               float* __restrict__ out) {
    int t  = threadIdx.x;                 // rh = r*16+h
    int n0 = blockIdx.x * 16;
    float su = 0.f, sq = 0.f;
#pragma unroll
    for (int r = 0; r < NREP; r++) {
        su += zsumR[r * 256 + t];
        sq += zsqR[r * 256 + t];
    }
    float mu  = su / (float)E_;
    float var = sq / (float)E_ - mu * mu;
    float isd = rsqrtf(var + 1e-5f);
    float g   = ntlg[t],  be  = ntlbe[t];
    float uw  = ntlu[t];
    float zv[16];
#pragma unroll
    for (int nl = 0; nl < 16; nl++)
        zv[nl] = (float)zh[(size_t)(n0 + nl) * 256 + t];
#pragma unroll 1
    for (int nl = 0; nl < 16; nl++) {
        float zn  = g * (zv[nl] - mu) * isd + be;
        float val = uw * tanh_fast(zn);
        val += __shfl_xor(val, 1);
        val += __shfl_xor(val, 2);
        val += __shfl_xor(val, 4);
        val += __shfl_xor(val, 8);
        if ((t & 15) == 0) out[(size_t)(n0 + nl) * 16 + (t >> 4)] = val;
    }
}

// ============================ host side =====================================
extern "C" void kernel_launch(void* const* d_in, const int* in_sizes, int n_in,
                              void* d_out, int out_size, void* d_ws, size_t ws_size,
                              hipStream_t stream) {
    const int*   seq   = (const int*)d_in[0];
    const int*   p2g   = (const int*)d_in[1];
    const int*   idx   = (const int*)d_in[2];
    const int*   u     = (const int*)d_in[3];
    const int*   v     = (const int*)d_in[4];
    const float* emb   = (const float*)d_in[5];
    const float* wihf  = (const float*)d_in[6];
    const float* whhf  = (const float*)d_in[7];
    const float* bihf  = (const float*)d_in[8];
    const float* bhhf  = (const float*)d_in[9];
    const float* wihb  = (const float*)d_in[10];
    const float* whhb  = (const float*)d_in[11];
    const float* bihb  = (const float*)d_in[12];
    const float* bhhb  = (const float*)d_in[13];
    const float* wsrc  = (const float*)d_in[14];
    const float* bsrc  = (const float*)d_in[15];
    const float* wdst  = (const float*)d_in[16];
    const float* bdst  = (const float*)d_in[17];
    const float* gs    = (const float*)d_in[18];
    const float* bes   = (const float*)d_in[19];
    const float* gd    = (const float*)d_in[20];
    const float* bed   = (const float*)d_in[21];
    const float* ntlw  = (const float*)d_in[22];
    const float* ntlv  = (const float*)d_in[23];
    const float* ntlb  = (const float*)d_in[24];
    const float* ntlu  = (const float*)d_in[25];
    const float* ntlg  = (const float*)d_in[26];
    const float* ntlbe = (const float*)d_in[27];
    float* out = (float*)d_out;

    char* ws = (char*)d_ws;
    size_t off = 0;
    auto take = [&](size_t bytes) -> char* {
        char* p = ws + off;
        off = (off + bytes + 255) & ~(size_t)255;
        return p;
    };
    // zeroed region (contiguous, one memset)
    int*   cnt_u  = (int*)  take(2048 * 4);
    int*   cnt_v  = (int*)  take(2048 * 4);
    float* zsumR  = (float*)take((size_t)NREP * 256 * 4);
    float* zsqR   = (float*)take((size_t)NREP * 256 * 4);
    float* bn_raw = (float*)take(128 * 4);
    float* x_grp  = (float*)take((size_t)B_ * G_ * 64 * 4);   // accumulated via atomics
    size_t zero_bytes = off;
    // rest
    int*   ucursor = (int*)  take(2048 * 4);
    int*   ustart  = (int*)  take(2049 * 4);
    int2*  eonv    = (int2*) take((size_t)E_ * 8);
    float* pre     = (float*)take((size_t)2 * 8192 * 256 * 4);
    float* hgrp    = (float*)take((size_t)B_ * G_ * 128 * 4);
    float* Psrc    = (float*)take((size_t)M_ * 32 * 4);
    float* Pdst    = (float*)take((size_t)M_ * 32 * 4);
    float* hsaugT  = (float*)take((size_t)36 * 2048 * 4);
    v2h*   htp     = (v2h*)  take((size_t)M_ * 16 * 4);
    float* waug    = (float*)take((size_t)JA * COLS * 4);
    v2h*   Ah      = (v2h*)  take((size_t)M_ * 4096 * 4);
    float* A32     = (float*)take((size_t)M_ * 256 * 4);
    _Float16* zbuf = (_Float16*)take((size_t)E_ * 256 * 2);
    (void)ws_size; (void)in_sizes; (void)n_in; (void)out_size;

    hipMemsetAsync(d_ws, 0, zero_bytes, stream);

    k_eh<<<512 + 1089, 256, 0, stream>>>(seq, p2g, emb, u, v, ntlw, ntlv, ntlb,
                                         x_grp, cnt_u, cnt_v, waug);
    k_pre<<<513, 256, 0, stream>>>(x_grp, wihf, bihf, bhhf, wihb, bihb, bhhb, pre,
                                   cnt_u, ustart, ucursor);
    k_lstm<<<128 + E_ / 64, 64, 0, stream>>>(pre, whhf, whhb, hgrp, u, v, ucursor, eonv);
    k_gp<<<M_ / 8, 256, 0, stream>>>(idx, p2g, hgrp, cnt_u, cnt_v,
                                     wsrc, bsrc, wdst, bdst, Psrc, Pdst, bn_raw);
    k_prep<<<392, 256, 0, stream>>>(Psrc, Pdst, bn_raw, gs, bes, gd, bed, hsaugT, htp);
    k_agemm<<<dim3(16, 17), 256, 0, stream>>>(hsaugT, waug, Ah, A32);
    k_z<<<512, 256, 0, stream>>>((const unsigned int*)Ah, A32, (const uint4*)htp,
                                 ustart, eonv, zbuf, zsumR, zsqR);
    k_logit<<<E_ / 16, 256, 0, stream>>>(zbuf, zsumR, zsqR, ntlu, ntlg, ntlbe, out);
}

// Round 3
// 387.718 us; speedup vs baseline: 1.1484x; 1.0743x over previous
//
#include <hip/hip_runtime.h>
#include <hip/hip_bf16.h>
#include <hip/hip_fp16.h>
#include <cstdint>

// Problem constants
constexpr int B_   = 64;
constexpr int L_   = 512;
constexpr int G_   = 128;
constexpr int E_   = 65536;
constexpr int RH   = 256;    // NREL*NHID
constexpr int M_   = 2048;   // B*N distinct nodes
constexpr int JA   = 33;     // augmented j (32 + const-1 slot)
constexpr int COLS = RH * JA;   // 8448
constexpr int NREP = 16;     // LN-stat accumulator replicas (atomic decontention)

typedef _Float16 v2h __attribute__((ext_vector_type(2)));
typedef _Float16 v8h __attribute__((ext_vector_type(8)));
typedef float    v4f __attribute__((ext_vector_type(4)));
typedef float    v2f32 __attribute__((ext_vector_type(2)));
typedef union { uint4 u4; v8h h8; } cvt8;

#define DEV static __device__ __forceinline__

DEV float sigm(float x) { return 1.f / (1.f + __expf(-x)); }
DEV float tanh_fast(float x) {
    x = fminf(15.f, fmaxf(-15.f, x));
    float e = __expf(2.f * x);
    return (e - 1.f) / (e + 1.f);
}

// ---------------- K_eh: embed + edge histograms + waug build ----------------
// blocks 0..255: embed (4 blocks/batch, lgkm-clean inner loop);
// blocks 256..511: hist; 512..1600: waug (read-coalesced).
// waug layout: waug[i*COLS + j*256 + rh]
__global__ __launch_bounds__(256) void k_eh(const int* __restrict__ seq,
                                            const int* __restrict__ p2g,
                                            const float* __restrict__ emb,
                                            const int* __restrict__ u,
                                            const int* __restrict__ v,
                                            const float* __restrict__ ntlw,
                                            const float* __restrict__ ntlv,
                                            const float* __restrict__ ntlb,
                                            float* __restrict__ xg,
                                            int* __restrict__ cu, int* __restrict__ cv,
                                            float* __restrict__ waug) {
    int blk = blockIdx.x;
    int t   = threadIdx.x;
    if (blk >= 512) {
        int gid = (blk - 512) * 256 + t;      // j-fastest: coalesced ntlw reads
        int i   = gid / COLS;
        int rem = gid - i * COLS;
        int rh  = rem / JA;
        int j   = rem - rh * JA;
        float val;
        if (i < 32) val = (j < 32) ? ntlw[((size_t)rh * 32 + i) * 32 + j] : ntlv[rh * 64 + i];
        else        val = (j < 32) ? ntlv[rh * 64 + 32 + j] : ntlb[rh];
        waug[(size_t)i * COLS + j * 256 + rh] = val;   // scattered, L2-absorbed
        return;
    }
    if (blk >= 256) {
        int n = (blk - 256) * 256 + t;
        atomicAdd(&cu[u[n]], 1);
        atomicAdd(&cv[v[n]], 1);
        return;
    }
    // ---- embed: 4 blocks per batch, each covers 128 sequence positions ----
    __shared__ float xgl[G_ * 64];          // 32 KB partial sums
    __shared__ int sl[128], gld[128];
    int b = blk >> 2, part = blk & 3;
    for (int i = t; i < G_ * 64; i += 256) xgl[i] = 0.f;
    if (t < 128) {
        sl[t]  = seq[b * L_ + part * 128 + t];
        gld[t] = p2g[b * L_ + part * 128 + t];
    }
    __syncthreads();
    int d = t & 63, sub = t >> 6;
#pragma unroll
    for (int gg = 0; gg < 2; gg++) {
        int sv[16], gv[16];
#pragma unroll
        for (int k = 0; k < 16; k++) {       // batch LDS reads first (lgkm group)
            sv[k] = sl[sub * 32 + gg * 16 + k];
            gv[k] = gld[sub * 32 + gg * 16 + k];
        }
#pragma unroll
        for (int k = 0; k < 16; k++)         // then pure-vm loads + ds atomics
            atomicAdd(&xgl[gv[k] * 64 + d], emb[(size_t)sv[k] * 64 + d]);
    }
    __syncthreads();
    for (int i = t; i < G_ * 64; i += 256)   // flush partials (xg pre-zeroed)
        atomicAdd(&xg[(size_t)b * G_ * 64 + i], xgl[i]);
}

// ---------------- K_pre: input-gate GEMM (scalar x broadcast) + scan --------
__global__ __launch_bounds__(256) void k_pre(const float* __restrict__ xg,
                                             const float* __restrict__ wihf,
                                             const float* __restrict__ bihf,
                                             const float* __restrict__ bhhf,
                                             const float* __restrict__ wihb,
                                             const float* __restrict__ bihb,
                                             const float* __restrict__ bhhb,
                                             float* __restrict__ pre,
                                             const int* __restrict__ cu,
                                             int* __restrict__ ustart,
                                             int* __restrict__ ucursor) {
    int blk = blockIdx.x;
    int t   = threadIdx.x;
    if (blk == 512) {
        __shared__ int ps[256];
        int base = t * 8, run = 0;
        int c[8], loc[8];
#pragma unroll
        for (int i = 0; i < 8; i++) c[i] = cu[base + i];
#pragma unroll
        for (int i = 0; i < 8; i++) { loc[i] = run; run += c[i]; }
        ps[t] = run;
        __syncthreads();
        for (int off = 1; off < 256; off <<= 1) {
            int a = (t >= off) ? ps[t - off] : 0;
            __syncthreads();
            ps[t] += a;
            __syncthreads();
        }
        int ex = ps[t] - run;
#pragma unroll
        for (int i = 0; i < 8; i++) { ustart[base + i] = ex + loc[i]; ucursor[base + i] = ex + loc[i]; }
        if (t == 255) ustart[2048] = E_;
        return;
    }
    int dir = blk >> 8;
    const float* wih = dir ? wihb : wihf;
    float bias = dir ? (bihb[t] + bhhb[t]) : (bihf[t] + bhhf[t]);
    int r0 = (blk & 255) * 32;

    float4 wv[16];
#pragma unroll
    for (int c = 0; c < 16; c++) wv[c] = ((const float4*)(wih + t * 64))[c];

#pragma unroll 2
    for (int ml = 0; ml < 32; ml++) {
        const float* xr = xg + (size_t)(r0 + ml) * 64;   // wave-uniform -> s_load
        float acc = bias;
#pragma unroll
        for (int c = 0; c < 16; c++) {
            float x0 = xr[4 * c], x1 = xr[4 * c + 1], x2 = xr[4 * c + 2], x3 = xr[4 * c + 3];
            acc += x0 * wv[c].x + x1 * wv[c].y + x2 * wv[c].z + x3 * wv[c].w;
        }
        pre[((size_t)dir * 8192 + r0 + ml) * 256 + t] = acc;   // gate-major, coalesced
    }
}

// ---------------- K_lstm: TWO waves per recurrence, gate-split --------------
// Wave 0 owns gates (i,f) for all 64 units; wave 1 owns (g,o). Each wave's
// weights are 64 v2f32 = 128 VGPRs (fits the 256-arch cap, NO spill, NO AGPR
// tricks). Per step: 64 readlane + 64 v_pk_fma_f32, nonlinearity, then a
// minimal 2-float/lane LDS exchange with ONE barrier (double-buffered); both
// waves redundantly compute the identical c/h update so each keeps a full h
// copy for its own readlane broadcast.
// blocks 128..639: edge counting-sort rider (128 threads each).
__global__ __launch_bounds__(128, 1) void k_lstm(const float* __restrict__ pre,
                                                 const float* __restrict__ whh_f,
                                                 const float* __restrict__ whh_b,
                                                 float* __restrict__ hgrp,
                                                 const int* __restrict__ u,
                                                 const int* __restrict__ v,
                                                 int* __restrict__ ucursor,
                                                 int2* __restrict__ eonv) {
    int blk = blockIdx.x;
    int t   = threadIdx.x;               // 0..127
    if (blk >= 128) {
        int n = (blk - 128) * 128 + t;
        int pos = atomicAdd(&ucursor[u[n]], 1);
        eonv[pos] = make_int2(n, v[n]);
        return;
    }
    __shared__ float2 xbuf[2][2][64];    // [step&1][wave][unit] gate pairs, 2 KB
    int wv = t >> 6;                     // 0 = (i,f), 1 = (g,o)
    int e  = t & 63;                     // hidden unit
    int dir = blk >> 6;
    int b   = blk & 63;
    const float* whh     = dir ? whh_b : whh_f;
    const float* prebase = pre + ((size_t)dir * 8192 + (size_t)b * G_) * 256;
    float* hout = hgrp + (size_t)b * G_ * 128 + dir * 64 + e;

    // ---- this wave's 2 gate rows for unit e, packed into v2f32 ------------
    v2f32 w[64];                         // 128 VGPRs
    {
        const float4* pa = (const float4*)(whh + (size_t)((2 * wv + 0) * 64 + e) * 64);
        const float4* pb = (const float4*)(whh + (size_t)((2 * wv + 1) * 64 + e) * 64);
#pragma unroll
        for (int c = 0; c < 16; c++) {
            float4 a = pa[c], bb = pb[c];
            w[4 * c + 0] = (v2f32){a.x, bb.x};
            w[4 * c + 1] = (v2f32){a.y, bb.y};
            w[4 * c + 2] = (v2f32){a.z, bb.z};
            w[4 * c + 3] = (v2f32){a.w, bb.w};
        }
    }
    int c0 = wv * 128 + e;               // pre columns this wave consumes
    int c1 = wv * 128 + 64 + e;

    float h = 0.f, creg = 0.f;

    // ---- 2-deep prefetch of pre-activations -------------------------------
    int s0i = dir ? (G_ - 1) : 0;
    int s1i = dir ? (G_ - 2) : 1;
    float q0 = prebase[(size_t)s0i * 256 + c0];
    float q1 = prebase[(size_t)s0i * 256 + c1];
    float r0 = prebase[(size_t)s1i * 256 + c0];
    float r1 = prebase[(size_t)s1i * 256 + c1];

#pragma unroll 1
    for (int step = 0; step < G_; step++) {
        int s  = dir ? (G_ - 1 - step) : step;
        int t2 = (step + 2 < G_) ? step + 2 : G_ - 1;
        int s2 = dir ? (G_ - 1 - t2) : t2;
        const float* pn = prebase + (size_t)s2 * 256;
        float n0 = pn[c0], n1 = pn[c1];  // consumed 2 iterations later

        // ---- matvec: 64 readlane + 64 pk_fma, 4-way acc split -------------
        v2f32 acc[4];
        acc[0] = (v2f32){q0, q1};
        acc[1] = (v2f32){0.f, 0.f};
        acc[2] = (v2f32){0.f, 0.f};
        acc[3] = (v2f32){0.f, 0.f};
#pragma unroll
        for (int j = 0; j < 64; j++) {
            float hv = __int_as_float(__builtin_amdgcn_readlane(__float_as_int(h), j));
            v2f32 hv2 = {hv, hv};
            acc[j & 3] += w[j] * hv2;
        }
        v2f32 sg = (acc[0] + acc[1]) + (acc[2] + acc[3]);

        // wave-uniform nonlinearity: wave0 -> (ai,af), wave1 -> (ag,ao)
        float ga = wv ? tanh_fast(sg.x) : sigm(sg.x);
        float gb = sigm(sg.y);

        xbuf[step & 1][wv][e] = make_float2(ga, gb);
        __syncthreads();
        float2 oth = xbuf[step & 1][1 - wv][e];

        float ai = wv ? oth.x : ga;
        float af = wv ? oth.y : gb;
        float ag = wv ? ga : oth.x;
        float ao = wv ? gb : oth.y;
        creg = af * creg + ai * ag;      // identical in both waves
        h    = ao * tanh_fast(creg);
        if (wv == 0) hout[(size_t)s * 128] = h;   // coalesced 256B store

        q0 = r0; q1 = r1;                // rotate prefetch stages
        r0 = n0; r1 = n1;
    }
}

// ---------------- K_gp: gather + projections + BN partial stats (fused) -----
__global__ __launch_bounds__(256) void k_gp(const int* __restrict__ idx,
                                            const int* __restrict__ p2g,
                                            const float* __restrict__ hgrp,
                                            const int* __restrict__ cu,
                                            const int* __restrict__ cv,
                                            const float* __restrict__ wsrc,
                                            const float* __restrict__ bsrc,
                                            const float* __restrict__ wdst,
                                            const float* __restrict__ bdst,
                                            float* __restrict__ Ps, float* __restrict__ Pd,
                                            float* __restrict__ bn_raw) {
    __shared__ __align__(16) float hsl[8][128];
    __shared__ float red[256];
    int m0 = blockIdx.x * 8;
    int t  = threadIdx.x;
    int d = t & 127, mh = t >> 7;
#pragma unroll
    for (int rep = 0; rep < 4; rep++) {
        int ml = rep * 2 + mh;
        int m  = m0 + ml;
        int b  = m >> 5;
        float acc = 0.f;
#pragma unroll
        for (int k = 0; k < 8; k++) {
            int l = idx[m * 8 + k];
            int g = p2g[b * L_ + l];
            acc += hgrp[((size_t)b * G_ + g) * 128 + d];
        }
        hsl[ml][d] = acc;
    }
    __syncthreads();
    int ml = t >> 5, o = t & 31;
    int m  = m0 + ml;
    const float4* hp = (const float4*)&hsl[ml][0];
    float cw_u = (float)cu[m], cw_v = (float)cv[m];
#pragma unroll 1
    for (int side = 0; side < 2; side++) {
        const float* W = side ? wdst : wsrc;
        float4 wr[32];
#pragma unroll
        for (int c = 0; c < 32; c++) wr[c] = ((const float4*)(W + (size_t)o * 128))[c];
        float acc = side ? bdst[o] : bsrc[o];
#pragma unroll
        for (int c = 0; c < 32; c++) {
            float4 h4 = hp[c];
            acc += h4.x * wr[c].x + h4.y * wr[c].y + h4.z * wr[c].z + h4.w * wr[c].w;
        }
        (side ? Pd : Ps)[(size_t)m * 32 + o] = acc;
        float cw = side ? cw_v : cw_u;
        red[t] = cw * acc;
        __syncthreads();
        if (t < 32) {
            float s = 0.f;
#pragma unroll
            for (int i = 0; i < 8; i++) s += red[i * 32 + t];
            atomicAdd(&bn_raw[side * 64 + t], s);
        }
        __syncthreads();
        red[t] = cw * acc * acc;
        __syncthreads();
        if (t < 32) {
            float s = 0.f;
#pragma unroll
            for (int i = 0; i < 8; i++) s += red[i * 32 + t];
            atomicAdd(&bn_raw[side * 64 + 32 + t], s);
        }
        __syncthreads();
    }
}

// ---------------- K_prep: BN-normalize; build hsaugT[i][m] and htp (f16x2) --
__global__ __launch_bounds__(256) void k_prep(const float* __restrict__ Ps,
                                              const float* __restrict__ Pd,
                                              const float* __restrict__ bn_raw,
                                              const float* __restrict__ gs,
                                              const float* __restrict__ bes,
                                              const float* __restrict__ gd,
                                              const float* __restrict__ bed,
                                              float* __restrict__ hsaugT,
                                              v2h* __restrict__ htp) {
    int blk = blockIdx.x;
    int t   = threadIdx.x;
    constexpr float invE = 1.f / (float)E_;
    if (blk < 264) {                        // 264*256 = 33*2048
        int gid = blk * 256 + t;
        int c = gid >> 11;                   // 0..32
        int m = gid & 2047;
        float val = 1.f;
        if (c < 32) {
            float mu  = bn_raw[c] * invE;
            float isd = rsqrtf(bn_raw[32 + c] * invE - mu * mu + 1e-5f);
            val = gs[c] * (Ps[(size_t)m * 32 + c] - mu) * isd + bes[c];
        }
        hsaugT[(size_t)c * 2048 + m] = val;   // coalesced over m
        return;
    }
    int gid = (blk - 264) * 256 + t;         // 128*256 = 2048*16
    int m  = gid >> 4;
    int jp = gid & 15;
    int j0 = 2 * jp, j1 = 2 * jp + 1;
    float mu0  = bn_raw[64 + j0] * invE;
    float isd0 = rsqrtf(bn_raw[96 + j0] * invE - mu0 * mu0 + 1e-5f);
    float mu1  = bn_raw[64 + j1] * invE;
    float isd1 = rsqrtf(bn_raw[96 + j1] * invE - mu1 * mu1 + 1e-5f);
    float h0 = gd[j0] * (Pd[(size_t)m * 32 + j0] - mu0) * isd0 + bed[j0];
    float h1 = gd[j1] * (Pd[(size_t)m * 32 + j1] - mu1) * isd1 + bed[j1];
    v2h p;
    p.x = (_Float16)h0; p.y = (_Float16)h1;
    htp[gid] = p;                            // coalesced
}

// ---------------- K_agemm: w in REGISTERS (fully-unrolled i), low block count
// grid (16 m-slices, 17 jp). Each block: load w once, loop 16 chunks x 8 m.
__global__ __launch_bounds__(256, 1) void k_agemm(const float* __restrict__ hsaugT,
                                                  const float* __restrict__ waug,
                                                  v2h* __restrict__ Ah,
                                                  float* __restrict__ A32) {
    int ms = blockIdx.x;                   // 16 slices of 128 m
    int jp = blockIdx.y;                   // 0..16
    int t  = threadIdx.x;                  // rh
    int mbase = ms * 128;
    if (jp < 16) {
        float w0[JA], w1[JA];
#pragma unroll
        for (int i = 0; i < JA; i++) {      // FULL unroll: static indices -> registers
            w0[i] = waug[(size_t)i * COLS + (2 * jp) * 256 + t];
            w1[i] = waug[(size_t)i * COLS + (2 * jp + 1) * 256 + t];
        }
#pragma unroll 1
        for (int ch = 0; ch < 16; ch++) {
            int m0 = mbase + ch * 8;
            float acc0[8], acc1[8];
#pragma unroll
            for (int ml = 0; ml < 8; ml++) { acc0[ml] = 0.f; acc1[ml] = 0.f; }
#pragma unroll
            for (int i = 0; i < JA; i++) {
                const float* hr = hsaugT + (size_t)i * 2048 + m0;   // s_load dwordx8
#pragma unroll
                for (int ml = 0; ml < 8; ml++) {
                    float hv = hr[ml];
                    acc0[ml] += hv * w0[i];
                    acc1[ml] += hv * w1[i];
                }
            }
#pragma unroll
            for (int ml = 0; ml < 8; ml++) {
                v2h p;
                p.x = (_Float16)acc0[ml]; p.y = (_Float16)acc1[ml];
                Ah[(size_t)(m0 + ml) * 4096 + jp * 256 + t] = p;
            }
        }
    } else {
        float w2[JA];
#pragma unroll
        for (int i = 0; i < JA; i++) w2[i] = waug[(size_t)i * COLS + 32 * 256 + t];
#pragma unroll 1
        for (int ch = 0; ch < 16; ch++) {
            int m0 = mbase + ch * 8;
            float acc[8];
#pragma unroll
            for (int ml = 0; ml < 8; ml++) acc[ml] = 0.f;
#pragma unroll
            for (int i = 0; i < JA; i++) {
                const float* hr = hsaugT + (size_t)i * 2048 + m0;
#pragma unroll
                for (int ml = 0; ml < 8; ml++) acc[ml] += hr[ml] * w2[i];
            }
#pragma unroll
            for (int ml = 0; ml < 8; ml++)
                A32[(size_t)(m0 + ml) * 256 + t] = acc[ml];
        }
    }
}

// ---------------- K_z: MFMA edge-tile GEMM + replicated LN-stat atomics -----
__global__ __launch_bounds__(256) void k_z(const unsigned int* __restrict__ Ah,
                                           const float* __restrict__ A32,
                                           const uint4* __restrict__ htp4,
                                           const int* __restrict__ ustart,
                                           const int2* __restrict__ eonv,
                                           _Float16* __restrict__ zh,
                                           float* __restrict__ zsumR,
                                           float* __restrict__ zsqR) {
    int t    = threadIdx.x;
    int lane = t & 63;
    int uu   = blockIdx.x * 4 + (t >> 6);
    int l15  = lane & 15, quad = lane >> 4;

    // B fragments for all 16 rh-tiles (64 VGPRs, loaded once per u)
    uint4 bf[16];
#pragma unroll
    for (int nt = 0; nt < 16; nt++) {
        const unsigned int* bp = Ah + (size_t)uu * 4096 + (quad * 4) * 256 + nt * 16 + l15;
        bf[nt].x = bp[0]; bf[nt].y = bp[256]; bf[nt].z = bp[512]; bf[nt].w = bp[768];
    }
    float a32[16];
#pragma unroll
    for (int nt = 0; nt < 16; nt++) a32[nt] = A32[(size_t)uu * 256 + nt * 16 + l15];

    float s1[16], s2[16];
#pragma unroll
    for (int nt = 0; nt < 16; nt++) { s1[nt] = 0.f; s2[nt] = 0.f; }

    int e0 = ustart[uu], e1 = ustart[uu + 1];
    for (int base = e0; base < e1; base += 16) {
        int ei = min(base + l15, e1 - 1);          // clamp: duplicate rows are idempotent
        int2 q = eonv[ei];
        uint4 afu = htp4[(size_t)q.y * 4 + quad];  // A-frag: vector dwordx4, no broadcast
        cvt8 ac; ac.u4 = afu;
        int nrow[4], valid[4];
#pragma unroll
        for (int r = 0; r < 4; r++) {
            int er = quad * 4 + r;
            nrow[r]  = __builtin_amdgcn_ds_bpermute(er << 2, q.x);   // n of D-row er
            valid[r] = (base + er) < e1;
        }
#pragma unroll
        for (int nt = 0; nt < 16; nt++) {
            cvt8 bc; bc.u4 = bf[nt];
            v4f acc = { a32[nt], a32[nt], a32[nt], a32[nt] };
            acc = __builtin_amdgcn_mfma_f32_16x16x32_f16(ac.h8, bc.h8, acc, 0, 0, 0);
#pragma unroll
            for (int r = 0; r < 4; r++) {
                if (valid[r]) {
                    float z = acc[r];
                    zh[(size_t)nrow[r] * 256 + nt * 16 + l15] = (_Float16)z;
                    s1[nt] += z; s2[nt] += z * z;
                }
            }
        }
    }
    int rep = (blockIdx.x & (NREP - 1)) * 256;     // replica slice (atomic decontention)
#pragma unroll
    for (int nt = 0; nt < 16; nt++) {
        float a = s1[nt], b = s2[nt];
        a += __shfl_xor(a, 16); a += __shfl_xor(a, 32);
        b += __shfl_xor(b, 16); b += __shfl_xor(b, 32);
        if (quad == 0) {
            atomicAdd(&zsumR[rep + nt * 16 + l15], a);
            atomicAdd(&zsqR[rep + nt * 16 + l15], b);
        }
    }
}

// ---------------- K_logit: LN (replica-sum inline) + tanh + contract --------
__global__ __launch_bounds__(256) void k_logit(const _Float16* __restrict__ zh,
                                               const float* __restrict__ zsumR,
                                               const float* __restrict__ zsqR,
                                               const float* __restrict__ ntlu,
                                               const float* __restrict__ ntlg,
                                               const float* __restrict__ ntlbe,
                                               float* __restrict__ out) {
    int t  = threadIdx.x;                 // rh = r*16+h
    int n0 = blockIdx.x * 16;
    float su = 0.f, sq = 0.f;
#pragma unroll
    for (int r = 0; r < NREP; r++) {
        su += zsumR[r * 256 + t];
        sq += zsqR[r * 256 + t];
    }
    float mu  = su / (float)E_;
    float var = sq / (float)E_ - mu * mu;
    float isd = rsqrtf(var + 1e-5f);
    float g   = ntlg[t],  be  = ntlbe[t];
    float uw  = ntlu[t];
    float zv[16];
#pragma unroll
    for (int nl = 0; nl < 16; nl++)
        zv[nl] = (float)zh[(size_t)(n0 + nl) * 256 + t];
#pragma unroll 1
    for (int nl = 0; nl < 16; nl++) {
        float zn  = g * (zv[nl] - mu) * isd + be;
        float val = uw * tanh_fast(zn);
        val += __shfl_xor(val, 1);
        val += __shfl_xor(val, 2);
        val += __shfl_xor(val, 4);
        val += __shfl_xor(val, 8);
        if ((t & 15) == 0) out[(size_t)(n0 + nl) * 16 + (t >> 4)] = val;
    }
}

// ============================ host side =====================================
extern "C" void kernel_launch(void* const* d_in, const int* in_sizes, int n_in,
                              void* d_out, int out_size, void* d_ws, size_t ws_size,
                              hipStream_t stream) {
    const int*   seq   = (const int*)d_in[0];
    const int*   p2g   = (const int*)d_in[1];
    const int*   idx   = (const int*)d_in[2];
    const int*   u     = (const int*)d_in[3];
    const int*   v     = (const int*)d_in[4];
    const float* emb   = (const float*)d_in[5];
    const float* wihf  = (const float*)d_in[6];
    const float* whhf  = (const float*)d_in[7];
    const float* bihf  = (const float*)d_in[8];
    const float* bhhf  = (const float*)d_in[9];
    const float* wihb  = (const float*)d_in[10];
    const float* whhb  = (const float*)d_in[11];
    const float* bihb  = (const float*)d_in[12];
    const float* bhhb  = (const float*)d_in[13];
    const float* wsrc  = (const float*)d_in[14];
    const float* bsrc  = (const float*)d_in[15];
    const float* wdst  = (const float*)d_in[16];
    const float* bdst  = (const float*)d_in[17];
    const float* gs    = (const float*)d_in[18];
    const float* bes   = (const float*)d_in[19];
    const float* gd    = (const float*)d_in[20];
    const float* bed   = (const float*)d_in[21];
    const float* ntlw  = (const float*)d_in[22];
    const float* ntlv  = (const float*)d_in[23];
    const float* ntlb  = (const float*)d_in[24];
    const float* ntlu  = (const float*)d_in[25];
    const float* ntlg  = (const float*)d_in[26];
    const float* ntlbe = (const float*)d_in[27];
    float* out = (float*)d_out;

    char* ws = (char*)d_ws;
    size_t off = 0;
    auto take = [&](size_t bytes) -> char* {
        char* p = ws + off;
        off = (off + bytes + 255) & ~(size_t)255;
        return p;
    };
    // zeroed region (contiguous, one memset)
    int*   cnt_u  = (int*)  take(2048 * 4);
    int*   cnt_v  = (int*)  take(2048 * 4);
    float* zsumR  = (float*)take((size_t)NREP * 256 * 4);
    float* zsqR   = (float*)take((size_t)NREP * 256 * 4);
    float* bn_raw = (float*)take(128 * 4);
    float* x_grp  = (float*)take((size_t)B_ * G_ * 64 * 4);   // accumulated via atomics
    size_t zero_bytes = off;
    // rest
    int*   ucursor = (int*)  take(2048 * 4);
    int*   ustart  = (int*)  take(2049 * 4);
    int2*  eonv    = (int2*) take((size_t)E_ * 8);
    float* pre     = (float*)take((size_t)2 * 8192 * 256 * 4);
    float* hgrp    = (float*)take((size_t)B_ * G_ * 128 * 4);
    float* Psrc    = (float*)take((size_t)M_ * 32 * 4);
    float* Pdst    = (float*)take((size_t)M_ * 32 * 4);
    float* hsaugT  = (float*)take((size_t)36 * 2048 * 4);
    v2h*   htp     = (v2h*)  take((size_t)M_ * 16 * 4);
    float* waug    = (float*)take((size_t)JA * COLS * 4);
    v2h*   Ah      = (v2h*)  take((size_t)M_ * 4096 * 4);
    float* A32     = (float*)take((size_t)M_ * 256 * 4);
    _Float16* zbuf = (_Float16*)take((size_t)E_ * 256 * 2);
    (void)ws_size; (void)in_sizes; (void)n_in; (void)out_size;

    hipMemsetAsync(d_ws, 0, zero_bytes, stream);

    k_eh<<<512 + 1089, 256, 0, stream>>>(seq, p2g, emb, u, v, ntlw, ntlv, ntlb,
                                         x_grp, cnt_u, cnt_v, waug);
    k_pre<<<513, 256, 0, stream>>>(x_grp, wihf, bihf, bhhf, wihb, bihb, bhhb, pre,
                                   cnt_u, ustart, ucursor);
    k_lstm<<<128 + E_ / 128, 128, 0, stream>>>(pre, whhf, whhb, hgrp, u, v, ucursor, eonv);
    k_gp<<<M_ / 8, 256, 0, stream>>>(idx, p2g, hgrp, cnt_u, cnt_v,
                                     wsrc, bsrc, wdst, bdst, Psrc, Pdst, bn_raw);
    k_prep<<<392, 256, 0, stream>>>(Psrc, Pdst, bn_raw, gs, bes, gd, bed, hsaugT, htp);
    k_agemm<<<dim3(16, 17), 256, 0, stream>>>(hsaugT, waug, Ah, A32);
    k_z<<<512, 256, 0, stream>>>((const unsigned int*)Ah, A32, (const uint4*)htp,
                                 ustart, eonv, zbuf, zsumR, zsqR);
    k_logit<<<E_ / 16, 256, 0, stream>>>(zbuf, zsumR, zsqR, ntlu, ntlg, ntlbe, out);
}

// Round 4
// 370.709 us; speedup vs baseline: 1.2011x; 1.0459x over previous
//
#include <hip/hip_runtime.h>
#include <hip/hip_bf16.h>
#include <hip/hip_fp16.h>
#include <cstdint>

// Problem constants
constexpr int B_   = 64;
constexpr int L_   = 512;
constexpr int G_   = 128;
constexpr int E_   = 65536;
constexpr int RH   = 256;    // NREL*NHID
constexpr int M_   = 2048;   // B*N distinct nodes
constexpr int JA   = 33;     // augmented j (32 + const-1 slot)
constexpr int COLS = RH * JA;   // 8448
constexpr int NREP = 16;     // LN-stat accumulator replicas (atomic decontention)

typedef _Float16 v2h __attribute__((ext_vector_type(2)));
typedef _Float16 v8h __attribute__((ext_vector_type(8)));
typedef float    v4f __attribute__((ext_vector_type(4)));
typedef float    v2f32 __attribute__((ext_vector_type(2)));
typedef union { uint4 u4; v8h h8; } cvt8;

#define DEV static __device__ __forceinline__

DEV float sigm(float x) { return 1.f / (1.f + __expf(-x)); }
DEV float tanh_fast(float x) {
    x = fminf(15.f, fmaxf(-15.f, x));
    float e = __expf(2.f * x);
    return (e - 1.f) / (e + 1.f);
}

// ---------------- K_eh: embed + edge histograms + waug build ----------------
// blocks 0..255: embed (4 blocks/batch, lgkm-clean inner loop);
// blocks 256..511: hist; 512..1600: waug (read-coalesced).
// waug layout: waug[i*COLS + j*256 + rh]
__global__ __launch_bounds__(256) void k_eh(const int* __restrict__ seq,
                                            const int* __restrict__ p2g,
                                            const float* __restrict__ emb,
                                            const int* __restrict__ u,
                                            const int* __restrict__ v,
                                            const float* __restrict__ ntlw,
                                            const float* __restrict__ ntlv,
                                            const float* __restrict__ ntlb,
                                            float* __restrict__ xg,
                                            int* __restrict__ cu, int* __restrict__ cv,
                                            float* __restrict__ waug) {
    int blk = blockIdx.x;
    int t   = threadIdx.x;
    if (blk >= 512) {
        int gid = (blk - 512) * 256 + t;      // j-fastest: coalesced ntlw reads
        int i   = gid / COLS;
        int rem = gid - i * COLS;
        int rh  = rem / JA;
        int j   = rem - rh * JA;
        float val;
        if (i < 32) val = (j < 32) ? ntlw[((size_t)rh * 32 + i) * 32 + j] : ntlv[rh * 64 + i];
        else        val = (j < 32) ? ntlv[rh * 64 + 32 + j] : ntlb[rh];
        waug[(size_t)i * COLS + j * 256 + rh] = val;   // scattered, L2-absorbed
        return;
    }
    if (blk >= 256) {
        int n = (blk - 256) * 256 + t;
        atomicAdd(&cu[u[n]], 1);
        atomicAdd(&cv[v[n]], 1);
        return;
    }
    // ---- embed: 4 blocks per batch, each covers 128 sequence positions ----
    __shared__ float xgl[G_ * 64];          // 32 KB partial sums
    __shared__ int sl[128], gld[128];
    int b = blk >> 2, part = blk & 3;
    for (int i = t; i < G_ * 64; i += 256) xgl[i] = 0.f;
    if (t < 128) {
        sl[t]  = seq[b * L_ + part * 128 + t];
        gld[t] = p2g[b * L_ + part * 128 + t];
    }
    __syncthreads();
    int d = t & 63, sub = t >> 6;
#pragma unroll
    for (int gg = 0; gg < 2; gg++) {
        int sv[16], gv[16];
#pragma unroll
        for (int k = 0; k < 16; k++) {       // batch LDS reads first (lgkm group)
            sv[k] = sl[sub * 32 + gg * 16 + k];
            gv[k] = gld[sub * 32 + gg * 16 + k];
        }
#pragma unroll
        for (int k = 0; k < 16; k++)         // then pure-vm loads + ds atomics
            atomicAdd(&xgl[gv[k] * 64 + d], emb[(size_t)sv[k] * 64 + d]);
    }
    __syncthreads();
    for (int i = t; i < G_ * 64; i += 256)   // flush partials (xg pre-zeroed)
        atomicAdd(&xg[(size_t)b * G_ * 64 + i], xgl[i]);
}

// ---------------- K_pre: input-gate GEMM (scalar x broadcast) + scan --------
__global__ __launch_bounds__(256) void k_pre(const float* __restrict__ xg,
                                             const float* __restrict__ wihf,
                                             const float* __restrict__ bihf,
                                             const float* __restrict__ bhhf,
                                             const float* __restrict__ wihb,
                                             const float* __restrict__ bihb,
                                             const float* __restrict__ bhhb,
                                             float* __restrict__ pre,
                                             const int* __restrict__ cu,
                                             int* __restrict__ ustart,
                                             int* __restrict__ ucursor) {
    int blk = blockIdx.x;
    int t   = threadIdx.x;
    if (blk == 512) {
        __shared__ int ps[256];
        int base = t * 8, run = 0;
        int c[8], loc[8];
#pragma unroll
        for (int i = 0; i < 8; i++) c[i] = cu[base + i];
#pragma unroll
        for (int i = 0; i < 8; i++) { loc[i] = run; run += c[i]; }
        ps[t] = run;
        __syncthreads();
        for (int off = 1; off < 256; off <<= 1) {
            int a = (t >= off) ? ps[t - off] : 0;
            __syncthreads();
            ps[t] += a;
            __syncthreads();
        }
        int ex = ps[t] - run;
#pragma unroll
        for (int i = 0; i < 8; i++) { ustart[base + i] = ex + loc[i]; ucursor[base + i] = ex + loc[i]; }
        if (t == 255) ustart[2048] = E_;
        return;
    }
    int dir = blk >> 8;
    const float* wih = dir ? wihb : wihf;
    float bias = dir ? (bihb[t] + bhhb[t]) : (bihf[t] + bhhf[t]);
    int r0 = (blk & 255) * 32;

    float4 wv[16];
#pragma unroll
    for (int c = 0; c < 16; c++) wv[c] = ((const float4*)(wih + t * 64))[c];

#pragma unroll 2
    for (int ml = 0; ml < 32; ml++) {
        const float* xr = xg + (size_t)(r0 + ml) * 64;   // wave-uniform -> s_load
        float acc = bias;
#pragma unroll
        for (int c = 0; c < 16; c++) {
            float x0 = xr[4 * c], x1 = xr[4 * c + 1], x2 = xr[4 * c + 2], x3 = xr[4 * c + 3];
            acc += x0 * wv[c].x + x1 * wv[c].y + x2 * wv[c].z + x3 * wv[c].w;
        }
        pre[((size_t)dir * 8192 + r0 + ml) * 256 + t] = acc;   // gate-major, coalesced
    }
}

// ---------------- K_lstm: TWO waves per recurrence, gate-split --------------
// Wave 0 owns gates (i,f) for all 64 units; wave 1 owns (g,o). The 128
// weight floats per lane are 64 NAMED v2f32 SSA values (macro-expanded) —
// NOT an array. hipcc's promote-alloca bails on >=128-scalar arrays (rounds
// 1-3 all silently went to scratch: VGPR_Count 144/148/76); named vectors go
// through regalloc proper, which honors __launch_bounds__(128,1).
// Per step: 64 readlane + 64 v_pk_fma_f32, one LDS float2 exchange + ONE
// barrier (double-buffered); both waves redundantly compute c/h so each
// keeps a full h copy for its own readlane broadcast.
// blocks 128..639: edge counting-sort rider (128 threads each).
__global__ __launch_bounds__(128, 1) void k_lstm(const float* __restrict__ pre,
                                                 const float* __restrict__ whh_f,
                                                 const float* __restrict__ whh_b,
                                                 float* __restrict__ hgrp,
                                                 const int* __restrict__ u,
                                                 const int* __restrict__ v,
                                                 int* __restrict__ ucursor,
                                                 int2* __restrict__ eonv) {
    int blk = blockIdx.x;
    int t   = threadIdx.x;               // 0..127
    if (blk >= 128) {
        int n = (blk - 128) * 128 + t;
        int pos = atomicAdd(&ucursor[u[n]], 1);
        eonv[pos] = make_int2(n, v[n]);
        return;
    }
    __shared__ float2 xbuf[2][2][64];    // [step&1][wave][unit] gate pairs, 2 KB
    int wv = t >> 6;                     // 0 = (i,f), 1 = (g,o)
    int e  = t & 63;                     // hidden unit
    int dir = blk >> 6;
    int b   = blk & 63;
    const float* whh     = dir ? whh_b : whh_f;
    const float* prebase = pre + ((size_t)dir * 8192 + (size_t)b * G_) * 256;
    float* hout = hgrp + (size_t)b * G_ * 128 + dir * 64 + e;

    const float4* pa = (const float4*)(whh + (size_t)((2 * wv + 0) * 64 + e) * 64);
    const float4* pb = (const float4*)(whh + (size_t)((2 * wv + 1) * 64 + e) * 64);

    // ---- 64 NAMED v2f32 weight pairs (no alloca -> no scratch demotion) ---
#define DECL_W(c) v2f32 w_##c##_0, w_##c##_1, w_##c##_2, w_##c##_3;
    DECL_W(0)  DECL_W(1)  DECL_W(2)  DECL_W(3)
    DECL_W(4)  DECL_W(5)  DECL_W(6)  DECL_W(7)
    DECL_W(8)  DECL_W(9)  DECL_W(10) DECL_W(11)
    DECL_W(12) DECL_W(13) DECL_W(14) DECL_W(15)
#define INIT_W(c) { float4 a_ = pa[c]; float4 b_ = pb[c];                    \
    w_##c##_0 = (v2f32){a_.x, b_.x}; w_##c##_1 = (v2f32){a_.y, b_.y};        \
    w_##c##_2 = (v2f32){a_.z, b_.z}; w_##c##_3 = (v2f32){a_.w, b_.w}; }
    INIT_W(0)  INIT_W(1)  INIT_W(2)  INIT_W(3)
    INIT_W(4)  INIT_W(5)  INIT_W(6)  INIT_W(7)
    INIT_W(8)  INIT_W(9)  INIT_W(10) INIT_W(11)
    INIT_W(12) INIT_W(13) INIT_W(14) INIT_W(15)

    int c0 = wv * 128 + e;               // pre columns this wave consumes
    int c1 = wv * 128 + 64 + e;

    float h = 0.f, creg = 0.f;

    // ---- 2-deep prefetch of pre-activations -------------------------------
    int s0i = dir ? (G_ - 1) : 0;
    int s1i = dir ? (G_ - 2) : 1;
    float q0 = prebase[(size_t)s0i * 256 + c0];
    float q1 = prebase[(size_t)s0i * 256 + c1];
    float r0 = prebase[(size_t)s1i * 256 + c0];
    float r1 = prebase[(size_t)s1i * 256 + c1];

#pragma unroll 1
    for (int step = 0; step < G_; step++) {
        int s  = dir ? (G_ - 1 - step) : step;
        int t2 = (step + 2 < G_) ? step + 2 : G_ - 1;
        int s2 = dir ? (G_ - 1 - t2) : t2;
        const float* pn = prebase + (size_t)s2 * 256;
        float n0 = pn[c0], n1 = pn[c1];  // consumed 2 iterations later

        // ---- matvec: 64 readlane + 64 pk_fma, 4-way acc split -------------
        v2f32 acc0 = (v2f32){q0, q1};
        v2f32 acc1 = (v2f32){0.f, 0.f};
        v2f32 acc2 = (v2f32){0.f, 0.f};
        v2f32 acc3 = (v2f32){0.f, 0.f};
#define MV(c) {                                                              \
    float h0_ = __int_as_float(__builtin_amdgcn_readlane(__float_as_int(h), 4 * c + 0)); \
    float h1_ = __int_as_float(__builtin_amdgcn_readlane(__float_as_int(h), 4 * c + 1)); \
    float h2_ = __int_as_float(__builtin_amdgcn_readlane(__float_as_int(h), 4 * c + 2)); \
    float h3_ = __int_as_float(__builtin_amdgcn_readlane(__float_as_int(h), 4 * c + 3)); \
    acc0 += w_##c##_0 * (v2f32){h0_, h0_};                                   \
    acc1 += w_##c##_1 * (v2f32){h1_, h1_};                                   \
    acc2 += w_##c##_2 * (v2f32){h2_, h2_};                                   \
    acc3 += w_##c##_3 * (v2f32){h3_, h3_}; }
        MV(0)  MV(1)  MV(2)  MV(3)
        MV(4)  MV(5)  MV(6)  MV(7)
        MV(8)  MV(9)  MV(10) MV(11)
        MV(12) MV(13) MV(14) MV(15)
        v2f32 sg = (acc0 + acc1) + (acc2 + acc3);

        // wave-uniform nonlinearity: wave0 -> (ai,af), wave1 -> (ag,ao)
        float ga = wv ? tanh_fast(sg.x) : sigm(sg.x);
        float gb = sigm(sg.y);

        xbuf[step & 1][wv][e] = make_float2(ga, gb);
        __syncthreads();
        float2 oth = xbuf[step & 1][1 - wv][e];

        float ai = wv ? oth.x : ga;
        float af = wv ? oth.y : gb;
        float ag = wv ? ga : oth.x;
        float ao = wv ? gb : oth.y;
        creg = af * creg + ai * ag;      // identical in both waves
        h    = ao * tanh_fast(creg);
        if (wv == 0) hout[(size_t)s * 128] = h;   // coalesced 256B store

        q0 = r0; q1 = r1;                // rotate prefetch stages
        r0 = n0; r1 = n1;
    }
#undef MV
#undef INIT_W
#undef DECL_W
}

// ---------------- K_gp: gather + projections + BN partial stats (fused) -----
__global__ __launch_bounds__(256) void k_gp(const int* __restrict__ idx,
                                            const int* __restrict__ p2g,
                                            const float* __restrict__ hgrp,
                                            const int* __restrict__ cu,
                                            const int* __restrict__ cv,
                                            const float* __restrict__ wsrc,
                                            const float* __restrict__ bsrc,
                                            const float* __restrict__ wdst,
                                            const float* __restrict__ bdst,
                                            float* __restrict__ Ps, float* __restrict__ Pd,
                                            float* __restrict__ bn_raw) {
    __shared__ __align__(16) float hsl[8][128];
    __shared__ float red[256];
    int m0 = blockIdx.x * 8;
    int t  = threadIdx.x;
    int d = t & 127, mh = t >> 7;
#pragma unroll
    for (int rep = 0; rep < 4; rep++) {
        int ml = rep * 2 + mh;
        int m  = m0 + ml;
        int b  = m >> 5;
        float acc = 0.f;
#pragma unroll
        for (int k = 0; k < 8; k++) {
            int l = idx[m * 8 + k];
            int g = p2g[b * L_ + l];
            acc += hgrp[((size_t)b * G_ + g) * 128 + d];
        }
        hsl[ml][d] = acc;
    }
    __syncthreads();
    int ml = t >> 5, o = t & 31;
    int m  = m0 + ml;
    const float4* hp = (const float4*)&hsl[ml][0];
    float cw_u = (float)cu[m], cw_v = (float)cv[m];
#pragma unroll 1
    for (int side = 0; side < 2; side++) {
        const float* W = side ? wdst : wsrc;
        float4 wr[32];
#pragma unroll
        for (int c = 0; c < 32; c++) wr[c] = ((const float4*)(W + (size_t)o * 128))[c];
        float acc = side ? bdst[o] : bsrc[o];
#pragma unroll
        for (int c = 0; c < 32; c++) {
            float4 h4 = hp[c];
            acc += h4.x * wr[c].x + h4.y * wr[c].y + h4.z * wr[c].z + h4.w * wr[c].w;
        }
        (side ? Pd : Ps)[(size_t)m * 32 + o] = acc;
        float cw = side ? cw_v : cw_u;
        red[t] = cw * acc;
        __syncthreads();
        if (t < 32) {
            float s = 0.f;
#pragma unroll
            for (int i = 0; i < 8; i++) s += red[i * 32 + t];
            atomicAdd(&bn_raw[side * 64 + t], s);
        }
        __syncthreads();
        red[t] = cw * acc * acc;
        __syncthreads();
        if (t < 32) {
            float s = 0.f;
#pragma unroll
            for (int i = 0; i < 8; i++) s += red[i * 32 + t];
            atomicAdd(&bn_raw[side * 64 + 32 + t], s);
        }
        __syncthreads();
    }
}

// ---------------- K_prep: BN-normalize; build hsaugT[i][m] and htp (f16x2) --
__global__ __launch_bounds__(256) void k_prep(const float* __restrict__ Ps,
                                              const float* __restrict__ Pd,
                                              const float* __restrict__ bn_raw,
                                              const float* __restrict__ gs,
                                              const float* __restrict__ bes,
                                              const float* __restrict__ gd,
                                              const float* __restrict__ bed,
                                              float* __restrict__ hsaugT,
                                              v2h* __restrict__ htp) {
    int blk = blockIdx.x;
    int t   = threadIdx.x;
    constexpr float invE = 1.f / (float)E_;
    if (blk < 264) {                        // 264*256 = 33*2048
        int gid = blk * 256 + t;
        int c = gid >> 11;                   // 0..32
        int m = gid & 2047;
        float val = 1.f;
        if (c < 32) {
            float mu  = bn_raw[c] * invE;
            float isd = rsqrtf(bn_raw[32 + c] * invE - mu * mu + 1e-5f);
            val = gs[c] * (Ps[(size_t)m * 32 + c] - mu) * isd + bes[c];
        }
        hsaugT[(size_t)c * 2048 + m] = val;   // coalesced over m
        return;
    }
    int gid = (blk - 264) * 256 + t;         // 128*256 = 2048*16
    int m  = gid >> 4;
    int jp = gid & 15;
    int j0 = 2 * jp, j1 = 2 * jp + 1;
    float mu0  = bn_raw[64 + j0] * invE;
    float isd0 = rsqrtf(bn_raw[96 + j0] * invE - mu0 * mu0 + 1e-5f);
    float mu1  = bn_raw[64 + j1] * invE;
    float isd1 = rsqrtf(bn_raw[96 + j1] * invE - mu1 * mu1 + 1e-5f);
    float h0 = gd[j0] * (Pd[(size_t)m * 32 + j0] - mu0) * isd0 + bed[j0];
    float h1 = gd[j1] * (Pd[(size_t)m * 32 + j1] - mu1) * isd1 + bed[j1];
    v2h p;
    p.x = (_Float16)h0; p.y = (_Float16)h1;
    htp[gid] = p;                            // coalesced
}

// ---------------- K_agemm: w in REGISTERS (fully-unrolled i), low block count
// grid (16 m-slices, 17 jp). Each block: load w once, loop 16 chunks x 8 m.
__global__ __launch_bounds__(256, 1) void k_agemm(const float* __restrict__ hsaugT,
                                                  const float* __restrict__ waug,
                                                  v2h* __restrict__ Ah,
                                                  float* __restrict__ A32) {
    int ms = blockIdx.x;                   // 16 slices of 128 m
    int jp = blockIdx.y;                   // 0..16
    int t  = threadIdx.x;                  // rh
    int mbase = ms * 128;
    if (jp < 16) {
        float w0[JA], w1[JA];
#pragma unroll
        for (int i = 0; i < JA; i++) {      // FULL unroll: static indices -> registers
            w0[i] = waug[(size_t)i * COLS + (2 * jp) * 256 + t];
            w1[i] = waug[(size_t)i * COLS + (2 * jp + 1) * 256 + t];
        }
#pragma unroll 1
        for (int ch = 0; ch < 16; ch++) {
            int m0 = mbase + ch * 8;
            float acc0[8], acc1[8];
#pragma unroll
            for (int ml = 0; ml < 8; ml++) { acc0[ml] = 0.f; acc1[ml] = 0.f; }
#pragma unroll
            for (int i = 0; i < JA; i++) {
                const float* hr = hsaugT + (size_t)i * 2048 + m0;   // s_load dwordx8
#pragma unroll
                for (int ml = 0; ml < 8; ml++) {
                    float hv = hr[ml];
                    acc0[ml] += hv * w0[i];
                    acc1[ml] += hv * w1[i];
                }
            }
#pragma unroll
            for (int ml = 0; ml < 8; ml++) {
                v2h p;
                p.x = (_Float16)acc0[ml]; p.y = (_Float16)acc1[ml];
                Ah[(size_t)(m0 + ml) * 4096 + jp * 256 + t] = p;
            }
        }
    } else {
        float w2[JA];
#pragma unroll
        for (int i = 0; i < JA; i++) w2[i] = waug[(size_t)i * COLS + 32 * 256 + t];
#pragma unroll 1
        for (int ch = 0; ch < 16; ch++) {
            int m0 = mbase + ch * 8;
            float acc[8];
#pragma unroll
            for (int ml = 0; ml < 8; ml++) acc[ml] = 0.f;
#pragma unroll
            for (int i = 0; i < JA; i++) {
                const float* hr = hsaugT + (size_t)i * 2048 + m0;
#pragma unroll
                for (int ml = 0; ml < 8; ml++) acc[ml] += hr[ml] * w2[i];
            }
#pragma unroll
            for (int ml = 0; ml < 8; ml++)
                A32[(size_t)(m0 + ml) * 256 + t] = acc[ml];
        }
    }
}

// ---------------- K_z: MFMA edge-tile GEMM + replicated LN-stat atomics -----
__global__ __launch_bounds__(256) void k_z(const unsigned int* __restrict__ Ah,
                                           const float* __restrict__ A32,
                                           const uint4* __restrict__ htp4,
                                           const int* __restrict__ ustart,
                                           const int2* __restrict__ eonv,
                                           _Float16* __restrict__ zh,
                                           float* __restrict__ zsumR,
                                           float* __restrict__ zsqR) {
    int t    = threadIdx.x;
    int lane = t & 63;
    int uu   = blockIdx.x * 4 + (t >> 6);
    int l15  = lane & 15, quad = lane >> 4;

    // B fragments for all 16 rh-tiles (64 VGPRs, loaded once per u)
    uint4 bf[16];
#pragma unroll
    for (int nt = 0; nt < 16; nt++) {
        const unsigned int* bp = Ah + (size_t)uu * 4096 + (quad * 4) * 256 + nt * 16 + l15;
        bf[nt].x = bp[0]; bf[nt].y = bp[256]; bf[nt].z = bp[512]; bf[nt].w = bp[768];
    }
    float a32[16];
#pragma unroll
    for (int nt = 0; nt < 16; nt++) a32[nt] = A32[(size_t)uu * 256 + nt * 16 + l15];

    float s1[16], s2[16];
#pragma unroll
    for (int nt = 0; nt < 16; nt++) { s1[nt] = 0.f; s2[nt] = 0.f; }

    int e0 = ustart[uu], e1 = ustart[uu + 1];
    for (int base = e0; base < e1; base += 16) {
        int ei = min(base + l15, e1 - 1);          // clamp: duplicate rows are idempotent
        int2 q = eonv[ei];
        uint4 afu = htp4[(size_t)q.y * 4 + quad];  // A-frag: vector dwordx4, no broadcast
        cvt8 ac; ac.u4 = afu;
        int nrow[4], valid[4];
#pragma unroll
        for (int r = 0; r < 4; r++) {
            int er = quad * 4 + r;
            nrow[r]  = __builtin_amdgcn_ds_bpermute(er << 2, q.x);   // n of D-row er
            valid[r] = (base + er) < e1;
        }
#pragma unroll
        for (int nt = 0; nt < 16; nt++) {
            cvt8 bc; bc.u4 = bf[nt];
            v4f acc = { a32[nt], a32[nt], a32[nt], a32[nt] };
            acc = __builtin_amdgcn_mfma_f32_16x16x32_f16(ac.h8, bc.h8, acc, 0, 0, 0);
#pragma unroll
            for (int r = 0; r < 4; r++) {
                if (valid[r]) {
                    float z = acc[r];
                    zh[(size_t)nrow[r] * 256 + nt * 16 + l15] = (_Float16)z;
                    s1[nt] += z; s2[nt] += z * z;
                }
            }
        }
    }
    int rep = (blockIdx.x & (NREP - 1)) * 256;     // replica slice (atomic decontention)
#pragma unroll
    for (int nt = 0; nt < 16; nt++) {
        float a = s1[nt], b = s2[nt];
        a += __shfl_xor(a, 16); a += __shfl_xor(a, 32);
        b += __shfl_xor(b, 16); b += __shfl_xor(b, 32);
        if (quad == 0) {
            atomicAdd(&zsumR[rep + nt * 16 + l15], a);
            atomicAdd(&zsqR[rep + nt * 16 + l15], b);
        }
    }
}

// ---------------- K_logit: LN (replica-sum inline) + tanh + contract --------
__global__ __launch_bounds__(256) void k_logit(const _Float16* __restrict__ zh,
                                               const float* __restrict__ zsumR,
                                               const float* __restrict__ zsqR,
                                               const float* __restrict__ ntlu,
                                               const float* __restrict__ ntlg,
                                               const float* __restrict__ ntlbe,
                                               float* __restrict__ out) {
    int t  = threadIdx.x;                 // rh = r*16+h
    int n0 = blockIdx.x * 16;
    float su = 0.f, sq = 0.f;
#pragma unroll
    for (int r = 0; r < NREP; r++) {
        su += zsumR[r * 256 + t];
        sq += zsqR[r * 256 + t];
    }
    float mu  = su / (float)E_;
    float var = sq / (float)E_ - mu * mu;
    float isd = rsqrtf(var + 1e-5f);
    float g   = ntlg[t],  be  = ntlbe[t];
    float uw  = ntlu[t];
    float zv[16];
#pragma unroll
    for (int nl = 0; nl < 16; nl++)
        zv[nl] = (float)zh[(size_t)(n0 + nl) * 256 + t];
#pragma unroll 1
    for (int nl = 0; nl < 16; nl++) {
        float zn  = g * (zv[nl] - mu) * isd + be;
        float val = uw * tanh_fast(zn);
        val += __shfl_xor(val, 1);
        val += __shfl_xor(val, 2);
        val += __shfl_xor(val, 4);
        val += __shfl_xor(val, 8);
        if ((t & 15) == 0) out[(size_t)(n0 + nl) * 16 + (t >> 4)] = val;
    }
}

// ============================ host side =====================================
extern "C" void kernel_launch(void* const* d_in, const int* in_sizes, int n_in,
                              void* d_out, int out_size, void* d_ws, size_t ws_size,
                              hipStream_t stream) {
    const int*   seq   = (const int*)d_in[0];
    const int*   p2g   = (const int*)d_in[1];
    const int*   idx   = (const int*)d_in[2];
    const int*   u     = (const int*)d_in[3];
    const int*   v     = (const int*)d_in[4];
    const float* emb   = (const float*)d_in[5];
    const float* wihf  = (const float*)d_in[6];
    const float* whhf  = (const float*)d_in[7];
    const float* bihf  = (const float*)d_in[8];
    const float* bhhf  = (const float*)d_in[9];
    const float* wihb  = (const float*)d_in[10];
    const float* whhb  = (const float*)d_in[11];
    const float* bihb  = (const float*)d_in[12];
    const float* bhhb  = (const float*)d_in[13];
    const float* wsrc  = (const float*)d_in[14];
    const float* bsrc  = (const float*)d_in[15];
    const float* wdst  = (const float*)d_in[16];
    const float* bdst  = (const float*)d_in[17];
    const float* gs    = (const float*)d_in[18];
    const float* bes   = (const float*)d_in[19];
    const float* gd    = (const float*)d_in[20];
    const float* bed   = (const float*)d_in[21];
    const float* ntlw  = (const float*)d_in[22];
    const float* ntlv  = (const float*)d_in[23];
    const float* ntlb  = (const float*)d_in[24];
    const float* ntlu  = (const float*)d_in[25];
    const float* ntlg  = (const float*)d_in[26];
    const float* ntlbe = (const float*)d_in[27];
    float* out = (float*)d_out;

    char* ws = (char*)d_ws;
    size_t off = 0;
    auto take = [&](size_t bytes) -> char* {
        char* p = ws + off;
        off = (off + bytes + 255) & ~(size_t)255;
        return p;
    };
    // zeroed region (contiguous, one memset)
    int*   cnt_u  = (int*)  take(2048 * 4);
    int*   cnt_v  = (int*)  take(2048 * 4);
    float* zsumR  = (float*)take((size_t)NREP * 256 * 4);
    float* zsqR   = (float*)take((size_t)NREP * 256 * 4);
    float* bn_raw = (float*)take(128 * 4);
    float* x_grp  = (float*)take((size_t)B_ * G_ * 64 * 4);   // accumulated via atomics
    size_t zero_bytes = off;
    // rest
    int*   ucursor = (int*)  take(2048 * 4);
    int*   ustart  = (int*)  take(2049 * 4);
    int2*  eonv    = (int2*) take((size_t)E_ * 8);
    float* pre     = (float*)take((size_t)2 * 8192 * 256 * 4);
    float* hgrp    = (float*)take((size_t)B_ * G_ * 128 * 4);
    float* Psrc    = (float*)take((size_t)M_ * 32 * 4);
    float* Pdst    = (float*)take((size_t)M_ * 32 * 4);
    float* hsaugT  = (float*)take((size_t)36 * 2048 * 4);
    v2h*   htp     = (v2h*)  take((size_t)M_ * 16 * 4);
    float* waug    = (float*)take((size_t)JA * COLS * 4);
    v2h*   Ah      = (v2h*)  take((size_t)M_ * 4096 * 4);
    float* A32     = (float*)take((size_t)M_ * 256 * 4);
    _Float16* zbuf = (_Float16*)take((size_t)E_ * 256 * 2);
    (void)ws_size; (void)in_sizes; (void)n_in; (void)out_size;

    hipMemsetAsync(d_ws, 0, zero_bytes, stream);

    k_eh<<<512 + 1089, 256, 0, stream>>>(seq, p2g, emb, u, v, ntlw, ntlv, ntlb,
                                         x_grp, cnt_u, cnt_v, waug);
    k_pre<<<513, 256, 0, stream>>>(x_grp, wihf, bihf, bhhf, wihb, bihb, bhhb, pre,
                                   cnt_u, ustart, ucursor);
    k_lstm<<<128 + E_ / 128, 128, 0, stream>>>(pre, whhf, whhb, hgrp, u, v, ucursor, eonv);
    k_gp<<<M_ / 8, 256, 0, stream>>>(idx, p2g, hgrp, cnt_u, cnt_v,
                                     wsrc, bsrc, wdst, bdst, Psrc, Pdst, bn_raw);
    k_prep<<<392, 256, 0, stream>>>(Psrc, Pdst, bn_raw, gs, bes, gd, bed, hsaugT, htp);
    k_agemm<<<dim3(16, 17), 256, 0, stream>>>(hsaugT, waug, Ah, A32);
    k_z<<<512, 256, 0, stream>>>((const unsigned int*)Ah, A32, (const uint4*)htp,
                                 ustart, eonv, zbuf, zsumR, zsqR);
    k_logit<<<E_ / 16, 256, 0, stream>>>(zbuf, zsumR, zsqR, ntlu, ntlg, ntlbe, out);
}

// Round 6
// 366.539 us; speedup vs baseline: 1.2148x; 1.0114x over previous
//
#include <hip/hip_runtime.h>
#include <hip/hip_bf16.h>
#include <hip/hip_fp16.h>
#include <cstdint>

// Problem constants
constexpr int B_   = 64;
constexpr int L_   = 512;
constexpr int G_   = 128;
constexpr int E_   = 65536;
constexpr int RH   = 256;    // NREL*NHID
constexpr int M_   = 2048;   // B*N distinct nodes
constexpr int JA   = 33;     // augmented j (32 + const-1 slot)
constexpr int COLS = RH * JA;   // 8448
constexpr int NREP = 16;     // LN-stat accumulator replicas (atomic decontention)

typedef _Float16 v2h __attribute__((ext_vector_type(2)));
typedef _Float16 v8h __attribute__((ext_vector_type(8)));
typedef float    v4f __attribute__((ext_vector_type(4)));
typedef union { uint4 u4; v8h h8; } cvt8;

#define DEV static __device__ __forceinline__

DEV float sigm(float x) { return 1.f / (1.f + __expf(-x)); }
DEV float tanh_fast(float x) {
    x = fminf(15.f, fmaxf(-15.f, x));
    float e = __expf(2.f * x);
    return (e - 1.f) / (e + 1.f);
}

// ---------------- K_eh: embed + edge histograms + waug build ----------------
// blocks 0..255: embed (4 blocks/batch, lgkm-clean inner loop);
// blocks 256..511: hist; 512..1600: waug (read-coalesced).
// waug layout: waug[i*COLS + j*256 + rh]
__global__ __launch_bounds__(256) void k_eh(const int* __restrict__ seq,
                                            const int* __restrict__ p2g,
                                            const float* __restrict__ emb,
                                            const int* __restrict__ u,
                                            const int* __restrict__ v,
                                            const float* __restrict__ ntlw,
                                            const float* __restrict__ ntlv,
                                            const float* __restrict__ ntlb,
                                            float* __restrict__ xg,
                                            int* __restrict__ cu, int* __restrict__ cv,
                                            float* __restrict__ waug) {
    int blk = blockIdx.x;
    int t   = threadIdx.x;
    if (blk >= 512) {
        int gid = (blk - 512) * 256 + t;      // j-fastest: coalesced ntlw reads
        int i   = gid / COLS;
        int rem = gid - i * COLS;
        int rh  = rem / JA;
        int j   = rem - rh * JA;
        float val;
        if (i < 32) val = (j < 32) ? ntlw[((size_t)rh * 32 + i) * 32 + j] : ntlv[rh * 64 + i];
        else        val = (j < 32) ? ntlv[rh * 64 + 32 + j] : ntlb[rh];
        waug[(size_t)i * COLS + j * 256 + rh] = val;   // scattered, L2-absorbed
        return;
    }
    if (blk >= 256) {
        int n = (blk - 256) * 256 + t;
        atomicAdd(&cu[u[n]], 1);
        atomicAdd(&cv[v[n]], 1);
        return;
    }
    // ---- embed: 4 blocks per batch, each covers 128 sequence positions ----
    __shared__ float xgl[G_ * 64];          // 32 KB partial sums
    __shared__ int sl[128], gld[128];
    int b = blk >> 2, part = blk & 3;
    for (int i = t; i < G_ * 64; i += 256) xgl[i] = 0.f;
    if (t < 128) {
        sl[t]  = seq[b * L_ + part * 128 + t];
        gld[t] = p2g[b * L_ + part * 128 + t];
    }
    __syncthreads();
    int d = t & 63, sub = t >> 6;
#pragma unroll
    for (int gg = 0; gg < 2; gg++) {
        int sv[16], gv[16];
#pragma unroll
        for (int k = 0; k < 16; k++) {       // batch LDS reads first (lgkm group)
            sv[k] = sl[sub * 32 + gg * 16 + k];
            gv[k] = gld[sub * 32 + gg * 16 + k];
        }
#pragma unroll
        for (int k = 0; k < 16; k++)         // then pure-vm loads + ds atomics
            atomicAdd(&xgl[gv[k] * 64 + d], emb[(size_t)sv[k] * 64 + d]);
    }
    __syncthreads();
    for (int i = t; i < G_ * 64; i += 256)   // flush partials (xg pre-zeroed)
        atomicAdd(&xg[(size_t)b * G_ * 64 + i], xgl[i]);
}

// ---------------- K_pre: input-gate GEMM (scalar x broadcast) + scan --------
__global__ __launch_bounds__(256) void k_pre(const float* __restrict__ xg,
                                             const float* __restrict__ wihf,
                                             const float* __restrict__ bihf,
                                             const float* __restrict__ bhhf,
                                             const float* __restrict__ wihb,
                                             const float* __restrict__ bihb,
                                             const float* __restrict__ bhhb,
                                             float* __restrict__ pre,
                                             const int* __restrict__ cu,
                                             int* __restrict__ ustart,
                                             int* __restrict__ ucursor) {
    int blk = blockIdx.x;
    int t   = threadIdx.x;
    if (blk == 512) {
        __shared__ int ps[256];
        int base = t * 8, run = 0;
        int c[8], loc[8];
#pragma unroll
        for (int i = 0; i < 8; i++) c[i] = cu[base + i];
#pragma unroll
        for (int i = 0; i < 8; i++) { loc[i] = run; run += c[i]; }
        ps[t] = run;
        __syncthreads();
        for (int off = 1; off < 256; off <<= 1) {
            int a = (t >= off) ? ps[t - off] : 0;
            __syncthreads();
            ps[t] += a;
            __syncthreads();
        }
        int ex = ps[t] - run;
#pragma unroll
        for (int i = 0; i < 8; i++) { ustart[base + i] = ex + loc[i]; ucursor[base + i] = ex + loc[i]; }
        if (t == 255) ustart[2048] = E_;
        return;
    }
    int dir = blk >> 8;
    const float* wih = dir ? wihb : wihf;
    float bias = dir ? (bihb[t] + bhhb[t]) : (bihf[t] + bhhf[t]);
    int r0 = (blk & 255) * 32;

    float4 wv[16];
#pragma unroll
    for (int c = 0; c < 16; c++) wv[c] = ((const float4*)(wih + t * 64))[c];

#pragma unroll 2
    for (int ml = 0; ml < 32; ml++) {
        const float* xr = xg + (size_t)(r0 + ml) * 64;   // wave-uniform -> s_load
        float acc = bias;
#pragma unroll
        for (int c = 0; c < 16; c++) {
            float x0 = xr[4 * c], x1 = xr[4 * c + 1], x2 = xr[4 * c + 2], x3 = xr[4 * c + 3];
            acc += x0 * wv[c].x + x1 * wv[c].y + x2 * wv[c].z + x3 * wv[c].w;
        }
        pre[((size_t)dir * 8192 + r0 + ml) * 256 + t] = acc;   // gate-major, coalesced
    }
}

// ---------------- K_lstm: 4 waves, UNIT-QUARTER split, 64 weights/lane ------
// Wave q owns ALL FOUR gates of units q*16..q*16+15: lane l = gate (l>>4) of
// unit q*16+(l&15), gate-row r=(l>>4)*64+q*16+(l&15), holding whh[r][0..63]
// as float4 wv[16] — 64 floats/lane, the size hipcc provably promotes
// (round-0: VGPR 132; every >=128-float attempt went to scratch).
// c/h update: the 4 gate values of a unit sit in lanes {k,16+k,32+k,48+k} of
// the SAME wave -> 4 intra-wave __shfl, no LDS. Only the new h crosses
// waves: 16 floats/wave to a 64-float LDS buffer, ONE barrier, 1 ds_read.
// pre is read via 2-deep global register prefetch (no plds staging).
// blocks 128..383: edge counting-sort rider.
__global__ __launch_bounds__(256, 1) void k_lstm(const float* __restrict__ pre,
                                                 const float* __restrict__ whh_f,
                                                 const float* __restrict__ whh_b,
                                                 float* __restrict__ hgrp,
                                                 const int* __restrict__ u,
                                                 const int* __restrict__ v,
                                                 int* __restrict__ ucursor,
                                                 int2* __restrict__ eonv) {
    int blk = blockIdx.x;
    int t   = threadIdx.x;
    if (blk >= 128) {
        int n = (blk - 128) * 256 + t;
        int pos = atomicAdd(&ucursor[u[n]], 1);
        eonv[pos] = make_int2(n, v[n]);
        return;
    }
    __shared__ float hx[2][64];          // h exchange, double-buffered (512 B)
    int l    = t & 63;                   // lane in wave
    int q    = t >> 6;                   // wave id = unit quarter
    int gate = l >> 4;                   // 0:i 1:f 2:g 3:o
    int k    = l & 15;
    int unit = q * 16 + k;               // owned unit
    int r    = gate * 64 + unit;         // gate-row in whh / pre column
    int dir  = blk >> 6;
    int b    = blk & 63;
    const float* whh     = dir ? whh_b : whh_f;
    const float* prebase = pre + ((size_t)dir * 8192 + (size_t)b * G_) * 256;

    float4 wv[16];                       // whh[r][0..63] — 64 VGPRs
#pragma unroll
    for (int c = 0; c < 16; c++) wv[c] = ((const float4*)(whh + (size_t)r * 64))[c];

    float hreg = 0.f;                    // lane l holds h[l] (full copy per wave)
    float creg = 0.f;                    // c for owned unit (replicated x4)

    // ---- 2-deep prefetch of pre-activation column r -----------------------
    int s0i = dir ? (G_ - 1) : 0;
    int s1i = dir ? (G_ - 2) : 1;
    float pq = prebase[(size_t)s0i * 256 + r];
    float pr = prebase[(size_t)s1i * 256 + r];

#pragma unroll 1
    for (int step = 0; step < G_; step++) {
        int s  = dir ? (G_ - 1 - step) : step;
        int t2 = (step + 2 < G_) ? step + 2 : G_ - 1;
        int s2 = dir ? (G_ - 1 - t2) : t2;
        float pn = prebase[(size_t)s2 * 256 + r];   // consumed 2 iters later

        // ---- matvec: 64 readlane + 64 fmac, 4 acc chains ------------------
        float a0 = pq, a1 = 0.f, a2 = 0.f, a3 = 0.f;
#pragma unroll
        for (int c = 0; c < 16; c++) {
            float h0 = __int_as_float(__builtin_amdgcn_readlane(__float_as_int(hreg), 4 * c + 0));
            float h1 = __int_as_float(__builtin_amdgcn_readlane(__float_as_int(hreg), 4 * c + 1));
            float h2 = __int_as_float(__builtin_amdgcn_readlane(__float_as_int(hreg), 4 * c + 2));
            float h3 = __int_as_float(__builtin_amdgcn_readlane(__float_as_int(hreg), 4 * c + 3));
            a0 += wv[c].x * h0;
            a1 += wv[c].y * h1;
            a2 += wv[c].z * h2;
            a3 += wv[c].w * h3;
        }
        float gpre = (a0 + a1) + (a2 + a3);
        float gval = (gate == 2) ? tanh_fast(gpre) : sigm(gpre);

        // ---- gather 4 gates of owned unit (same wave) + update ------------
        float gi = __shfl(gval, k);
        float gf = __shfl(gval, 16 + k);
        float gg = __shfl(gval, 32 + k);
        float go = __shfl(gval, 48 + k);
        creg = gf * creg + gi * gg;
        float hnew = go * tanh_fast(creg);

        if (gate == 0) {
            hgrp[((size_t)(b * G_ + s)) * 128 + dir * 64 + unit] = hnew;
            hx[step & 1][unit] = hnew;
        }
        __syncthreads();
        hreg = hx[step & 1][l];          // refresh full h copy

        pq = pr; pr = pn;                // rotate prefetch stages
    }
}

// ---------------- K_gp: gather + projections + BN partial stats (fused) -----
__global__ __launch_bounds__(256) void k_gp(const int* __restrict__ idx,
                                            const int* __restrict__ p2g,
                                            const float* __restrict__ hgrp,
                                            const int* __restrict__ cu,
                                            const int* __restrict__ cv,
                                            const float* __restrict__ wsrc,
                                            const float* __restrict__ bsrc,
                                            const float* __restrict__ wdst,
                                            const float* __restrict__ bdst,
                                            float* __restrict__ Ps, float* __restrict__ Pd,
                                            float* __restrict__ bn_raw) {
    __shared__ __align__(16) float hsl[8][128];
    __shared__ float red[256];
    int m0 = blockIdx.x * 8;
    int t  = threadIdx.x;
    int d = t & 127, mh = t >> 7;
#pragma unroll
    for (int rep = 0; rep < 4; rep++) {
        int ml = rep * 2 + mh;
        int m  = m0 + ml;
        int b  = m >> 5;
        float acc = 0.f;
#pragma unroll
        for (int k = 0; k < 8; k++) {
            int l = idx[m * 8 + k];
            int g = p2g[b * L_ + l];
            acc += hgrp[((size_t)b * G_ + g) * 128 + d];
        }
        hsl[ml][d] = acc;
    }
    __syncthreads();
    int ml = t >> 5, o = t & 31;
    int m  = m0 + ml;
    const float4* hp = (const float4*)&hsl[ml][0];
    float cw_u = (float)cu[m], cw_v = (float)cv[m];
#pragma unroll 1
    for (int side = 0; side < 2; side++) {
        const float* W = side ? wdst : wsrc;
        float4 wr[32];
#pragma unroll
        for (int c = 0; c < 32; c++) wr[c] = ((const float4*)(W + (size_t)o * 128))[c];
        float acc = side ? bdst[o] : bsrc[o];
#pragma unroll
        for (int c = 0; c < 32; c++) {
            float4 h4 = hp[c];
            acc += h4.x * wr[c].x + h4.y * wr[c].y + h4.z * wr[c].z + h4.w * wr[c].w;
        }
        (side ? Pd : Ps)[(size_t)m * 32 + o] = acc;
        float cw = side ? cw_v : cw_u;
        red[t] = cw * acc;
        __syncthreads();
        if (t < 32) {
            float s = 0.f;
#pragma unroll
            for (int i = 0; i < 8; i++) s += red[i * 32 + t];
            atomicAdd(&bn_raw[side * 64 + t], s);
        }
        __syncthreads();
        red[t] = cw * acc * acc;
        __syncthreads();
        if (t < 32) {
            float s = 0.f;
#pragma unroll
            for (int i = 0; i < 8; i++) s += red[i * 32 + t];
            atomicAdd(&bn_raw[side * 64 + 32 + t], s);
        }
        __syncthreads();
    }
}

// ---------------- K_prep: BN-normalize; build hsaugT[i][m] and htp (f16x2) --
__global__ __launch_bounds__(256) void k_prep(const float* __restrict__ Ps,
                                              const float* __restrict__ Pd,
                                              const float* __restrict__ bn_raw,
                                              const float* __restrict__ gs,
                                              const float* __restrict__ bes,
                                              const float* __restrict__ gd,
                                              const float* __restrict__ bed,
                                              float* __restrict__ hsaugT,
                                              v2h* __restrict__ htp) {
    int blk = blockIdx.x;
    int t   = threadIdx.x;
    constexpr float invE = 1.f / (float)E_;
    if (blk < 264) {                        // 264*256 = 33*2048
        int gid = blk * 256 + t;
        int c = gid >> 11;                   // 0..32
        int m = gid & 2047;
        float val = 1.f;
        if (c < 32) {
            float mu  = bn_raw[c] * invE;
            float isd = rsqrtf(bn_raw[32 + c] * invE - mu * mu + 1e-5f);
            val = gs[c] * (Ps[(size_t)m * 32 + c] - mu) * isd + bes[c];
        }
        hsaugT[(size_t)c * 2048 + m] = val;   // coalesced over m
        return;
    }
    int gid = (blk - 264) * 256 + t;         // 128*256 = 2048*16
    int m  = gid >> 4;
    int jp = gid & 15;
    int j0 = 2 * jp, j1 = 2 * jp + 1;
    float mu0  = bn_raw[64 + j0] * invE;
    float isd0 = rsqrtf(bn_raw[96 + j0] * invE - mu0 * mu0 + 1e-5f);
    float mu1  = bn_raw[64 + j1] * invE;
    float isd1 = rsqrtf(bn_raw[96 + j1] * invE - mu1 * mu1 + 1e-5f);
    float h0 = gd[j0] * (Pd[(size_t)m * 32 + j0] - mu0) * isd0 + bed[j0];
    float h1 = gd[j1] * (Pd[(size_t)m * 32 + j1] - mu1) * isd1 + bed[j1];
    v2h p;
    p.x = (_Float16)h0; p.y = (_Float16)h1;
    htp[gid] = p;                            // coalesced
}

// ---------------- K_agemm: w in REGISTERS (fully-unrolled i), low block count
// grid (16 m-slices, 17 jp). Each block: load w once, loop 16 chunks x 8 m.
__global__ __launch_bounds__(256, 1) void k_agemm(const float* __restrict__ hsaugT,
                                                  const float* __restrict__ waug,
                                                  v2h* __restrict__ Ah,
                                                  float* __restrict__ A32) {
    int ms = blockIdx.x;                   // 16 slices of 128 m
    int jp = blockIdx.y;                   // 0..16
    int t  = threadIdx.x;                  // rh
    int mbase = ms * 128;
    if (jp < 16) {
        float w0[JA], w1[JA];
#pragma unroll
        for (int i = 0; i < JA; i++) {      // FULL unroll: static indices -> registers
            w0[i] = waug[(size_t)i * COLS + (2 * jp) * 256 + t];
            w1[i] = waug[(size_t)i * COLS + (2 * jp + 1) * 256 + t];
        }
#pragma unroll 1
        for (int ch = 0; ch < 16; ch++) {
            int m0 = mbase + ch * 8;
            float acc0[8], acc1[8];
#pragma unroll
            for (int ml = 0; ml < 8; ml++) { acc0[ml] = 0.f; acc1[ml] = 0.f; }
#pragma unroll
            for (int i = 0; i < JA; i++) {
                const float* hr = hsaugT + (size_t)i * 2048 + m0;   // s_load dwordx8
#pragma unroll
                for (int ml = 0; ml < 8; ml++) {
                    float hv = hr[ml];
                    acc0[ml] += hv * w0[i];
                    acc1[ml] += hv * w1[i];
                }
            }
#pragma unroll
            for (int ml = 0; ml < 8; ml++) {
                v2h p;
                p.x = (_Float16)acc0[ml]; p.y = (_Float16)acc1[ml];
                Ah[(size_t)(m0 + ml) * 4096 + jp * 256 + t] = p;
            }
        }
    } else {
        float w2[JA];
#pragma unroll
        for (int i = 0; i < JA; i++) w2[i] = waug[(size_t)i * COLS + 32 * 256 + t];
#pragma unroll 1
        for (int ch = 0; ch < 16; ch++) {
            int m0 = mbase + ch * 8;
            float acc[8];
#pragma unroll
            for (int ml = 0; ml < 8; ml++) acc[ml] = 0.f;
#pragma unroll
            for (int i = 0; i < JA; i++) {
                const float* hr = hsaugT + (size_t)i * 2048 + m0;
#pragma unroll
                for (int ml = 0; ml < 8; ml++) acc[ml] += hr[ml] * w2[i];
            }
#pragma unroll
            for (int ml = 0; ml < 8; ml++)
                A32[(size_t)(m0 + ml) * 256 + t] = acc[ml];
        }
    }
}

// ---------------- K_z: MFMA edge-tile GEMM + replicated LN-stat atomics -----
__global__ __launch_bounds__(256) void k_z(const unsigned int* __restrict__ Ah,
                                           const float* __restrict__ A32,
                                           const uint4* __restrict__ htp4,
                                           const int* __restrict__ ustart,
                                           const int2* __restrict__ eonv,
                                           _Float16* __restrict__ zh,
                                           float* __restrict__ zsumR,
                                           float* __restrict__ zsqR) {
    int t    = threadIdx.x;
    int lane = t & 63;
    int uu   = blockIdx.x * 4 + (t >> 6);
    int l15  = lane & 15, quad = lane >> 4;

    // B fragments for all 16 rh-tiles (64 VGPRs, loaded once per u)
    uint4 bf[16];
#pragma unroll
    for (int nt = 0; nt < 16; nt++) {
        const unsigned int* bp = Ah + (size_t)uu * 4096 + (quad * 4) * 256 + nt * 16 + l15;
        bf[nt].x = bp[0]; bf[nt].y = bp[256]; bf[nt].z = bp[512]; bf[nt].w = bp[768];
    }
    float a32[16];
#pragma unroll
    for (int nt = 0; nt < 16; nt++) a32[nt] = A32[(size_t)uu * 256 + nt * 16 + l15];

    float s1[16], s2[16];
#pragma unroll
    for (int nt = 0; nt < 16; nt++) { s1[nt] = 0.f; s2[nt] = 0.f; }

    int e0 = ustart[uu], e1 = ustart[uu + 1];
    for (int base = e0; base < e1; base += 16) {
        int ei = min(base + l15, e1 - 1);          // clamp: duplicate rows are idempotent
        int2 q = eonv[ei];
        uint4 afu = htp4[(size_t)q.y * 4 + quad];  // A-frag: vector dwordx4, no broadcast
        cvt8 ac; ac.u4 = afu;
        int nrow[4], valid[4];
#pragma unroll
        for (int r = 0; r < 4; r++) {
            int er = quad * 4 + r;
            nrow[r]  = __builtin_amdgcn_ds_bpermute(er << 2, q.x);   // n of D-row er
            valid[r] = (base + er) < e1;
        }
#pragma unroll
        for (int nt = 0; nt < 16; nt++) {
            cvt8 bc; bc.u4 = bf[nt];
            v4f acc = { a32[nt], a32[nt], a32[nt], a32[nt] };
            acc = __builtin_amdgcn_mfma_f32_16x16x32_f16(ac.h8, bc.h8, acc, 0, 0, 0);
#pragma unroll
            for (int r = 0; r < 4; r++) {
                if (valid[r]) {
                    float z = acc[r];
                    zh[(size_t)nrow[r] * 256 + nt * 16 + l15] = (_Float16)z;
                    s1[nt] += z; s2[nt] += z * z;
                }
            }
        }
    }
    int rep = (blockIdx.x & (NREP - 1)) * 256;     // replica slice (atomic decontention)
#pragma unroll
    for (int nt = 0; nt < 16; nt++) {
        float a = s1[nt], b = s2[nt];
        a += __shfl_xor(a, 16); a += __shfl_xor(a, 32);
        b += __shfl_xor(b, 16); b += __shfl_xor(b, 32);
        if (quad == 0) {
            atomicAdd(&zsumR[rep + nt * 16 + l15], a);
            atomicAdd(&zsqR[rep + nt * 16 + l15], b);
        }
    }
}

// ---------------- K_logit: LN (replica-sum inline) + tanh + contract --------
__global__ __launch_bounds__(256) void k_logit(const _Float16* __restrict__ zh,
                                               const float* __restrict__ zsumR,
                                               const float* __restrict__ zsqR,
                                               const float* __restrict__ ntlu,
                                               const float* __restrict__ ntlg,
                                               const float* __restrict__ ntlbe,
                                               float* __restrict__ out) {
    int t  = threadIdx.x;                 // rh = r*16+h
    int n0 = blockIdx.x * 16;
    float su = 0.f, sq = 0.f;
#pragma unroll
    for (int r = 0; r < NREP; r++) {
        su += zsumR[r * 256 + t];
        sq += zsqR[r * 256 + t];
    }
    float mu  = su / (float)E_;
    float var = sq / (float)E_ - mu * mu;
    float isd = rsqrtf(var + 1e-5f);
    float g   = ntlg[t],  be  = ntlbe[t];
    float uw  = ntlu[t];
    float zv[16];
#pragma unroll
    for (int nl = 0; nl < 16; nl++)
        zv[nl] = (float)zh[(size_t)(n0 + nl) * 256 + t];
#pragma unroll 1
    for (int nl = 0; nl < 16; nl++) {
        float zn  = g * (zv[nl] - mu) * isd + be;
        float val = uw * tanh_fast(zn);
        val += __shfl_xor(val, 1);
        val += __shfl_xor(val, 2);
        val += __shfl_xor(val, 4);
        val += __shfl_xor(val, 8);
        if ((t & 15) == 0) out[(size_t)(n0 + nl) * 16 + (t >> 4)] = val;
    }
}

// ============================ host side =====================================
extern "C" void kernel_launch(void* const* d_in, const int* in_sizes, int n_in,
                              void* d_out, int out_size, void* d_ws, size_t ws_size,
                              hipStream_t stream) {
    const int*   seq   = (const int*)d_in[0];
    const int*   p2g   = (const int*)d_in[1];
    const int*   idx   = (const int*)d_in[2];
    const int*   u     = (const int*)d_in[3];
    const int*   v     = (const int*)d_in[4];
    const float* emb   = (const float*)d_in[5];
    const float* wihf  = (const float*)d_in[6];
    const float* whhf  = (const float*)d_in[7];
    const float* bihf  = (const float*)d_in[8];
    const float* bhhf  = (const float*)d_in[9];
    const float* wihb  = (const float*)d_in[10];
    const float* whhb  = (const float*)d_in[11];
    const float* bihb  = (const float*)d_in[12];
    const float* bhhb  = (const float*)d_in[13];
    const float* wsrc  = (const float*)d_in[14];
    const float* bsrc  = (const float*)d_in[15];
    const float* wdst  = (const float*)d_in[16];
    const float* bdst  = (const float*)d_in[17];
    const float* gs    = (const float*)d_in[18];
    const float* bes   = (const float*)d_in[19];
    const float* gd    = (const float*)d_in[20];
    const float* bed   = (const float*)d_in[21];
    const float* ntlw  = (const float*)d_in[22];
    const float* ntlv  = (const float*)d_in[23];
    const float* ntlb  = (const float*)d_in[24];
    const float* ntlu  = (const float*)d_in[25];
    const float* ntlg  = (const float*)d_in[26];
    const float* ntlbe = (const float*)d_in[27];
    float* out = (float*)d_out;

    char* ws = (char*)d_ws;
    size_t off = 0;
    auto take = [&](size_t bytes) -> char* {
        char* p = ws + off;
        off = (off + bytes + 255) & ~(size_t)255;
        return p;
    };
    // zeroed region (contiguous, one memset)
    int*   cnt_u  = (int*)  take(2048 * 4);
    int*   cnt_v  = (int*)  take(2048 * 4);
    float* zsumR  = (float*)take((size_t)NREP * 256 * 4);
    float* zsqR   = (float*)take((size_t)NREP * 256 * 4);
    float* bn_raw = (float*)take(128 * 4);
    float* x_grp  = (float*)take((size_t)B_ * G_ * 64 * 4);   // accumulated via atomics
    size_t zero_bytes = off;
    // rest
    int*   ucursor = (int*)  take(2048 * 4);
    int*   ustart  = (int*)  take(2049 * 4);
    int2*  eonv    = (int2*) take((size_t)E_ * 8);
    float* pre     = (float*)take((size_t)2 * 8192 * 256 * 4);
    float* hgrp    = (float*)take((size_t)B_ * G_ * 128 * 4);
    float* Psrc    = (float*)take((size_t)M_ * 32 * 4);
    float* Pdst    = (float*)take((size_t)M_ * 32 * 4);
    float* hsaugT  = (float*)take((size_t)36 * 2048 * 4);
    v2h*   htp     = (v2h*)  take((size_t)M_ * 16 * 4);
    float* waug    = (float*)take((size_t)JA * COLS * 4);
    v2h*   Ah      = (v2h*)  take((size_t)M_ * 4096 * 4);
    float* A32     = (float*)take((size_t)M_ * 256 * 4);
    _Float16* zbuf = (_Float16*)take((size_t)E_ * 256 * 2);
    (void)ws_size; (void)in_sizes; (void)n_in; (void)out_size;

    hipMemsetAsync(d_ws, 0, zero_bytes, stream);

    k_eh<<<512 + 1089, 256, 0, stream>>>(seq, p2g, emb, u, v, ntlw, ntlv, ntlb,
                                         x_grp, cnt_u, cnt_v, waug);
    k_pre<<<513, 256, 0, stream>>>(x_grp, wihf, bihf, bhhf, wihb, bihb, bhhb, pre,
                                   cnt_u, ustart, ucursor);
    k_lstm<<<384, 256, 0, stream>>>(pre, whhf, whhb, hgrp, u, v, ucursor, eonv);
    k_gp<<<M_ / 8, 256, 0, stream>>>(idx, p2g, hgrp, cnt_u, cnt_v,
                                     wsrc, bsrc, wdst, bdst, Psrc, Pdst, bn_raw);
    k_prep<<<392, 256, 0, stream>>>(Psrc, Pdst, bn_raw, gs, bes, gd, bed, hsaugT, htp);
    k_agemm<<<dim3(16, 17), 256, 0, stream>>>(hsaugT, waug, Ah, A32);
    k_z<<<512, 256, 0, stream>>>((const unsigned int*)Ah, A32, (const uint4*)htp,
                                 ustart, eonv, zbuf, zsumR, zsqR);
    k_logit<<<E_ / 16, 256, 0, stream>>>(zbuf, zsumR, zsqR, ntlu, ntlg, ntlbe, out);
}

// Round 7
// 360.491 us; speedup vs baseline: 1.2352x; 1.0168x over previous
//
#include <hip/hip_runtime.h>
#include <hip/hip_bf16.h>
#include <hip/hip_fp16.h>
#include <cstdint>

// Problem constants
constexpr int B_   = 64;
constexpr int L_   = 512;
constexpr int G_   = 128;
constexpr int E_   = 65536;
constexpr int RH   = 256;    // NREL*NHID
constexpr int M_   = 2048;   // B*N distinct nodes
constexpr int JA   = 33;     // augmented j (32 + const-1 slot)
constexpr int COLS = RH * JA;   // 8448
constexpr int NREP = 16;     // LN-stat accumulator replicas (atomic decontention)

typedef _Float16 v2h __attribute__((ext_vector_type(2)));
typedef _Float16 v8h __attribute__((ext_vector_type(8)));
typedef float    v4f __attribute__((ext_vector_type(4)));
typedef union { uint4 u4; v8h h8; } cvt8;

#define DEV static __device__ __forceinline__

DEV float sigm(float x) { return 1.f / (1.f + __expf(-x)); }
DEV float tanh_fast(float x) {
    x = fminf(15.f, fmaxf(-15.f, x));
    float e = __expf(2.f * x);
    return (e - 1.f) / (e + 1.f);
}

// ---------------- K_eh: embed + edge histograms + waug build ----------------
// blocks 0..255: embed (4 blocks/batch, lgkm-clean inner loop);
// blocks 256..511: hist; 512..1600: waug (read-coalesced).
// waug layout: waug[i*COLS + j*256 + rh]
__global__ __launch_bounds__(256) void k_eh(const int* __restrict__ seq,
                                            const int* __restrict__ p2g,
                                            const float* __restrict__ emb,
                                            const int* __restrict__ u,
                                            const int* __restrict__ v,
                                            const float* __restrict__ ntlw,
                                            const float* __restrict__ ntlv,
                                            const float* __restrict__ ntlb,
                                            float* __restrict__ xg,
                                            int* __restrict__ cu, int* __restrict__ cv,
                                            float* __restrict__ waug) {
    int blk = blockIdx.x;
    int t   = threadIdx.x;
    if (blk >= 512) {
        int gid = (blk - 512) * 256 + t;      // j-fastest: coalesced ntlw reads
        int i   = gid / COLS;
        int rem = gid - i * COLS;
        int rh  = rem / JA;
        int j   = rem - rh * JA;
        float val;
        if (i < 32) val = (j < 32) ? ntlw[((size_t)rh * 32 + i) * 32 + j] : ntlv[rh * 64 + i];
        else        val = (j < 32) ? ntlv[rh * 64 + 32 + j] : ntlb[rh];
        waug[(size_t)i * COLS + j * 256 + rh] = val;   // scattered, L2-absorbed
        return;
    }
    if (blk >= 256) {
        int n = (blk - 256) * 256 + t;
        atomicAdd(&cu[u[n]], 1);
        atomicAdd(&cv[v[n]], 1);
        return;
    }
    // ---- embed: 4 blocks per batch, each covers 128 sequence positions ----
    __shared__ float xgl[G_ * 64];          // 32 KB partial sums
    __shared__ int sl[128], gld[128];
    int b = blk >> 2, part = blk & 3;
    for (int i = t; i < G_ * 64; i += 256) xgl[i] = 0.f;
    if (t < 128) {
        sl[t]  = seq[b * L_ + part * 128 + t];
        gld[t] = p2g[b * L_ + part * 128 + t];
    }
    __syncthreads();
    int d = t & 63, sub = t >> 6;
#pragma unroll
    for (int gg = 0; gg < 2; gg++) {
        int sv[16], gv[16];
#pragma unroll
        for (int k = 0; k < 16; k++) {       // batch LDS reads first (lgkm group)
            sv[k] = sl[sub * 32 + gg * 16 + k];
            gv[k] = gld[sub * 32 + gg * 16 + k];
        }
#pragma unroll
        for (int k = 0; k < 16; k++)         // then pure-vm loads + ds atomics
            atomicAdd(&xgl[gv[k] * 64 + d], emb[(size_t)sv[k] * 64 + d]);
    }
    __syncthreads();
    for (int i = t; i < G_ * 64; i += 256)   // flush partials (xg pre-zeroed)
        atomicAdd(&xg[(size_t)b * G_ * 64 + i], xgl[i]);
}

// ---------------- K_pre: input-gate GEMM (scalar x broadcast) + scan --------
__global__ __launch_bounds__(256) void k_pre(const float* __restrict__ xg,
                                             const float* __restrict__ wihf,
                                             const float* __restrict__ bihf,
                                             const float* __restrict__ bhhf,
                                             const float* __restrict__ wihb,
                                             const float* __restrict__ bihb,
                                             const float* __restrict__ bhhb,
                                             float* __restrict__ pre,
                                             const int* __restrict__ cu,
                                             int* __restrict__ ustart,
                                             int* __restrict__ ucursor) {
    int blk = blockIdx.x;
    int t   = threadIdx.x;
    if (blk == 512) {
        __shared__ int ps[256];
        int base = t * 8, run = 0;
        int c[8], loc[8];
#pragma unroll
        for (int i = 0; i < 8; i++) c[i] = cu[base + i];
#pragma unroll
        for (int i = 0; i < 8; i++) { loc[i] = run; run += c[i]; }
        ps[t] = run;
        __syncthreads();
        for (int off = 1; off < 256; off <<= 1) {
            int a = (t >= off) ? ps[t - off] : 0;
            __syncthreads();
            ps[t] += a;
            __syncthreads();
        }
        int ex = ps[t] - run;
#pragma unroll
        for (int i = 0; i < 8; i++) { ustart[base + i] = ex + loc[i]; ucursor[base + i] = ex + loc[i]; }
        if (t == 255) ustart[2048] = E_;
        return;
    }
    int dir = blk >> 8;
    const float* wih = dir ? wihb : wihf;
    float bias = dir ? (bihb[t] + bhhb[t]) : (bihf[t] + bhhf[t]);
    int r0 = (blk & 255) * 32;

    float4 wv[16];
#pragma unroll
    for (int c = 0; c < 16; c++) wv[c] = ((const float4*)(wih + t * 64))[c];

#pragma unroll 2
    for (int ml = 0; ml < 32; ml++) {
        const float* xr = xg + (size_t)(r0 + ml) * 64;   // wave-uniform -> s_load
        float acc = bias;
#pragma unroll
        for (int c = 0; c < 16; c++) {
            float x0 = xr[4 * c], x1 = xr[4 * c + 1], x2 = xr[4 * c + 2], x3 = xr[4 * c + 3];
            acc += x0 * wv[c].x + x1 * wv[c].y + x2 * wv[c].z + x3 * wv[c].w;
        }
        pre[((size_t)dir * 8192 + r0 + ml) * 256 + t] = acc;   // gate-major, coalesced
    }
}

// ---------------- K_lstm: round-0 skeleton, slim memory plumbing ------------
// Wave q = gate q for all 64 units (lane row = t, WAVE-UNIFORM nonlinearity
// branch — the round-0 configuration, the only one measured to promote
// wv[16] to VGPRs: VGPR 132 there vs 44-148 for every variant with lane-
// divergent gates or >=128 floats/lane). Changes vs round 0, memory only:
//   plds[64][256] staging  -> 2-deep global register prefetch of column t
//   hist[64][64] + store loops -> direct coalesced hgrp store from wave 0
// Per step: matvec (64 readlane + 64 fmac) + gl write + ONE barrier + 4 gl
// reads + redundant c/h update in all 4 waves.
// blocks 128..383: edge counting-sort rider.
__global__ __launch_bounds__(256, 1) void k_lstm(const float* __restrict__ pre,
                                                 const float* __restrict__ whh_f,
                                                 const float* __restrict__ whh_b,
                                                 float* __restrict__ hgrp,
                                                 const int* __restrict__ u,
                                                 const int* __restrict__ v,
                                                 int* __restrict__ ucursor,
                                                 int2* __restrict__ eonv) {
    int blk = blockIdx.x;
    int t   = threadIdx.x;
    if (blk >= 128) {
        int n = (blk - 128) * 256 + t;
        int pos = atomicAdd(&ucursor[u[n]], 1);
        eonv[pos] = make_int2(n, v[n]);
        return;
    }
    __shared__ float gl[2][256];         // gate exchange, double-buffered (2 KB)
    int q   = t >> 6;                    // wave id = gate (0:i 1:f 2:g 3:o)
    int e   = t & 63;                    // unit
    int dir = blk >> 6;
    int b   = blk & 63;
    const float* whh     = dir ? whh_b : whh_f;
    const float* prebase = pre + ((size_t)dir * 8192 + (size_t)b * G_) * 256;

    float4 wv[16];                       // whh row t — round-0 exact load shape
#pragma unroll
    for (int c = 0; c < 16; c++) wv[c] = ((const float4*)(whh + t * 64))[c];

    float h = 0.f, creg = 0.f;

    // ---- 2-deep prefetch of pre-activation column t ------------------------
    int s0i = dir ? (G_ - 1) : 0;
    int s1i = dir ? (G_ - 2) : 1;
    float pq = prebase[(size_t)s0i * 256 + t];
    float pr = prebase[(size_t)s1i * 256 + t];

#pragma unroll 1
    for (int step = 0; step < G_; step++) {
        int s  = dir ? (G_ - 1 - step) : step;
        int t2 = (step + 2 < G_) ? step + 2 : G_ - 1;
        int s2 = dir ? (G_ - 1 - t2) : t2;
        float pn = prebase[(size_t)s2 * 256 + t];   // consumed 2 iters later

        // ---- matvec: 64 readlane + 64 fmac, 4 acc chains (round-0 shape) --
        float a0 = pq, a1 = 0.f, a2 = 0.f, a3 = 0.f;
#pragma unroll
        for (int c = 0; c < 16; c++) {
            float f0 = __int_as_float(__builtin_amdgcn_readlane(__float_as_int(h), 4 * c + 0));
            float f1 = __int_as_float(__builtin_amdgcn_readlane(__float_as_int(h), 4 * c + 1));
            float f2 = __int_as_float(__builtin_amdgcn_readlane(__float_as_int(h), 4 * c + 2));
            float f3 = __int_as_float(__builtin_amdgcn_readlane(__float_as_int(h), 4 * c + 3));
            a0 += wv[c].x * f0;
            a1 += wv[c].y * f1;
            a2 += wv[c].z * f2;
            a3 += wv[c].w * f3;
        }
        float g = (a0 + a1) + (a2 + a3);
        gl[step & 1][t] = (q == 2) ? tanh_fast(g) : sigm(g);   // wave-uniform
        __syncthreads();
        float ai = gl[step & 1][e];
        float af = gl[step & 1][64 + e];
        float ag = gl[step & 1][128 + e];
        float ao = gl[step & 1][192 + e];
        creg = af * creg + ai * ag;      // identical in all 4 waves
        h    = ao * tanh_fast(creg);
        if (q == 0)                      // direct coalesced 256 B store
            hgrp[((size_t)(b * G_ + s)) * 128 + dir * 64 + e] = h;

        pq = pr; pr = pn;                // rotate prefetch stages
    }
}

// ---------------- K_gp: gather + projections + BN partial stats (fused) -----
__global__ __launch_bounds__(256) void k_gp(const int* __restrict__ idx,
                                            const int* __restrict__ p2g,
                                            const float* __restrict__ hgrp,
                                            const int* __restrict__ cu,
                                            const int* __restrict__ cv,
                                            const float* __restrict__ wsrc,
                                            const float* __restrict__ bsrc,
                                            const float* __restrict__ wdst,
                                            const float* __restrict__ bdst,
                                            float* __restrict__ Ps, float* __restrict__ Pd,
                                            float* __restrict__ bn_raw) {
    __shared__ __align__(16) float hsl[8][128];
    __shared__ float red[256];
    int m0 = blockIdx.x * 8;
    int t  = threadIdx.x;
    int d = t & 127, mh = t >> 7;
#pragma unroll
    for (int rep = 0; rep < 4; rep++) {
        int ml = rep * 2 + mh;
        int m  = m0 + ml;
        int b  = m >> 5;
        float acc = 0.f;
#pragma unroll
        for (int k = 0; k < 8; k++) {
            int l = idx[m * 8 + k];
            int g = p2g[b * L_ + l];
            acc += hgrp[((size_t)b * G_ + g) * 128 + d];
        }
        hsl[ml][d] = acc;
    }
    __syncthreads();
    int ml = t >> 5, o = t & 31;
    int m  = m0 + ml;
    const float4* hp = (const float4*)&hsl[ml][0];
    float cw_u = (float)cu[m], cw_v = (float)cv[m];
#pragma unroll 1
    for (int side = 0; side < 2; side++) {
        const float* W = side ? wdst : wsrc;
        float4 wr[32];
#pragma unroll
        for (int c = 0; c < 32; c++) wr[c] = ((const float4*)(W + (size_t)o * 128))[c];
        float acc = side ? bdst[o] : bsrc[o];
#pragma unroll
        for (int c = 0; c < 32; c++) {
            float4 h4 = hp[c];
            acc += h4.x * wr[c].x + h4.y * wr[c].y + h4.z * wr[c].z + h4.w * wr[c].w;
        }
        (side ? Pd : Ps)[(size_t)m * 32 + o] = acc;
        float cw = side ? cw_v : cw_u;
        red[t] = cw * acc;
        __syncthreads();
        if (t < 32) {
            float s = 0.f;
#pragma unroll
            for (int i = 0; i < 8; i++) s += red[i * 32 + t];
            atomicAdd(&bn_raw[side * 64 + t], s);
        }
        __syncthreads();
        red[t] = cw * acc * acc;
        __syncthreads();
        if (t < 32) {
            float s = 0.f;
#pragma unroll
            for (int i = 0; i < 8; i++) s += red[i * 32 + t];
            atomicAdd(&bn_raw[side * 64 + 32 + t], s);
        }
        __syncthreads();
    }
}

// ---------------- K_prep: BN-normalize; build hsaugT[i][m] and htp (f16x2) --
__global__ __launch_bounds__(256) void k_prep(const float* __restrict__ Ps,
                                              const float* __restrict__ Pd,
                                              const float* __restrict__ bn_raw,
                                              const float* __restrict__ gs,
                                              const float* __restrict__ bes,
                                              const float* __restrict__ gd,
                                              const float* __restrict__ bed,
                                              float* __restrict__ hsaugT,
                                              v2h* __restrict__ htp) {
    int blk = blockIdx.x;
    int t   = threadIdx.x;
    constexpr float invE = 1.f / (float)E_;
    if (blk < 264) {                        // 264*256 = 33*2048
        int gid = blk * 256 + t;
        int c = gid >> 11;                   // 0..32
        int m = gid & 2047;
        float val = 1.f;
        if (c < 32) {
            float mu  = bn_raw[c] * invE;
            float isd = rsqrtf(bn_raw[32 + c] * invE - mu * mu + 1e-5f);
            val = gs[c] * (Ps[(size_t)m * 32 + c] - mu) * isd + bes[c];
        }
        hsaugT[(size_t)c * 2048 + m] = val;   // coalesced over m
        return;
    }
    int gid = (blk - 264) * 256 + t;         // 128*256 = 2048*16
    int m  = gid >> 4;
    int jp = gid & 15;
    int j0 = 2 * jp, j1 = 2 * jp + 1;
    float mu0  = bn_raw[64 + j0] * invE;
    float isd0 = rsqrtf(bn_raw[96 + j0] * invE - mu0 * mu0 + 1e-5f);
    float mu1  = bn_raw[64 + j1] * invE;
    float isd1 = rsqrtf(bn_raw[96 + j1] * invE - mu1 * mu1 + 1e-5f);
    float h0 = gd[j0] * (Pd[(size_t)m * 32 + j0] - mu0) * isd0 + bed[j0];
    float h1 = gd[j1] * (Pd[(size_t)m * 32 + j1] - mu1) * isd1 + bed[j1];
    v2h p;
    p.x = (_Float16)h0; p.y = (_Float16)h1;
    htp[gid] = p;                            // coalesced
}

// ---------------- K_agemm: w in REGISTERS (fully-unrolled i), low block count
// grid (16 m-slices, 17 jp). Each block: load w once, loop 16 chunks x 8 m.
__global__ __launch_bounds__(256, 1) void k_agemm(const float* __restrict__ hsaugT,
                                                  const float* __restrict__ waug,
                                                  v2h* __restrict__ Ah,
                                                  float* __restrict__ A32) {
    int ms = blockIdx.x;                   // 16 slices of 128 m
    int jp = blockIdx.y;                   // 0..16
    int t  = threadIdx.x;                  // rh
    int mbase = ms * 128;
    if (jp < 16) {
        float w0[JA], w1[JA];
#pragma unroll
        for (int i = 0; i < JA; i++) {      // FULL unroll: static indices -> registers
            w0[i] = waug[(size_t)i * COLS + (2 * jp) * 256 + t];
            w1[i] = waug[(size_t)i * COLS + (2 * jp + 1) * 256 + t];
        }
#pragma unroll 1
        for (int ch = 0; ch < 16; ch++) {
            int m0 = mbase + ch * 8;
            float acc0[8], acc1[8];
#pragma unroll
            for (int ml = 0; ml < 8; ml++) { acc0[ml] = 0.f; acc1[ml] = 0.f; }
#pragma unroll
            for (int i = 0; i < JA; i++) {
                const float* hr = hsaugT + (size_t)i * 2048 + m0;   // s_load dwordx8
#pragma unroll
                for (int ml = 0; ml < 8; ml++) {
                    float hv = hr[ml];
                    acc0[ml] += hv * w0[i];
                    acc1[ml] += hv * w1[i];
                }
            }
#pragma unroll
            for (int ml = 0; ml < 8; ml++) {
                v2h p;
                p.x = (_Float16)acc0[ml]; p.y = (_Float16)acc1[ml];
                Ah[(size_t)(m0 + ml) * 4096 + jp * 256 + t] = p;
            }
        }
    } else {
        float w2[JA];
#pragma unroll
        for (int i = 0; i < JA; i++) w2[i] = waug[(size_t)i * COLS + 32 * 256 + t];
#pragma unroll 1
        for (int ch = 0; ch < 16; ch++) {
            int m0 = mbase + ch * 8;
            float acc[8];
#pragma unroll
            for (int ml = 0; ml < 8; ml++) acc[ml] = 0.f;
#pragma unroll
            for (int i = 0; i < JA; i++) {
                const float* hr = hsaugT + (size_t)i * 2048 + m0;
#pragma unroll
                for (int ml = 0; ml < 8; ml++) acc[ml] += hr[ml] * w2[i];
            }
#pragma unroll
            for (int ml = 0; ml < 8; ml++)
                A32[(size_t)(m0 + ml) * 256 + t] = acc[ml];
        }
    }
}

// ---------------- K_z: MFMA edge-tile GEMM + replicated LN-stat atomics -----
__global__ __launch_bounds__(256) void k_z(const unsigned int* __restrict__ Ah,
                                           const float* __restrict__ A32,
                                           const uint4* __restrict__ htp4,
                                           const int* __restrict__ ustart,
                                           const int2* __restrict__ eonv,
                                           _Float16* __restrict__ zh,
                                           float* __restrict__ zsumR,
                                           float* __restrict__ zsqR) {
    int t    = threadIdx.x;
    int lane = t & 63;
    int uu   = blockIdx.x * 4 + (t >> 6);
    int l15  = lane & 15, quad = lane >> 4;

    // B fragments for all 16 rh-tiles (64 VGPRs, loaded once per u)
    uint4 bf[16];
#pragma unroll
    for (int nt = 0; nt < 16; nt++) {
        const unsigned int* bp = Ah + (size_t)uu * 4096 + (quad * 4) * 256 + nt * 16 + l15;
        bf[nt].x = bp[0]; bf[nt].y = bp[256]; bf[nt].z = bp[512]; bf[nt].w = bp[768];
    }
    float a32[16];
#pragma unroll
    for (int nt = 0; nt < 16; nt++) a32[nt] = A32[(size_t)uu * 256 + nt * 16 + l15];

    float s1[16], s2[16];
#pragma unroll
    for (int nt = 0; nt < 16; nt++) { s1[nt] = 0.f; s2[nt] = 0.f; }

    int e0 = ustart[uu], e1 = ustart[uu + 1];
    for (int base = e0; base < e1; base += 16) {
        int ei = min(base + l15, e1 - 1);          // clamp: duplicate rows are idempotent
        int2 q = eonv[ei];
        uint4 afu = htp4[(size_t)q.y * 4 + quad];  // A-frag: vector dwordx4, no broadcast
        cvt8 ac; ac.u4 = afu;
        int nrow[4], valid[4];
#pragma unroll
        for (int r = 0; r < 4; r++) {
            int er = quad * 4 + r;
            nrow[r]  = __builtin_amdgcn_ds_bpermute(er << 2, q.x);   // n of D-row er
            valid[r] = (base + er) < e1;
        }
#pragma unroll
        for (int nt = 0; nt < 16; nt++) {
            cvt8 bc; bc.u4 = bf[nt];
            v4f acc = { a32[nt], a32[nt], a32[nt], a32[nt] };
            acc = __builtin_amdgcn_mfma_f32_16x16x32_f16(ac.h8, bc.h8, acc, 0, 0, 0);
#pragma unroll
            for (int r = 0; r < 4; r++) {
                if (valid[r]) {
                    float z = acc[r];
                    zh[(size_t)nrow[r] * 256 + nt * 16 + l15] = (_Float16)z;
                    s1[nt] += z; s2[nt] += z * z;
                }
            }
        }
    }
    int rep = (blockIdx.x & (NREP - 1)) * 256;     // replica slice (atomic decontention)
#pragma unroll
    for (int nt = 0; nt < 16; nt++) {
        float a = s1[nt], b = s2[nt];
        a += __shfl_xor(a, 16); a += __shfl_xor(a, 32);
        b += __shfl_xor(b, 16); b += __shfl_xor(b, 32);
        if (quad == 0) {
            atomicAdd(&zsumR[rep + nt * 16 + l15], a);
            atomicAdd(&zsqR[rep + nt * 16 + l15], b);
        }
    }
}

// ---------------- K_logit: LN (replica-sum inline) + tanh + contract --------
__global__ __launch_bounds__(256) void k_logit(const _Float16* __restrict__ zh,
                                               const float* __restrict__ zsumR,
                                               const float* __restrict__ zsqR,
                                               const float* __restrict__ ntlu,
                                               const float* __restrict__ ntlg,
                                               const float* __restrict__ ntlbe,
                                               float* __restrict__ out) {
    int t  = threadIdx.x;                 // rh = r*16+h
    int n0 = blockIdx.x * 16;
    float su = 0.f, sq = 0.f;
#pragma unroll
    for (int r = 0; r < NREP; r++) {
        su += zsumR[r * 256 + t];
        sq += zsqR[r * 256 + t];
    }
    float mu  = su / (float)E_;
    float var = sq / (float)E_ - mu * mu;
    float isd = rsqrtf(var + 1e-5f);
    float g   = ntlg[t],  be  = ntlbe[t];
    float uw  = ntlu[t];
    float zv[16];
#pragma unroll
    for (int nl = 0; nl < 16; nl++)
        zv[nl] = (float)zh[(size_t)(n0 + nl) * 256 + t];
#pragma unroll 1
    for (int nl = 0; nl < 16; nl++) {
        float zn  = g * (zv[nl] - mu) * isd + be;
        float val = uw * tanh_fast(zn);
        val += __shfl_xor(val, 1);
        val += __shfl_xor(val, 2);
        val += __shfl_xor(val, 4);
        val += __shfl_xor(val, 8);
        if ((t & 15) == 0) out[(size_t)(n0 + nl) * 16 + (t >> 4)] = val;
    }
}

// ============================ host side =====================================
extern "C" void kernel_launch(void* const* d_in, const int* in_sizes, int n_in,
                              void* d_out, int out_size, void* d_ws, size_t ws_size,
                              hipStream_t stream) {
    const int*   seq   = (const int*)d_in[0];
    const int*   p2g   = (const int*)d_in[1];
    const int*   idx   = (const int*)d_in[2];
    const int*   u     = (const int*)d_in[3];
    const int*   v     = (const int*)d_in[4];
    const float* emb   = (const float*)d_in[5];
    const float* wihf  = (const float*)d_in[6];
    const float* whhf  = (const float*)d_in[7];
    const float* bihf  = (const float*)d_in[8];
    const float* bhhf  = (const float*)d_in[9];
    const float* wihb  = (const float*)d_in[10];
    const float* whhb  = (const float*)d_in[11];
    const float* bihb  = (const float*)d_in[12];
    const float* bhhb  = (const float*)d_in[13];
    const float* wsrc  = (const float*)d_in[14];
    const float* bsrc  = (const float*)d_in[15];
    const float* wdst  = (const float*)d_in[16];
    const float* bdst  = (const float*)d_in[17];
    const float* gs    = (const float*)d_in[18];
    const float* bes   = (const float*)d_in[19];
    const float* gd    = (const float*)d_in[20];
    const float* bed   = (const float*)d_in[21];
    const float* ntlw  = (const float*)d_in[22];
    const float* ntlv  = (const float*)d_in[23];
    const float* ntlb  = (const float*)d_in[24];
    const float* ntlu  = (const float*)d_in[25];
    const float* ntlg  = (const float*)d_in[26];
    const float* ntlbe = (const float*)d_in[27];
    float* out = (float*)d_out;

    char* ws = (char*)d_ws;
    size_t off = 0;
    auto take = [&](size_t bytes) -> char* {
        char* p = ws + off;
        off = (off + bytes + 255) & ~(size_t)255;
        return p;
    };
    // zeroed region (contiguous, one memset)
    int*   cnt_u  = (int*)  take(2048 * 4);
    int*   cnt_v  = (int*)  take(2048 * 4);
    float* zsumR  = (float*)take((size_t)NREP * 256 * 4);
    float* zsqR   = (float*)take((size_t)NREP * 256 * 4);
    float* bn_raw = (float*)take(128 * 4);
    float* x_grp  = (float*)take((size_t)B_ * G_ * 64 * 4);   // accumulated via atomics
    size_t zero_bytes = off;
    // rest
    int*   ucursor = (int*)  take(2048 * 4);
    int*   ustart  = (int*)  take(2049 * 4);
    int2*  eonv    = (int2*) take((size_t)E_ * 8);
    float* pre     = (float*)take((size_t)2 * 8192 * 256 * 4);
    float* hgrp    = (float*)take((size_t)B_ * G_ * 128 * 4);
    float* Psrc    = (float*)take((size_t)M_ * 32 * 4);
    float* Pdst    = (float*)take((size_t)M_ * 32 * 4);
    float* hsaugT  = (float*)take((size_t)36 * 2048 * 4);
    v2h*   htp     = (v2h*)  take((size_t)M_ * 16 * 4);
    float* waug    = (float*)take((size_t)JA * COLS * 4);
    v2h*   Ah      = (v2h*)  take((size_t)M_ * 4096 * 4);
    float* A32     = (float*)take((size_t)M_ * 256 * 4);
    _Float16* zbuf = (_Float16*)take((size_t)E_ * 256 * 2);
    (void)ws_size; (void)in_sizes; (void)n_in; (void)out_size;

    hipMemsetAsync(d_ws, 0, zero_bytes, stream);

    k_eh<<<512 + 1089, 256, 0, stream>>>(seq, p2g, emb, u, v, ntlw, ntlv, ntlb,
                                         x_grp, cnt_u, cnt_v, waug);
    k_pre<<<513, 256, 0, stream>>>(x_grp, wihf, bihf, bhhf, wihb, bihb, bhhb, pre,
                                   cnt_u, ustart, ucursor);
    k_lstm<<<384, 256, 0, stream>>>(pre, whhf, whhb, hgrp, u, v, ucursor, eonv);
    k_gp<<<M_ / 8, 256, 0, stream>>>(idx, p2g, hgrp, cnt_u, cnt_v,
                                     wsrc, bsrc, wdst, bdst, Psrc, Pdst, bn_raw);
    k_prep<<<392, 256, 0, stream>>>(Psrc, Pdst, bn_raw, gs, bes, gd, bed, hsaugT, htp);
    k_agemm<<<dim3(16, 17), 256, 0, stream>>>(hsaugT, waug, Ah, A32);
    k_z<<<512, 256, 0, stream>>>((const unsigned int*)Ah, A32, (const uint4*)htp,
                                 ustart, eonv, zbuf, zsumR, zsqR);
    k_logit<<<E_ / 16, 256, 0, stream>>>(zbuf, zsumR, zsqR, ntlu, ntlg, ntlbe, out);
}

// Round 8
// 351.575 us; speedup vs baseline: 1.2665x; 1.0254x over previous
//
#include <hip/hip_runtime.h>
#include <hip/hip_bf16.h>
#include <hip/hip_fp16.h>
#include <cstdint>

// Problem constants
constexpr int B_   = 64;
constexpr int L_   = 512;
constexpr int G_   = 128;
constexpr int E_   = 65536;
constexpr int RH   = 256;    // NREL*NHID
constexpr int M_   = 2048;   // B*N distinct nodes
constexpr int JA   = 33;     // augmented j (32 + const-1 slot)
constexpr int COLS = RH * JA;   // 8448
constexpr int NREP = 16;     // LN-stat accumulator replicas (atomic decontention)

typedef _Float16 v2h __attribute__((ext_vector_type(2)));
typedef _Float16 v8h __attribute__((ext_vector_type(8)));
typedef float    v4f __attribute__((ext_vector_type(4)));
typedef union { uint4 u4; v8h h8; } cvt8;

#define DEV static __device__ __forceinline__

DEV float sigm(float x) { return 1.f / (1.f + __expf(-x)); }
DEV float tanh_fast(float x) {
    x = fminf(15.f, fmaxf(-15.f, x));
    float e = __expf(2.f * x);
    return (e - 1.f) / (e + 1.f);
}

// ---------------- K_eh: embed + edge histograms + waug build ----------------
// blocks 0..255: embed (4 blocks/batch, lgkm-clean inner loop);
// blocks 256..511: hist; 512..1600: waug (read-coalesced).
// waug layout: waug[i*COLS + j*256 + rh]
__global__ __launch_bounds__(256) void k_eh(const int* __restrict__ seq,
                                            const int* __restrict__ p2g,
                                            const float* __restrict__ emb,
                                            const int* __restrict__ u,
                                            const int* __restrict__ v,
                                            const float* __restrict__ ntlw,
                                            const float* __restrict__ ntlv,
                                            const float* __restrict__ ntlb,
                                            float* __restrict__ xg,
                                            int* __restrict__ cu, int* __restrict__ cv,
                                            float* __restrict__ waug) {
    int blk = blockIdx.x;
    int t   = threadIdx.x;
    if (blk >= 512) {
        int gid = (blk - 512) * 256 + t;      // j-fastest: coalesced ntlw reads
        int i   = gid / COLS;
        int rem = gid - i * COLS;
        int rh  = rem / JA;
        int j   = rem - rh * JA;
        float val;
        if (i < 32) val = (j < 32) ? ntlw[((size_t)rh * 32 + i) * 32 + j] : ntlv[rh * 64 + i];
        else        val = (j < 32) ? ntlv[rh * 64 + 32 + j] : ntlb[rh];
        waug[(size_t)i * COLS + j * 256 + rh] = val;   // scattered, L2-absorbed
        return;
    }
    if (blk >= 256) {
        int n = (blk - 256) * 256 + t;
        atomicAdd(&cu[u[n]], 1);
        atomicAdd(&cv[v[n]], 1);
        return;
    }
    // ---- embed: 4 blocks per batch, each covers 128 sequence positions ----
    __shared__ float xgl[G_ * 64];          // 32 KB partial sums
    __shared__ int sl[128], gld[128];
    int b = blk >> 2, part = blk & 3;
    for (int i = t; i < G_ * 64; i += 256) xgl[i] = 0.f;
    if (t < 128) {
        sl[t]  = seq[b * L_ + part * 128 + t];
        gld[t] = p2g[b * L_ + part * 128 + t];
    }
    __syncthreads();
    int d = t & 63, sub = t >> 6;
#pragma unroll
    for (int gg = 0; gg < 2; gg++) {
        int sv[16], gv[16];
#pragma unroll
        for (int k = 0; k < 16; k++) {       // batch LDS reads first (lgkm group)
            sv[k] = sl[sub * 32 + gg * 16 + k];
            gv[k] = gld[sub * 32 + gg * 16 + k];
        }
#pragma unroll
        for (int k = 0; k < 16; k++)         // then pure-vm loads + ds atomics
            atomicAdd(&xgl[gv[k] * 64 + d], emb[(size_t)sv[k] * 64 + d]);
    }
    __syncthreads();
    for (int i = t; i < G_ * 64; i += 256)   // flush partials (xg pre-zeroed)
        atomicAdd(&xg[(size_t)b * G_ * 64 + i], xgl[i]);
}

// ---------------- K_pre: input-gate GEMM (scalar x broadcast) + scan --------
__global__ __launch_bounds__(256) void k_pre(const float* __restrict__ xg,
                                             const float* __restrict__ wihf,
                                             const float* __restrict__ bihf,
                                             const float* __restrict__ bhhf,
                                             const float* __restrict__ wihb,
                                             const float* __restrict__ bihb,
                                             const float* __restrict__ bhhb,
                                             float* __restrict__ pre,
                                             const int* __restrict__ cu,
                                             int* __restrict__ ustart,
                                             int* __restrict__ ucursor) {
    int blk = blockIdx.x;
    int t   = threadIdx.x;
    if (blk == 512) {
        __shared__ int ps[256];
        int base = t * 8, run = 0;
        int c[8], loc[8];
#pragma unroll
        for (int i = 0; i < 8; i++) c[i] = cu[base + i];
#pragma unroll
        for (int i = 0; i < 8; i++) { loc[i] = run; run += c[i]; }
        ps[t] = run;
        __syncthreads();
        for (int off = 1; off < 256; off <<= 1) {
            int a = (t >= off) ? ps[t - off] : 0;
            __syncthreads();
            ps[t] += a;
            __syncthreads();
        }
        int ex = ps[t] - run;
#pragma unroll
        for (int i = 0; i < 8; i++) { ustart[base + i] = ex + loc[i]; ucursor[base + i] = ex + loc[i]; }
        if (t == 255) ustart[2048] = E_;
        return;
    }
    int dir = blk >> 8;
    const float* wih = dir ? wihb : wihf;
    float bias = dir ? (bihb[t] + bhhb[t]) : (bihf[t] + bhhf[t]);
    int r0 = (blk & 255) * 32;

    float4 wv[16];
#pragma unroll
    for (int c = 0; c < 16; c++) wv[c] = ((const float4*)(wih + t * 64))[c];

#pragma unroll 2
    for (int ml = 0; ml < 32; ml++) {
        const float* xr = xg + (size_t)(r0 + ml) * 64;   // wave-uniform -> s_load
        float acc = bias;
#pragma unroll
        for (int c = 0; c < 16; c++) {
            float x0 = xr[4 * c], x1 = xr[4 * c + 1], x2 = xr[4 * c + 2], x3 = xr[4 * c + 3];
            acc += x0 * wv[c].x + x1 * wv[c].y + x2 * wv[c].z + x3 * wv[c].w;
        }
        pre[((size_t)dir * 8192 + r0 + ml) * 256 + t] = acc;   // gate-major, coalesced
    }
}

// ---------------- K_lstm: merged 128-step recurrence (round-0 verbatim) -----
// Five redesign rounds (r1-r7) proved hipcc demotes any >=512B weight alloca
// to scratch, and removing plds staging (r7) loses even wv[16] promotion
// (VGPR 40, weights re-streamed from L2 at ~64KB/block/step). This exact
// form is the only measured configuration with register-resident weights
// (VGPR 132, 79.7 us). Parallelism cap: 128 chains on 256 CUs.
// blocks 128..383: edge counting-sort rider.
__global__ __launch_bounds__(256, 1) void k_lstm(const float* __restrict__ pre,
                                                 const float* __restrict__ whh_f,
                                                 const float* __restrict__ whh_b,
                                                 float* __restrict__ hgrp,
                                                 const int* __restrict__ u,
                                                 const int* __restrict__ v,
                                                 int* __restrict__ ucursor,
                                                 int2* __restrict__ eonv) {
    int blk = blockIdx.x;
    int t   = threadIdx.x;
    if (blk >= 128) {
        int n = (blk - 128) * 256 + t;
        int pos = atomicAdd(&ucursor[u[n]], 1);
        eonv[pos] = make_int2(n, v[n]);
        return;
    }
    __shared__ __align__(16) float plds[64][256];
    __shared__ __align__(16) float hist[64][64];
    __shared__ float gl[2][256];
    int dir = blk >> 6;
    int b   = blk & 63;
    const float* whh = dir ? whh_b : whh_f;
    const float* src = pre + ((size_t)dir * 8192 + (size_t)b * G_) * 256;
    int e = t & 63;
    int q = t >> 6;

    float4 wv[16];
#pragma unroll
    for (int c = 0; c < 16; c++) wv[c] = ((const float4*)(whh + (size_t)t * 64))[c];

    float h = 0.f, creg = 0.f;

    for (int half = 0; half < 2; half++) {
        {
            int base = (dir ^ half) ? 64 : 0;
            const float4* s4 = (const float4*)(src + (size_t)base * 256);
            float4* d4 = (float4*)&plds[0][0];
#pragma unroll
            for (int i = 0; i < 16; i++) d4[i * 256 + t] = s4[i * 256 + t];
        }
        __syncthreads();
        for (int kk = 0; kk < 64; kk++) {
            int k = half * 64 + kk;
            int srow = dir ? (63 - kk) : kk;
            float p = plds[srow][t];
            float a0 = p, a1 = 0.f, a2 = 0.f, a3 = 0.f;
#pragma unroll
            for (int c = 0; c < 16; c++) {
                float f0 = __int_as_float(__builtin_amdgcn_readlane(__float_as_int(h), 4 * c + 0));
                float f1 = __int_as_float(__builtin_amdgcn_readlane(__float_as_int(h), 4 * c + 1));
                float f2 = __int_as_float(__builtin_amdgcn_readlane(__float_as_int(h), 4 * c + 2));
                float f3 = __int_as_float(__builtin_amdgcn_readlane(__float_as_int(h), 4 * c + 3));
                a0 += wv[c].x * f0;
                a1 += wv[c].y * f1;
                a2 += wv[c].z * f2;
                a3 += wv[c].w * f3;
            }
            float g = (a0 + a1) + (a2 + a3);
            gl[k & 1][t] = (q == 2) ? tanh_fast(g) : sigm(g);
            __syncthreads();
            float ai = gl[k & 1][e];
            float af = gl[k & 1][64 + e];
            float ag = gl[k & 1][128 + e];
            float ao = gl[k & 1][192 + e];
            creg = af * creg + ai * ag;
            h = ao * tanh_fast(creg);
            if (q == 0) hist[srow][e] = h;
        }
        __syncthreads();
        int sbase = (dir ? (1 - half) : half) * 64;
#pragma unroll
        for (int i = 0; i < 16; i++) {
            int row = q * 16 + i;
            int s = sbase + row;
            hgrp[((size_t)(b * G_ + s)) * 128 + dir * 64 + e] = hist[row][e];
        }
    }
}

// ---------------- K_gp: gather + projections + BN partial stats (fused) -----
// W loads MERGED into the FMA loop: the previous wr[32] float4 staging was a
// 512B alloca — the exact size class hipcc demotes to scratch (proven on
// k_lstm r3/r4). Fused load+FMA never materializes the array; W tables are
// 16KB/side, 8-fold broadcast-read -> L1-resident. Numerics identical.
__global__ __launch_bounds__(256) void k_gp(const int* __restrict__ idx,
                                            const int* __restrict__ p2g,
                                            const float* __restrict__ hgrp,
                                            const int* __restrict__ cu,
                                            const int* __restrict__ cv,
                                            const float* __restrict__ wsrc,
                                            const float* __restrict__ bsrc,
                                            const float* __restrict__ wdst,
                                            const float* __restrict__ bdst,
                                            float* __restrict__ Ps, float* __restrict__ Pd,
                                            float* __restrict__ bn_raw) {
    __shared__ __align__(16) float hsl[8][128];
    __shared__ float red[256];
    int m0 = blockIdx.x * 8;
    int t  = threadIdx.x;
    int d = t & 127, mh = t >> 7;
#pragma unroll
    for (int rep = 0; rep < 4; rep++) {
        int ml = rep * 2 + mh;
        int m  = m0 + ml;
        int b  = m >> 5;
        float acc = 0.f;
#pragma unroll
        for (int k = 0; k < 8; k++) {
            int l = idx[m * 8 + k];
            int g = p2g[b * L_ + l];
            acc += hgrp[((size_t)b * G_ + g) * 128 + d];
        }
        hsl[ml][d] = acc;
    }
    __syncthreads();
    int ml = t >> 5, o = t & 31;
    int m  = m0 + ml;
    const float4* hp = (const float4*)&hsl[ml][0];
    float cw_u = (float)cu[m], cw_v = (float)cv[m];
#pragma unroll 1
    for (int side = 0; side < 2; side++) {
        const float* W = side ? wdst : wsrc;
        const float4* wrow = (const float4*)(W + (size_t)o * 128);
        float acc = side ? bdst[o] : bsrc[o];
#pragma unroll
        for (int c = 0; c < 32; c++) {       // load fused with use: no alloca
            float4 h4 = hp[c];
            float4 w4 = wrow[c];
            acc += h4.x * w4.x + h4.y * w4.y + h4.z * w4.z + h4.w * w4.w;
        }
        (side ? Pd : Ps)[(size_t)m * 32 + o] = acc;
        float cw = side ? cw_v : cw_u;
        red[t] = cw * acc;
        __syncthreads();
        if (t < 32) {
            float s = 0.f;
#pragma unroll
            for (int i = 0; i < 8; i++) s += red[i * 32 + t];
            atomicAdd(&bn_raw[side * 64 + t], s);
        }
        __syncthreads();
        red[t] = cw * acc * acc;
        __syncthreads();
        if (t < 32) {
            float s = 0.f;
#pragma unroll
            for (int i = 0; i < 8; i++) s += red[i * 32 + t];
            atomicAdd(&bn_raw[side * 64 + 32 + t], s);
        }
        __syncthreads();
    }
}

// ---------------- K_prep: BN-normalize; build hsaugT[i][m] and htp (f16x2) --
__global__ __launch_bounds__(256) void k_prep(const float* __restrict__ Ps,
                                              const float* __restrict__ Pd,
                                              const float* __restrict__ bn_raw,
                                              const float* __restrict__ gs,
                                              const float* __restrict__ bes,
                                              const float* __restrict__ gd,
                                              const float* __restrict__ bed,
                                              float* __restrict__ hsaugT,
                                              v2h* __restrict__ htp) {
    int blk = blockIdx.x;
    int t   = threadIdx.x;
    constexpr float invE = 1.f / (float)E_;
    if (blk < 264) {                        // 264*256 = 33*2048
        int gid = blk * 256 + t;
        int c = gid >> 11;                   // 0..32
        int m = gid & 2047;
        float val = 1.f;
        if (c < 32) {
            float mu  = bn_raw[c] * invE;
            float isd = rsqrtf(bn_raw[32 + c] * invE - mu * mu + 1e-5f);
            val = gs[c] * (Ps[(size_t)m * 32 + c] - mu) * isd + bes[c];
        }
        hsaugT[(size_t)c * 2048 + m] = val;   // coalesced over m
        return;
    }
    int gid = (blk - 264) * 256 + t;         // 128*256 = 2048*16
    int m  = gid >> 4;
    int jp = gid & 15;
    int j0 = 2 * jp, j1 = 2 * jp + 1;
    float mu0  = bn_raw[64 + j0] * invE;
    float isd0 = rsqrtf(bn_raw[96 + j0] * invE - mu0 * mu0 + 1e-5f);
    float mu1  = bn_raw[64 + j1] * invE;
    float isd1 = rsqrtf(bn_raw[96 + j1] * invE - mu1 * mu1 + 1e-5f);
    float h0 = gd[j0] * (Pd[(size_t)m * 32 + j0] - mu0) * isd0 + bed[j0];
    float h1 = gd[j1] * (Pd[(size_t)m * 32 + j1] - mu1) * isd1 + bed[j1];
    v2h p;
    p.x = (_Float16)h0; p.y = (_Float16)h1;
    htp[gid] = p;                            // coalesced
}

// ---------------- K_agemm: w in REGISTERS (fully-unrolled i), low block count
// grid (16 m-slices, 17 jp). Each block: load w once, loop 16 chunks x 8 m.
__global__ __launch_bounds__(256, 1) void k_agemm(const float* __restrict__ hsaugT,
                                                  const float* __restrict__ waug,
                                                  v2h* __restrict__ Ah,
                                                  float* __restrict__ A32) {
    int ms = blockIdx.x;                   // 16 slices of 128 m
    int jp = blockIdx.y;                   // 0..16
    int t  = threadIdx.x;                  // rh
    int mbase = ms * 128;
    if (jp < 16) {
        float w0[JA], w1[JA];
#pragma unroll
        for (int i = 0; i < JA; i++) {      // FULL unroll: static indices -> registers
            w0[i] = waug[(size_t)i * COLS + (2 * jp) * 256 + t];
            w1[i] = waug[(size_t)i * COLS + (2 * jp + 1) * 256 + t];
        }
#pragma unroll 1
        for (int ch = 0; ch < 16; ch++) {
            int m0 = mbase + ch * 8;
            float acc0[8], acc1[8];
#pragma unroll
            for (int ml = 0; ml < 8; ml++) { acc0[ml] = 0.f; acc1[ml] = 0.f; }
#pragma unroll
            for (int i = 0; i < JA; i++) {
                const float* hr = hsaugT + (size_t)i * 2048 + m0;   // s_load dwordx8
#pragma unroll
                for (int ml = 0; ml < 8; ml++) {
                    float hv = hr[ml];
                    acc0[ml] += hv * w0[i];
                    acc1[ml] += hv * w1[i];
                }
            }
#pragma unroll
            for (int ml = 0; ml < 8; ml++) {
                v2h p;
                p.x = (_Float16)acc0[ml]; p.y = (_Float16)acc1[ml];
                Ah[(size_t)(m0 + ml) * 4096 + jp * 256 + t] = p;
            }
        }
    } else {
        float w2[JA];
#pragma unroll
        for (int i = 0; i < JA; i++) w2[i] = waug[(size_t)i * COLS + 32 * 256 + t];
#pragma unroll 1
        for (int ch = 0; ch < 16; ch++) {
            int m0 = mbase + ch * 8;
            float acc[8];
#pragma unroll
            for (int ml = 0; ml < 8; ml++) acc[ml] = 0.f;
#pragma unroll
            for (int i = 0; i < JA; i++) {
                const float* hr = hsaugT + (size_t)i * 2048 + m0;
#pragma unroll
                for (int ml = 0; ml < 8; ml++) acc[ml] += hr[ml] * w2[i];
            }
#pragma unroll
            for (int ml = 0; ml < 8; ml++)
                A32[(size_t)(m0 + ml) * 256 + t] = acc[ml];
        }
    }
}

// ---------------- K_z: MFMA edge-tile GEMM + replicated LN-stat atomics -----
__global__ __launch_bounds__(256) void k_z(const unsigned int* __restrict__ Ah,
                                           const float* __restrict__ A32,
                                           const uint4* __restrict__ htp4,
                                           const int* __restrict__ ustart,
                                           const int2* __restrict__ eonv,
                                           _Float16* __restrict__ zh,
                                           float* __restrict__ zsumR,
                                           float* __restrict__ zsqR) {
    int t    = threadIdx.x;
    int lane = t & 63;
    int uu   = blockIdx.x * 4 + (t >> 6);
    int l15  = lane & 15, quad = lane >> 4;

    // B fragments for all 16 rh-tiles (64 VGPRs, loaded once per u)
    uint4 bf[16];
#pragma unroll
    for (int nt = 0; nt < 16; nt++) {
        const unsigned int* bp = Ah + (size_t)uu * 4096 + (quad * 4) * 256 + nt * 16 + l15;
        bf[nt].x = bp[0]; bf[nt].y = bp[256]; bf[nt].z = bp[512]; bf[nt].w = bp[768];
    }
    float a32[16];
#pragma unroll
    for (int nt = 0; nt < 16; nt++) a32[nt] = A32[(size_t)uu * 256 + nt * 16 + l15];

    float s1[16], s2[16];
#pragma unroll
    for (int nt = 0; nt < 16; nt++) { s1[nt] = 0.f; s2[nt] = 0.f; }

    int e0 = ustart[uu], e1 = ustart[uu + 1];
    for (int base = e0; base < e1; base += 16) {
        int ei = min(base + l15, e1 - 1);          // clamp: duplicate rows are idempotent
        int2 q = eonv[ei];
        uint4 afu = htp4[(size_t)q.y * 4 + quad];  // A-frag: vector dwordx4, no broadcast
        cvt8 ac; ac.u4 = afu;
        int nrow[4], valid[4];
#pragma unroll
        for (int r = 0; r < 4; r++) {
            int er = quad * 4 + r;
            nrow[r]  = __builtin_amdgcn_ds_bpermute(er << 2, q.x);   // n of D-row er
            valid[r] = (base + er) < e1;
        }
#pragma unroll
        for (int nt = 0; nt < 16; nt++) {
            cvt8 bc; bc.u4 = bf[nt];
            v4f acc = { a32[nt], a32[nt], a32[nt], a32[nt] };
            acc = __builtin_amdgcn_mfma_f32_16x16x32_f16(ac.h8, bc.h8, acc, 0, 0, 0);
#pragma unroll
            for (int r = 0; r < 4; r++) {
                if (valid[r]) {
                    float z = acc[r];
                    zh[(size_t)nrow[r] * 256 + nt * 16 + l15] = (_Float16)z;
                    s1[nt] += z; s2[nt] += z * z;
                }
            }
        }
    }
    int rep = (blockIdx.x & (NREP - 1)) * 256;     // replica slice (atomic decontention)
#pragma unroll
    for (int nt = 0; nt < 16; nt++) {
        float a = s1[nt], b = s2[nt];
        a += __shfl_xor(a, 16); a += __shfl_xor(a, 32);
        b += __shfl_xor(b, 16); b += __shfl_xor(b, 32);
        if (quad == 0) {
            atomicAdd(&zsumR[rep + nt * 16 + l15], a);
            atomicAdd(&zsqR[rep + nt * 16 + l15], b);
        }
    }
}

// ---------------- K_logit: LN (replica-sum inline) + tanh + contract --------
__global__ __launch_bounds__(256) void k_logit(const _Float16* __restrict__ zh,
                                               const float* __restrict__ zsumR,
                                               const float* __restrict__ zsqR,
                                               const float* __restrict__ ntlu,
                                               const float* __restrict__ ntlg,
                                               const float* __restrict__ ntlbe,
                                               float* __restrict__ out) {
    int t  = threadIdx.x;                 // rh = r*16+h
    int n0 = blockIdx.x * 16;
    float su = 0.f, sq = 0.f;
#pragma unroll
    for (int r = 0; r < NREP; r++) {
        su += zsumR[r * 256 + t];
        sq += zsqR[r * 256 + t];
    }
    float mu  = su / (float)E_;
    float var = sq / (float)E_ - mu * mu;
    float isd = rsqrtf(var + 1e-5f);
    float g   = ntlg[t],  be  = ntlbe[t];
    float uw  = ntlu[t];
    float zv[16];
#pragma unroll
    for (int nl = 0; nl < 16; nl++)
        zv[nl] = (float)zh[(size_t)(n0 + nl) * 256 + t];
#pragma unroll 1
    for (int nl = 0; nl < 16; nl++) {
        float zn  = g * (zv[nl] - mu) * isd + be;
        float val = uw * tanh_fast(zn);
        val += __shfl_xor(val, 1);
        val += __shfl_xor(val, 2);
        val += __shfl_xor(val, 4);
        val += __shfl_xor(val, 8);
        if ((t & 15) == 0) out[(size_t)(n0 + nl) * 16 + (t >> 4)] = val;
    }
}

// ============================ host side =====================================
extern "C" void kernel_launch(void* const* d_in, const int* in_sizes, int n_in,
                              void* d_out, int out_size, void* d_ws, size_t ws_size,
                              hipStream_t stream) {
    const int*   seq   = (const int*)d_in[0];
    const int*   p2g   = (const int*)d_in[1];
    const int*   idx   = (const int*)d_in[2];
    const int*   u     = (const int*)d_in[3];
    const int*   v     = (const int*)d_in[4];
    const float* emb   = (const float*)d_in[5];
    const float* wihf  = (const float*)d_in[6];
    const float* whhf  = (const float*)d_in[7];
    const float* bihf  = (const float*)d_in[8];
    const float* bhhf  = (const float*)d_in[9];
    const float* wihb  = (const float*)d_in[10];
    const float* whhb  = (const float*)d_in[11];
    const float* bihb  = (const float*)d_in[12];
    const float* bhhb  = (const float*)d_in[13];
    const float* wsrc  = (const float*)d_in[14];
    const float* bsrc  = (const float*)d_in[15];
    const float* wdst  = (const float*)d_in[16];
    const float* bdst  = (const float*)d_in[17];
    const float* gs    = (const float*)d_in[18];
    const float* bes   = (const float*)d_in[19];
    const float* gd    = (const float*)d_in[20];
    const float* bed   = (const float*)d_in[21];
    const float* ntlw  = (const float*)d_in[22];
    const float* ntlv  = (const float*)d_in[23];
    const float* ntlb  = (const float*)d_in[24];
    const float* ntlu  = (const float*)d_in[25];
    const float* ntlg  = (const float*)d_in[26];
    const float* ntlbe = (const float*)d_in[27];
    float* out = (float*)d_out;

    char* ws = (char*)d_ws;
    size_t off = 0;
    auto take = [&](size_t bytes) -> char* {
        char* p = ws + off;
        off = (off + bytes + 255) & ~(size_t)255;
        return p;
    };
    // zeroed region (contiguous, one memset)
    int*   cnt_u  = (int*)  take(2048 * 4);
    int*   cnt_v  = (int*)  take(2048 * 4);
    float* zsumR  = (float*)take((size_t)NREP * 256 * 4);
    float* zsqR   = (float*)take((size_t)NREP * 256 * 4);
    float* bn_raw = (float*)take(128 * 4);
    float* x_grp  = (float*)take((size_t)B_ * G_ * 64 * 4);   // accumulated via atomics
    size_t zero_bytes = off;
    // rest
    int*   ucursor = (int*)  take(2048 * 4);
    int*   ustart  = (int*)  take(2049 * 4);
    int2*  eonv    = (int2*) take((size_t)E_ * 8);
    float* pre     = (float*)take((size_t)2 * 8192 * 256 * 4);
    float* hgrp    = (float*)take((size_t)B_ * G_ * 128 * 4);
    float* Psrc    = (float*)take((size_t)M_ * 32 * 4);
    float* Pdst    = (float*)take((size_t)M_ * 32 * 4);
    float* hsaugT  = (float*)take((size_t)36 * 2048 * 4);
    v2h*   htp     = (v2h*)  take((size_t)M_ * 16 * 4);
    float* waug    = (float*)take((size_t)JA * COLS * 4);
    v2h*   Ah      = (v2h*)  take((size_t)M_ * 4096 * 4);
    float* A32     = (float*)take((size_t)M_ * 256 * 4);
    _Float16* zbuf = (_Float16*)take((size_t)E_ * 256 * 2);
    (void)ws_size; (void)in_sizes; (void)n_in; (void)out_size;

    hipMemsetAsync(d_ws, 0, zero_bytes, stream);

    k_eh<<<512 + 1089, 256, 0, stream>>>(seq, p2g, emb, u, v, ntlw, ntlv, ntlb,
                                         x_grp, cnt_u, cnt_v, waug);
    k_pre<<<513, 256, 0, stream>>>(x_grp, wihf, bihf, bhhf, wihb, bihb, bhhb, pre,
                                   cnt_u, ustart, ucursor);
    k_lstm<<<384, 256, 0, stream>>>(pre, whhf, whhb, hgrp, u, v, ucursor, eonv);
    k_gp<<<M_ / 8, 256, 0, stream>>>(idx, p2g, hgrp, cnt_u, cnt_v,
                                     wsrc, bsrc, wdst, bdst, Psrc, Pdst, bn_raw);
    k_prep<<<392, 256, 0, stream>>>(Psrc, Pdst, bn_raw, gs, bes, gd, bed, hsaugT, htp);
    k_agemm<<<dim3(16, 17), 256, 0, stream>>>(hsaugT, waug, Ah, A32);
    k_z<<<512, 256, 0, stream>>>((const unsigned int*)Ah, A32, (const uint4*)htp,
                                 ustart, eonv, zbuf, zsumR, zsqR);
    k_logit<<<E_ / 16, 256, 0, stream>>>(zbuf, zsumR, zsqR, ntlu, ntlg, ntlbe, out);
}